// Round 16
// baseline (337.542 us; speedup 1.0000x reference)
//
#include <hip/hip_runtime.h>
#include <math.h>

// Problem constants
#define BB 4
#define SS 1024
#define DD 768
#define HH 12
#define DHD 64
#define MROWS 4096
#define FF 3072

typedef unsigned short u16;
typedef float f32x4 __attribute__((ext_vector_type(4)));
typedef __bf16 bf16x8 __attribute__((ext_vector_type(8)));
typedef unsigned short u16x8 __attribute__((ext_vector_type(8)));
typedef unsigned short u16x4 __attribute__((ext_vector_type(4)));

static __device__ __forceinline__ float bf2f(u16 u) {
    union { unsigned int i; float f; } c; c.i = ((unsigned int)u) << 16; return c.f;
}
static __device__ __forceinline__ u16 f2bf(float f) {
    return __builtin_bit_cast(u16, static_cast<__bf16>(f));
}

#define LDST 40

// ---------------------------------------------------------------------------
// 128x128-tile bf16 MFMA GEMM. 4 waves (2x2), each wave 64x64 = 4x4 frags,
// BK=32. Depth-2 prefetch via explicit 2-step unroll. K % 64 == 0.
// ---------------------------------------------------------------------------
static __device__ __forceinline__ void gemm128_core(
    const u16* __restrict__ A, const u16* __restrict__ Bt,
    int K,
    const float* __restrict__ bias, int do_gelu,
    u16* __restrict__ Cbf, int ldcbf, int cboff,
    int row0, int col0, u16* As, u16* Bs)
{
    const int tid  = threadIdx.x;
    const int lane = tid & 63;
    const int w    = tid >> 6;
    const int wm = (w >> 1) * 64;
    const int wn = (w & 1) * 64;

    const int srow = tid >> 1;
    const int skc  = (tid & 1) * 16;

    const u16* Ap = A  + (size_t)(row0 + srow) * K + skc;
    const u16* Bp = Bt + (size_t)(col0 + srow) * K + skc;
    u16* AsW = &As[srow * LDST + skc];
    u16* BsW = &Bs[srow * LDST + skc];

    const int fr = lane & 15;
    const int fk = (lane >> 4) * 8;

    f32x4 acc[4][4] = {};

    u16x8 aa0, aa1, ba0, ba1;
    u16x8 ab0, ab1, bb0, bb1;
    aa0 = *(const u16x8*)(Ap);
    aa1 = *(const u16x8*)(Ap + 8);
    ba0 = *(const u16x8*)(Bp);
    ba1 = *(const u16x8*)(Bp + 8);
    ab0 = *(const u16x8*)(Ap + 32);
    ab1 = *(const u16x8*)(Ap + 40);
    bb0 = *(const u16x8*)(Bp + 32);
    bb1 = *(const u16x8*)(Bp + 40);

    for (int k0 = 0; k0 < K; k0 += 64) {
        if (k0) __syncthreads();
        *(u16x8*)(AsW)     = aa0;
        *(u16x8*)(AsW + 8) = aa1;
        *(u16x8*)(BsW)     = ba0;
        *(u16x8*)(BsW + 8) = ba1;
        __syncthreads();
        if (k0 + 64 < K) {
            aa0 = *(const u16x8*)(Ap + k0 + 64);
            aa1 = *(const u16x8*)(Ap + k0 + 72);
            ba0 = *(const u16x8*)(Bp + k0 + 64);
            ba1 = *(const u16x8*)(Bp + k0 + 72);
        }
        {
            bf16x8 af[4], bfv[4];
#pragma unroll
            for (int mi = 0; mi < 4; ++mi)
                af[mi] = __builtin_bit_cast(bf16x8,
                    *(const u16x8*)(&As[(wm + 16 * mi + fr) * LDST + fk]));
#pragma unroll
            for (int ni = 0; ni < 4; ++ni)
                bfv[ni] = __builtin_bit_cast(bf16x8,
                    *(const u16x8*)(&Bs[(wn + 16 * ni + fr) * LDST + fk]));
#pragma unroll
            for (int mi = 0; mi < 4; ++mi)
#pragma unroll
                for (int ni = 0; ni < 4; ++ni)
                    acc[mi][ni] = __builtin_amdgcn_mfma_f32_16x16x32_bf16(
                        af[mi], bfv[ni], acc[mi][ni], 0, 0, 0);
        }

        __syncthreads();
        *(u16x8*)(AsW)     = ab0;
        *(u16x8*)(AsW + 8) = ab1;
        *(u16x8*)(BsW)     = bb0;
        *(u16x8*)(BsW + 8) = bb1;
        __syncthreads();
        if (k0 + 96 < K) {
            ab0 = *(const u16x8*)(Ap + k0 + 96);
            ab1 = *(const u16x8*)(Ap + k0 + 104);
            bb0 = *(const u16x8*)(Bp + k0 + 96);
            bb1 = *(const u16x8*)(Bp + k0 + 104);
        }
        {
            bf16x8 af[4], bfv[4];
#pragma unroll
            for (int mi = 0; mi < 4; ++mi)
                af[mi] = __builtin_bit_cast(bf16x8,
                    *(const u16x8*)(&As[(wm + 16 * mi + fr) * LDST + fk]));
#pragma unroll
            for (int ni = 0; ni < 4; ++ni)
                bfv[ni] = __builtin_bit_cast(bf16x8,
                    *(const u16x8*)(&Bs[(wn + 16 * ni + fr) * LDST + fk]));
#pragma unroll
            for (int mi = 0; mi < 4; ++mi)
#pragma unroll
                for (int ni = 0; ni < 4; ++ni)
                    acc[mi][ni] = __builtin_amdgcn_mfma_f32_16x16x32_bf16(
                        af[mi], bfv[ni], acc[mi][ni], 0, 0, 0);
        }
    }

    const int orow0 = row0 + wm + (lane >> 4) * 4;
    const int ocol0 = col0 + wn + fr;
#pragma unroll
    for (int mi = 0; mi < 4; ++mi) {
#pragma unroll
        for (int ni = 0; ni < 4; ++ni) {
            const int col = ocol0 + ni * 16;
            const float bv = bias ? bias[col] : 0.0f;
#pragma unroll
            for (int r = 0; r < 4; ++r) {
                const int row = orow0 + mi * 16 + r;
                float v = acc[mi][ni][r] + bv;
                if (do_gelu) v = 0.5f * v * (1.0f + erff(v * 0.70710678118654752f));
                Cbf[(size_t)row * ldcbf + cboff + col] = f2bf(v);
            }
        }
    }
}

__global__ __launch_bounds__(256) void gemm128(
    const u16* __restrict__ A, const u16* __restrict__ Bt, int K,
    const float* __restrict__ bias, int do_gelu,
    u16* __restrict__ Cbf, int ldcbf)
{
    __shared__ u16 As[128 * LDST];
    __shared__ u16 Bs[128 * LDST];
    gemm128_core(A, Bt, K, bias, do_gelu, Cbf, ldcbf, 0,
                 blockIdx.y * 128, blockIdx.x * 128, As, Bs);
}

__global__ __launch_bounds__(256) void gemm128_qkv3(
    const u16* __restrict__ A0, const u16* __restrict__ A1, const u16* __restrict__ A2,
    const u16* __restrict__ B0, const u16* __restrict__ B1, const u16* __restrict__ B2,
    u16* __restrict__ Cbf, int ldcbf)
{
    __shared__ u16 As[128 * LDST];
    __shared__ u16 Bs[128 * LDST];
    const int z = blockIdx.z;
    const u16* A = (z == 0) ? A0 : (z == 1) ? A1 : A2;
    const u16* B = (z == 0) ? B0 : (z == 1) ? B1 : B2;
    gemm128_core(A, B, DD, nullptr, 0, Cbf, ldcbf, z * DD,
                 blockIdx.y * 128, blockIdx.x * 128, As, Bs);
}

// ---------------------------------------------------------------------------
// 64x128-tile GEMM (skinny launches: Wo x2, MLP2 split-K). Depth-2 unroll.
// ---------------------------------------------------------------------------
static __device__ __forceinline__ void gemm64_core(
    const u16* __restrict__ A, const u16* __restrict__ Bt,
    int N, int Kstride, int Klen,
    const float* __restrict__ bias,
    const float* __restrict__ residf, const u16* __restrict__ residb,
    float* __restrict__ C, u16* __restrict__ Cbf, int ldcbf, int cboff,
    int do_gelu, int row0, int col0, u16* As, u16* Bs)
{
    const int tid  = threadIdx.x;
    const int lane = tid & 63;
    const int w    = tid >> 6;
    const int wm = (w >> 1) * 32;
    const int wn = (w & 1) * 64;

    const int arow = tid >> 2;
    const int akc  = (tid & 3) * 8;
    const int brow = tid >> 1;
    const int bkc  = (tid & 1) * 16;

    const u16* Ap = A  + (size_t)(row0 + arow) * Kstride + akc;
    const u16* Bp = Bt + (size_t)(col0 + brow) * Kstride + bkc;
    u16* AsW = &As[arow * LDST + akc];
    u16* BsW = &Bs[brow * LDST + bkc];

    const int fr = lane & 15;
    const int fk = (lane >> 4) * 8;

    f32x4 acc[2][4] = {};

    u16x8 a0, b00, b01, a1, b10, b11;
    a0  = *(const u16x8*)(Ap);
    b00 = *(const u16x8*)(Bp);
    b01 = *(const u16x8*)(Bp + 8);
    a1  = *(const u16x8*)(Ap + 32);
    b10 = *(const u16x8*)(Bp + 32);
    b11 = *(const u16x8*)(Bp + 40);

    for (int k0 = 0; k0 < Klen; k0 += 64) {
        if (k0) __syncthreads();
        *(u16x8*)AsW       = a0;
        *(u16x8*)BsW       = b00;
        *(u16x8*)(BsW + 8) = b01;
        __syncthreads();
        if (k0 + 64 < Klen) {
            a0  = *(const u16x8*)(Ap + k0 + 64);
            b00 = *(const u16x8*)(Bp + k0 + 64);
            b01 = *(const u16x8*)(Bp + k0 + 72);
        }
        {
            bf16x8 af[2], bfv[4];
#pragma unroll
            for (int mi = 0; mi < 2; ++mi)
                af[mi] = __builtin_bit_cast(bf16x8,
                    *(const u16x8*)(&As[(wm + 16 * mi + fr) * LDST + fk]));
#pragma unroll
            for (int ni = 0; ni < 4; ++ni)
                bfv[ni] = __builtin_bit_cast(bf16x8,
                    *(const u16x8*)(&Bs[(wn + 16 * ni + fr) * LDST + fk]));
#pragma unroll
            for (int mi = 0; mi < 2; ++mi)
#pragma unroll
                for (int ni = 0; ni < 4; ++ni)
                    acc[mi][ni] = __builtin_amdgcn_mfma_f32_16x16x32_bf16(
                        af[mi], bfv[ni], acc[mi][ni], 0, 0, 0);
        }

        __syncthreads();
        *(u16x8*)AsW       = a1;
        *(u16x8*)BsW       = b10;
        *(u16x8*)(BsW + 8) = b11;
        __syncthreads();
        if (k0 + 96 < Klen) {
            a1  = *(const u16x8*)(Ap + k0 + 96);
            b10 = *(const u16x8*)(Bp + k0 + 96);
            b11 = *(const u16x8*)(Bp + k0 + 104);
        }
        {
            bf16x8 af[2], bfv[4];
#pragma unroll
            for (int mi = 0; mi < 2; ++mi)
                af[mi] = __builtin_bit_cast(bf16x8,
                    *(const u16x8*)(&As[(wm + 16 * mi + fr) * LDST + fk]));
#pragma unroll
            for (int ni = 0; ni < 4; ++ni)
                bfv[ni] = __builtin_bit_cast(bf16x8,
                    *(const u16x8*)(&Bs[(wn + 16 * ni + fr) * LDST + fk]));
#pragma unroll
            for (int mi = 0; mi < 2; ++mi)
#pragma unroll
                for (int ni = 0; ni < 4; ++ni)
                    acc[mi][ni] = __builtin_amdgcn_mfma_f32_16x16x32_bf16(
                        af[mi], bfv[ni], acc[mi][ni], 0, 0, 0);
        }
    }

    const int orow0 = row0 + wm + (lane >> 4) * 4;
    const int ocol0 = col0 + wn + fr;
#pragma unroll
    for (int mi = 0; mi < 2; ++mi) {
#pragma unroll
        for (int ni = 0; ni < 4; ++ni) {
            const int col = ocol0 + ni * 16;
            const float bv = bias ? bias[col] : 0.0f;
#pragma unroll
            for (int r = 0; r < 4; ++r) {
                const int row = orow0 + mi * 16 + r;
                float v = acc[mi][ni][r] + bv;
                if (do_gelu) v = 0.5f * v * (1.0f + erff(v * 0.70710678118654752f));
                if (residf) v += residf[(size_t)row * N + col];
                if (residb) v += bf2f(residb[(size_t)row * N + col]);
                if (C)   C[(size_t)row * N + col] = v;
                if (Cbf) Cbf[(size_t)row * ldcbf + cboff + col] = f2bf(v);
            }
        }
    }
}

__global__ __launch_bounds__(256) void gemm64(
    const u16* __restrict__ A, const u16* __restrict__ Bt, int N, int K,
    const float* __restrict__ bias,
    const float* __restrict__ residf, const u16* __restrict__ residb,
    float* __restrict__ C, u16* __restrict__ Cbf, int ldcbf, int do_gelu)
{
    __shared__ u16 As[64 * LDST];
    __shared__ u16 Bs[128 * LDST];
    gemm64_core(A, Bt, N, K, K, bias, residf, residb, C, Cbf, ldcbf, 0, do_gelu,
                blockIdx.y * 64, blockIdx.x * 128, As, Bs);
}

__global__ __launch_bounds__(256) void gemm64_sk(
    const u16* __restrict__ A, const u16* __restrict__ Bt, int N, int Kstride,
    int Klen, float* __restrict__ Cpair)
{
    __shared__ u16 As[64 * LDST];
    __shared__ u16 Bs[128 * LDST];
    const int z = blockIdx.z;
    const int koff = z * Klen;
    gemm64_core(A + koff, Bt + koff, N, Kstride, Klen,
                nullptr, nullptr, nullptr,
                Cpair + (size_t)z * MROWS * N, nullptr, 0, 0, 0,
                blockIdx.y * 64, blockIdx.x * 128, As, Bs);
}

// ---------------------------------------------------------------------------
// Transpose + fp32->bf16
// ---------------------------------------------------------------------------
__global__ __launch_bounds__(256) void tcvt_kernel(
    const float* __restrict__ in, u16* __restrict__ out, int K, int N)
{
    __shared__ float t[32][33];
    const float* ib = in + (size_t)blockIdx.z * K * N;
    u16* ob = out + (size_t)blockIdx.z * K * N;
    const int n0 = blockIdx.x * 32, k0 = blockIdx.y * 32;
    const int tx = threadIdx.x & 31, ty = threadIdx.x >> 5;
#pragma unroll
    for (int j = 0; j < 4; ++j)
        t[ty + j * 8][tx] = ib[(size_t)(k0 + ty + j * 8) * N + n0 + tx];
    __syncthreads();
#pragma unroll
    for (int j = 0; j < 4; ++j)
        ob[(size_t)(n0 + ty + j * 8) * K + k0 + tx] = f2bf(t[tx][ty + j * 8]);
}

__global__ __launch_bounds__(256) void tcvt6_kernel(
    const float* __restrict__ w0, const float* __restrict__ w1,
    const float* __restrict__ w2, const float* __restrict__ w3,
    const float* __restrict__ w4, const float* __restrict__ w5,
    u16* __restrict__ Wm6)
{
    __shared__ float t[32][33];
    const int z = blockIdx.z;
    const int wi = z / 12, head = z % 12;
    const float* wsel = (wi == 0) ? w0 : (wi == 1) ? w1 : (wi == 2) ? w2 :
                        (wi == 3) ? w3 : (wi == 4) ? w4 : w5;
    const float* ib = wsel + (size_t)head * DD * DHD;
    u16* ob = Wm6 + (size_t)wi * DD * DD + (size_t)head * DHD * DD;
    const int n0 = blockIdx.x * 32, k0 = blockIdx.y * 32;
    const int tx = threadIdx.x & 31, ty = threadIdx.x >> 5;
#pragma unroll
    for (int j = 0; j < 4; ++j)
        t[ty + j * 8][tx] = ib[(size_t)(k0 + ty + j * 8) * DHD + n0 + tx];
    __syncthreads();
#pragma unroll
    for (int j = 0; j < 4; ++j)
        ob[(size_t)(n0 + ty + j * 8) * DD + k0 + tx] = f2bf(t[tx][ty + j * 8]);
}

__global__ __launch_bounds__(256) void cvt3_kernel(
    const float* __restrict__ s0, const float* __restrict__ s1,
    const float* __restrict__ s2,
    u16* __restrict__ d0, u16* __restrict__ d1, u16* __restrict__ d2, int n4)
{
    const int z = blockIdx.z;
    const float* s = (z == 0) ? s0 : (z == 1) ? s1 : s2;
    u16* d = (z == 0) ? d0 : (z == 1) ? d1 : d2;
    const int i = blockIdx.x * 256 + threadIdx.x;
    if (i < n4) {
        float4 v = ((const float4*)s)[i];
        ushort4 o;
        o.x = f2bf(v.x); o.y = f2bf(v.y); o.z = f2bf(v.z); o.w = f2bf(v.w);
        ((ushort4*)d)[i] = o;
    }
}

// ---------------------------------------------------------------------------
// MFMA flash attention, 8 waves / 512 threads, 128-query tile per block.
// Max-free exp2 softmax (validated R11). K staged in rows 0..63 of the
// 128-row KPs buffer; P (128 rows) overwrites it after QK^T (barrier).
// Per-wave skip of fully-masked causal tiles (wave-uniform).
// LDS 27648 B -> 4 blocks/CU x 8 waves.
// ---------------------------------------------------------------------------
#define AST 72
#define CSC 0.18033688011112042f   // 0.125 * log2(e)
__global__ __launch_bounds__(512) void attn_mfma_kernel(
    const u16* __restrict__ Q, const u16* __restrict__ K,
    const u16* __restrict__ V, int ldq, const int* __restrict__ kmask,
    u16* __restrict__ O, int causal)
{
    const int qt = causal ? ((int)gridDim.x - 1 - (int)blockIdx.x) : (int)blockIdx.x;
    const int bh = blockIdx.y;
    const int b  = bh / HH;
    const int h  = bh % HH;
    const int tid  = threadIdx.x;
    const int lane = tid & 63;
    const int w    = tid >> 6;          // 0..7
    const int lr = lane & 15;
    const int lg = lane >> 4;

    __shared__ u16 KPs[128 * AST];      // K in rows 0..63; P in rows 0..127
    __shared__ u16 Vt[64 * AST];

    const int row0 = qt * 128;
    const int q0w  = row0 + w * 16;

    bf16x8 qf[2];
    {
        const u16* qp = Q + (size_t)(b * SS + q0w + lr) * ldq + h * DHD + lg * 8;
        qf[0] = __builtin_bit_cast(bf16x8, *(const u16x8*)(qp));
        qf[1] = __builtin_bit_cast(bf16x8, *(const u16x8*)(qp + 32));
    }

    // staging geometry (512 threads)
    const int sr = tid >> 3;                 // K row 0..63
    const int sc = (tid & 7) * 8;            // K col chunk
    const int vkey = tid & 63;               // V key
    const int vj = ((vkey & 15) << 2) | (vkey >> 4);   // permuted k-column
    const int vd = (tid >> 6) * 8;           // V d-chunk (8 d per thread)

    f32x4 acc[4] = {};
    float lsum[4] = {0.0f, 0.0f, 0.0f, 0.0f};

    const int nkt = causal ? (2 * qt + 2) : 16;

    u16x8 kr, vr;
    {
        const u16* kp = K + (size_t)(b * SS + sr) * ldq + h * DHD + sc;
        kr = *(const u16x8*)(kp);
        const u16* vp = V + (size_t)(b * SS + vkey) * ldq + h * DHD + vd;
        vr = *(const u16x8*)(vp);
    }

    for (int kt = 0; kt < nkt; ++kt) {
        const int kcol0 = kt * 64;
        if (kt) __syncthreads();        // all PV reads of KPs/Vt done

        *(u16x8*)(&KPs[sr * AST + sc]) = kr;
#pragma unroll
        for (int j = 0; j < 8; ++j) Vt[(vd + j) * AST + vj] = vr[j];
        __syncthreads();

        if (kt + 1 < nkt) {
            const int kn = kcol0 + 64;
            const u16* kp = K + (size_t)(b * SS + kn + sr) * ldq + h * DHD + sc;
            kr = *(const u16x8*)(kp);
            const u16* vp = V + (size_t)(b * SS + kn + vkey) * ldq + h * DHD + vd;
            vr = *(const u16x8*)(vp);
        }

        // wave-uniform causal skip: all keys in this tile > all rows of wave
        const bool active = !causal || (q0w + 15 >= kcol0);
        // per-score check needed only when tile straddles the diagonal
        const bool diag = causal && (kcol0 + 63 > q0w);

        f32x4 s[4] = {};
        if (active) {
#pragma unroll
            for (int fi = 0; fi < 4; ++fi) {
                bf16x8 kf0 = __builtin_bit_cast(bf16x8, *(const u16x8*)(&KPs[(fi * 16 + lr) * AST + lg * 8]));
                bf16x8 kf1 = __builtin_bit_cast(bf16x8, *(const u16x8*)(&KPs[(fi * 16 + lr) * AST + 32 + lg * 8]));
                s[fi] = __builtin_amdgcn_mfma_f32_16x16x32_bf16(qf[0], kf0, s[fi], 0, 0, 0);
                s[fi] = __builtin_amdgcn_mfma_f32_16x16x32_bf16(qf[1], kf1, s[fi], 0, 0, 0);
            }
        }
        __syncthreads();   // K tile fully consumed; safe to overwrite with P

        if (active) {
            float biasf[4];
#pragma unroll
            for (int fi = 0; fi < 4; ++fi)
                biasf[fi] = kmask[b * SS + kcol0 + fi * 16 + lr] ? 0.0f : -INFINITY;

#pragma unroll
            for (int r = 0; r < 4; ++r) {
                const int qrow = q0w + lg * 4 + r;
                u16x4 pk;
                float rs = 0.0f;
#pragma unroll
                for (int fi = 0; fi < 4; ++fi) {
                    float v = fmaf(s[fi][r], CSC, biasf[fi]);
                    if (diag) {
                        const int key = kcol0 + fi * 16 + lr;
                        v = (key <= qrow) ? v : -INFINITY;
                    }
                    const float pv = exp2f(v);   // 0 for masked
                    pk[fi] = f2bf(pv);
                    rs += pv;
                }
                lsum[r] += rs;
                *(u16x4*)(&KPs[(w * 16 + lg * 4 + r) * AST + lr * 4]) = pk;
            }

            // PV: A = own wave's P strip, B = Vt (both k-permuted identically)
#pragma unroll
            for (int kk = 0; kk < 2; ++kk) {
                bf16x8 pf = __builtin_bit_cast(bf16x8, *(const u16x8*)(&KPs[(w * 16 + lr) * AST + kk * 32 + lg * 8]));
#pragma unroll
                for (int di = 0; di < 4; ++di) {
                    bf16x8 vf = __builtin_bit_cast(bf16x8, *(const u16x8*)(&Vt[(di * 16 + lr) * AST + kk * 32 + lg * 8]));
                    acc[di] = __builtin_amdgcn_mfma_f32_16x16x32_bf16(pf, vf, acc[di], 0, 0, 0);
                }
            }
        }
    }

    // one l-reduction for the whole kernel
#pragma unroll
    for (int r = 0; r < 4; ++r) {
        float l = lsum[r];
        l += __shfl_xor(l, 1);
        l += __shfl_xor(l, 2);
        l += __shfl_xor(l, 4);
        l += __shfl_xor(l, 8);
        const float inv = (l > 0.0f) ? (1.0f / l) : 0.0f;
        const size_t orow = (size_t)(b * SS + q0w + lg * 4 + r) * DD + h * DHD;
#pragma unroll
        for (int di = 0; di < 4; ++di)
            O[orow + di * 16 + lr] = f2bf(acc[di][r] * inv);
    }
}

// ---------------------------------------------------------------------------
// LayerNorm over last dim (768); nullable fp32 out / bf16 out.
// ---------------------------------------------------------------------------
__global__ __launch_bounds__(256) void ln_kernel(
    const float* __restrict__ X, const float* __restrict__ gma,
    const float* __restrict__ bta, float* __restrict__ Y, u16* __restrict__ Ybf)
{
    const int row = blockIdx.x;
    const int tid = threadIdx.x;
    const float* x = X + (size_t)row * DD;

    const float v0 = x[tid], v1 = x[tid + 256], v2 = x[tid + 512];

    __shared__ float sd[256];
    sd[tid] = v0 + v1 + v2;
    __syncthreads();
    for (int off = 128; off > 0; off >>= 1) {
        if (tid < off) sd[tid] += sd[tid + off];
        __syncthreads();
    }
    const float mean = sd[0] * (1.0f / 768.0f);
    __syncthreads();

    const float q0 = v0 - mean, q1 = v1 - mean, q2 = v2 - mean;
    sd[tid] = q0 * q0 + q1 * q1 + q2 * q2;
    __syncthreads();
    for (int off = 128; off > 0; off >>= 1) {
        if (tid < off) sd[tid] += sd[tid + off];
        __syncthreads();
    }
    const float var = sd[0] * (1.0f / 768.0f);
    const float inv = rsqrtf(var + 1e-5f);

    const float y0 = q0 * inv * gma[tid]       + bta[tid];
    const float y1 = q1 * inv * gma[tid + 256] + bta[tid + 256];
    const float y2 = q2 * inv * gma[tid + 512] + bta[tid + 512];
    if (Y) {
        float* y = Y + (size_t)row * DD;
        y[tid] = y0; y[tid + 256] = y1; y[tid + 512] = y2;
    }
    if (Ybf) {
        u16* yb = Ybf + (size_t)row * DD;
        yb[tid] = f2bf(y0); yb[tid + 256] = f2bf(y1); yb[tid + 512] = f2bf(y2);
    }
}

// ---------------------------------------------------------------------------
// LayerNorm over (C0 + C1 + bias + resid_bf16): split-K reduce fused in.
// ---------------------------------------------------------------------------
__global__ __launch_bounds__(256) void ln_red_kernel(
    const float* __restrict__ C0, const float* __restrict__ C1,
    const float* __restrict__ bias, const u16* __restrict__ resid,
    const float* __restrict__ gma, const float* __restrict__ bta,
    float* __restrict__ Y)
{
    const int row = blockIdx.x;
    const int tid = threadIdx.x;
    const size_t base = (size_t)row * DD;

    float v[3];
#pragma unroll
    for (int j = 0; j < 3; ++j) {
        const int i = tid + j * 256;
        v[j] = C0[base + i] + C1[base + i] + bias[i] + bf2f(resid[base + i]);
    }

    __shared__ float sd[256];
    sd[tid] = v[0] + v[1] + v[2];
    __syncthreads();
    for (int off = 128; off > 0; off >>= 1) {
        if (tid < off) sd[tid] += sd[tid + off];
        __syncthreads();
    }
    const float mean = sd[0] * (1.0f / 768.0f);
    __syncthreads();

    float q[3];
#pragma unroll
    for (int j = 0; j < 3; ++j) q[j] = v[j] - mean;
    sd[tid] = q[0] * q[0] + q[1] * q[1] + q[2] * q[2];
    __syncthreads();
    for (int off = 128; off > 0; off >>= 1) {
        if (tid < off) sd[tid] += sd[tid + off];
        __syncthreads();
    }
    const float var = sd[0] * (1.0f / 768.0f);
    const float inv = rsqrtf(var + 1e-5f);

    float* y = Y + base;
#pragma unroll
    for (int j = 0; j < 3; ++j) {
        const int i = tid + j * 256;
        y[i] = q[j] * inv * gma[i] + bta[i];
    }
}

// ---------------------------------------------------------------------------
extern "C" void kernel_launch(void* const* d_in, const int* in_sizes, int n_in,
                              void* d_out, int out_size, void* d_ws, size_t ws_size,
                              hipStream_t stream)
{
    (void)in_sizes; (void)n_in; (void)out_size; (void)ws_size;

    const float* key_enc   = (const float*)d_in[0];
    const float* value_enc = (const float*)d_in[1];
    const float* x         = (const float*)d_in[2];
    const int*   src_mask  = (const int*)d_in[3];
    const int*   tgt_mask  = (const int*)d_in[4];
    const float* Wq_m = (const float*)d_in[5];
    const float* Wk_m = (const float*)d_in[6];
    const float* Wv_m = (const float*)d_in[7];
    const float* Wo_m = (const float*)d_in[8];
    const float* Wq_c = (const float*)d_in[9];
    const float* Wk_c = (const float*)d_in[10];
    const float* Wv_c = (const float*)d_in[11];
    const float* Wo_c = (const float*)d_in[12];
    const float* ln1_g = (const float*)d_in[13];
    const float* ln1_b = (const float*)d_in[14];
    const float* ln2_g = (const float*)d_in[15];
    const float* ln2_b = (const float*)d_in[16];
    const float* ln3_g = (const float*)d_in[17];
    const float* ln3_b = (const float*)d_in[18];
    const float* W1 = (const float*)d_in[19];
    const float* b1 = (const float*)d_in[20];
    const float* W2 = (const float*)d_in[21];
    const float* b2 = (const float*)d_in[22];

    float* out = (float*)d_out;

    // workspace layout
    const size_t ACT = (size_t)MROWS * DD;
    const size_t WP  = (size_t)DD * DD;
    char* p = (char*)d_ws;
    u16* QKV  = (u16*)p;   p += 3 * ACT * 2;
    u16* BFx  = (u16*)p;   p += ACT * 2;
    u16* BFK  = (u16*)p;   p += ACT * 2;
    u16* BFV  = (u16*)p;   p += ACT * 2;
    u16* BF1a = (u16*)p;   p += ACT * 2;
    u16* BF1h = (u16*)p;   p += ACT * 2;
    float* T2 = (float*)p; p += ACT * 4;   // pre-LN fp32 / split-K partial 0
    float* T2b = (float*)p; p += ACT * 4;  // split-K partial 1
    u16* Wm6  = (u16*)p;   p += 6 * WP * 2;
    u16* Wom_t = (u16*)p;  p += WP * 2;
    u16* Woc_t = (u16*)p;  p += WP * 2;
    u16* W1t  = (u16*)p;   p += (size_t)DD * FF * 2;
    u16* W2t  = (u16*)p;   p += (size_t)DD * FF * 2;
    u16* MID  = QKV;   // [4096][3072] bf16 aliases QKV+BFx (dead by MLP)

    const dim3 blk(256);
    const dim3 blkA(512);
    const int nc4 = (int)(ACT / 4);

    cvt3_kernel<<<dim3(nc4 / 256, 1, 3), blk, 0, stream>>>(
        x, key_enc, value_enc, BFx, BFK, BFV, nc4);
    tcvt6_kernel<<<dim3(2, 24, 72), blk, 0, stream>>>(
        Wq_m, Wk_m, Wv_m, Wq_c, Wk_c, Wv_c, Wm6);
    tcvt_kernel<<<dim3(24, 24, 1), blk, 0, stream>>>(Wo_m, Wom_t, DD, DD);
    tcvt_kernel<<<dim3(24, 24, 1), blk, 0, stream>>>(Wo_c, Woc_t, DD, DD);
    tcvt_kernel<<<dim3(96, 24, 1), blk, 0, stream>>>(W1, W1t, DD, FF);
    tcvt_kernel<<<dim3(24, 96, 1), blk, 0, stream>>>(W2, W2t, FF, DD);

    const dim3 gQKV(18, 32);      // 128x128: N=2304
    const dim3 gP(6, 64);         // 64x128 skinny
    const dim3 gP3(6, 32, 3);     // 128x128 cross projections
    const dim3 gM1(24, 32);       // 128x128: N=3072
    const dim3 gM2(6, 64, 2);     // MLP2 split-K
    const dim3 gAttn(8, BB * HH); // 128-query tiles

    // Self-attention
    gemm128<<<gQKV, blk, 0, stream>>>(BFx, Wm6, DD, nullptr, 0, QKV, 3 * DD);
    attn_mfma_kernel<<<gAttn, blkA, 0, stream>>>(QKV, QKV + DD, QKV + 2 * DD, 3 * DD,
                                                 tgt_mask, BF1a, 1);
    gemm64<<<gP, blk, 0, stream>>>(BF1a, Wom_t, DD, DD,
                                   nullptr, x, nullptr,
                                   T2, nullptr, DD, 0);
    ln_kernel<<<MROWS, blk, 0, stream>>>(T2, ln1_g, ln1_b, nullptr, BF1h);

    // Cross-attention
    gemm128_qkv3<<<gP3, blk, 0, stream>>>(BF1h, BFK, BFV,
                                          Wm6 + 3 * WP, Wm6 + 4 * WP, Wm6 + 5 * WP,
                                          QKV, 3 * DD);
    attn_mfma_kernel<<<gAttn, blkA, 0, stream>>>(QKV, QKV + DD, QKV + 2 * DD, 3 * DD,
                                                 src_mask, BF1a, 0);
    gemm64<<<gP, blk, 0, stream>>>(BF1a, Woc_t, DD, DD,
                                   nullptr, nullptr, BF1h,
                                   T2, nullptr, DD, 0);
    ln_kernel<<<MROWS, blk, 0, stream>>>(T2, ln2_g, ln2_b, nullptr, BF1h);

    // MLP
    gemm128<<<gM1, blk, 0, stream>>>(BF1h, W1t, DD, b1, 1, MID, FF);
    gemm64_sk<<<gM2, blk, 0, stream>>>(MID, W2t, DD, FF, FF / 2, T2);
    ln_red_kernel<<<MROWS, blk, 0, stream>>>(T2, T2b, b2, BF1h,
                                             ln3_g, ln3_b, out);
}

// Round 17
// 328.123 us; speedup vs baseline: 1.0287x; 1.0287x over previous
//
#include <hip/hip_runtime.h>
#include <math.h>

// Problem constants
#define BB 4
#define SS 1024
#define DD 768
#define HH 12
#define DHD 64
#define MROWS 4096
#define FF 3072
#define WPC (DD * DD)          // 589824, per-weight stride in Wm6

typedef unsigned short u16;
typedef float f32x4 __attribute__((ext_vector_type(4)));
typedef __bf16 bf16x8 __attribute__((ext_vector_type(8)));
typedef unsigned short u16x8 __attribute__((ext_vector_type(8)));
typedef unsigned short u16x4 __attribute__((ext_vector_type(4)));

static __device__ __forceinline__ float bf2f(u16 u) {
    union { unsigned int i; float f; } c; c.i = ((unsigned int)u) << 16; return c.f;
}
static __device__ __forceinline__ u16 f2bf(float f) {
    return __builtin_bit_cast(u16, static_cast<__bf16>(f));
}

#define LDST 40

// ---------------------------------------------------------------------------
// 128x128-tile bf16 MFMA GEMM core. 4 waves (2x2), each 64x64 = 4x4 frags,
// BK=32, depth-2 prefetch via explicit 2-step unroll. K % 64 == 0.
// ---------------------------------------------------------------------------
static __device__ __forceinline__ void gemm128_core(
    const u16* __restrict__ A, const u16* __restrict__ Bt,
    int K,
    const float* __restrict__ bias, int do_gelu,
    u16* __restrict__ Cbf, int ldcbf, int cboff,
    int row0, int col0, u16* As, u16* Bs)
{
    const int tid  = threadIdx.x;
    const int lane = tid & 63;
    const int w    = tid >> 6;
    const int wm = (w >> 1) * 64;
    const int wn = (w & 1) * 64;

    const int srow = tid >> 1;
    const int skc  = (tid & 1) * 16;

    const u16* Ap = A  + (size_t)(row0 + srow) * K + skc;
    const u16* Bp = Bt + (size_t)(col0 + srow) * K + skc;
    u16* AsW = &As[srow * LDST + skc];
    u16* BsW = &Bs[srow * LDST + skc];

    const int fr = lane & 15;
    const int fk = (lane >> 4) * 8;

    f32x4 acc[4][4] = {};

    u16x8 aa0, aa1, ba0, ba1;
    u16x8 ab0, ab1, bb0, bb1;
    aa0 = *(const u16x8*)(Ap);
    aa1 = *(const u16x8*)(Ap + 8);
    ba0 = *(const u16x8*)(Bp);
    ba1 = *(const u16x8*)(Bp + 8);
    ab0 = *(const u16x8*)(Ap + 32);
    ab1 = *(const u16x8*)(Ap + 40);
    bb0 = *(const u16x8*)(Bp + 32);
    bb1 = *(const u16x8*)(Bp + 40);

    for (int k0 = 0; k0 < K; k0 += 64) {
        if (k0) __syncthreads();
        *(u16x8*)(AsW)     = aa0;
        *(u16x8*)(AsW + 8) = aa1;
        *(u16x8*)(BsW)     = ba0;
        *(u16x8*)(BsW + 8) = ba1;
        __syncthreads();
        if (k0 + 64 < K) {
            aa0 = *(const u16x8*)(Ap + k0 + 64);
            aa1 = *(const u16x8*)(Ap + k0 + 72);
            ba0 = *(const u16x8*)(Bp + k0 + 64);
            ba1 = *(const u16x8*)(Bp + k0 + 72);
        }
        {
            bf16x8 af[4], bfv[4];
#pragma unroll
            for (int mi = 0; mi < 4; ++mi)
                af[mi] = __builtin_bit_cast(bf16x8,
                    *(const u16x8*)(&As[(wm + 16 * mi + fr) * LDST + fk]));
#pragma unroll
            for (int ni = 0; ni < 4; ++ni)
                bfv[ni] = __builtin_bit_cast(bf16x8,
                    *(const u16x8*)(&Bs[(wn + 16 * ni + fr) * LDST + fk]));
#pragma unroll
            for (int mi = 0; mi < 4; ++mi)
#pragma unroll
                for (int ni = 0; ni < 4; ++ni)
                    acc[mi][ni] = __builtin_amdgcn_mfma_f32_16x16x32_bf16(
                        af[mi], bfv[ni], acc[mi][ni], 0, 0, 0);
        }

        __syncthreads();
        *(u16x8*)(AsW)     = ab0;
        *(u16x8*)(AsW + 8) = ab1;
        *(u16x8*)(BsW)     = bb0;
        *(u16x8*)(BsW + 8) = bb1;
        __syncthreads();
        if (k0 + 96 < K) {
            ab0 = *(const u16x8*)(Ap + k0 + 96);
            ab1 = *(const u16x8*)(Ap + k0 + 104);
            bb0 = *(const u16x8*)(Bp + k0 + 96);
            bb1 = *(const u16x8*)(Bp + k0 + 104);
        }
        {
            bf16x8 af[4], bfv[4];
#pragma unroll
            for (int mi = 0; mi < 4; ++mi)
                af[mi] = __builtin_bit_cast(bf16x8,
                    *(const u16x8*)(&As[(wm + 16 * mi + fr) * LDST + fk]));
#pragma unroll
            for (int ni = 0; ni < 4; ++ni)
                bfv[ni] = __builtin_bit_cast(bf16x8,
                    *(const u16x8*)(&Bs[(wn + 16 * ni + fr) * LDST + fk]));
#pragma unroll
            for (int mi = 0; mi < 4; ++mi)
#pragma unroll
                for (int ni = 0; ni < 4; ++ni)
                    acc[mi][ni] = __builtin_amdgcn_mfma_f32_16x16x32_bf16(
                        af[mi], bfv[ni], acc[mi][ni], 0, 0, 0);
        }
    }

    const int orow0 = row0 + wm + (lane >> 4) * 4;
    const int ocol0 = col0 + wn + fr;
#pragma unroll
    for (int mi = 0; mi < 4; ++mi) {
#pragma unroll
        for (int ni = 0; ni < 4; ++ni) {
            const int col = ocol0 + ni * 16;
            const float bv = bias ? bias[col] : 0.0f;
#pragma unroll
            for (int r = 0; r < 4; ++r) {
                const int row = orow0 + mi * 16 + r;
                float v = acc[mi][ni][r] + bv;
                if (do_gelu) v = 0.5f * v * (1.0f + erff(v * 0.70710678118654752f));
                Cbf[(size_t)row * ldcbf + cboff + col] = f2bf(v);
            }
        }
    }
}

__global__ __launch_bounds__(256) void gemm128(
    const u16* __restrict__ A, const u16* __restrict__ Bt, int K,
    const float* __restrict__ bias, int do_gelu,
    u16* __restrict__ Cbf, int ldcbf)
{
    __shared__ u16 As[128 * LDST];
    __shared__ u16 Bs[128 * LDST];
    gemm128_core(A, Bt, K, bias, do_gelu, Cbf, ldcbf, 0,
                 blockIdx.y * 128, blockIdx.x * 128, As, Bs);
}

// Batched independent projections (flat 960-block grid):
//   fid [0,576):   self QKV:  BFx @ Wm6[0..3WP)  -> QKV  (ld 2304, coff 0)
//   fid [576,768): cross K:   BFK @ Wm6[4WP..)   -> KVc  (ld 1536, coff 0)
//   fid [768,960): cross V:   BFV @ Wm6[5WP..)   -> KVc  (ld 1536, coff 768)
__global__ __launch_bounds__(256) void gemm128_proj(
    const u16* __restrict__ BFx, const u16* __restrict__ BFK,
    const u16* __restrict__ BFV, const u16* __restrict__ Wm6,
    u16* __restrict__ QKV, u16* __restrict__ KVc)
{
    __shared__ u16 As[128 * LDST];
    __shared__ u16 Bs[128 * LDST];
    const int fid = blockIdx.x;
    const u16* A; const u16* B; u16* C; int ldc, coff, row0, col0;
    if (fid < 576) {
        A = BFx; B = Wm6; C = QKV; ldc = 3 * DD; coff = 0;
        row0 = (fid / 18) * 128; col0 = (fid % 18) * 128;
    } else if (fid < 768) {
        const int l = fid - 576;
        A = BFK; B = Wm6 + 4 * WPC; C = KVc; ldc = 2 * DD; coff = 0;
        row0 = (l / 6) * 128; col0 = (l % 6) * 128;
    } else {
        const int l = fid - 768;
        A = BFV; B = Wm6 + 5 * WPC; C = KVc; ldc = 2 * DD; coff = DD;
        row0 = (l / 6) * 128; col0 = (l % 6) * 128;
    }
    gemm128_core(A, B, DD, nullptr, 0, C, ldc, coff, row0, col0, As, Bs);
}

// ---------------------------------------------------------------------------
// 64x128-tile GEMM (skinny launches: Wo x2, MLP2 split-K). Depth-2 unroll.
// ---------------------------------------------------------------------------
static __device__ __forceinline__ void gemm64_core(
    const u16* __restrict__ A, const u16* __restrict__ Bt,
    int N, int Kstride, int Klen,
    const float* __restrict__ bias,
    const float* __restrict__ residf, const u16* __restrict__ residb,
    float* __restrict__ C, u16* __restrict__ Cbf, int ldcbf, int cboff,
    int do_gelu, int row0, int col0, u16* As, u16* Bs)
{
    const int tid  = threadIdx.x;
    const int lane = tid & 63;
    const int w    = tid >> 6;
    const int wm = (w >> 1) * 32;
    const int wn = (w & 1) * 64;

    const int arow = tid >> 2;
    const int akc  = (tid & 3) * 8;
    const int brow = tid >> 1;
    const int bkc  = (tid & 1) * 16;

    const u16* Ap = A  + (size_t)(row0 + arow) * Kstride + akc;
    const u16* Bp = Bt + (size_t)(col0 + brow) * Kstride + bkc;
    u16* AsW = &As[arow * LDST + akc];
    u16* BsW = &Bs[brow * LDST + bkc];

    const int fr = lane & 15;
    const int fk = (lane >> 4) * 8;

    f32x4 acc[2][4] = {};

    u16x8 a0, b00, b01, a1, b10, b11;
    a0  = *(const u16x8*)(Ap);
    b00 = *(const u16x8*)(Bp);
    b01 = *(const u16x8*)(Bp + 8);
    a1  = *(const u16x8*)(Ap + 32);
    b10 = *(const u16x8*)(Bp + 32);
    b11 = *(const u16x8*)(Bp + 40);

    for (int k0 = 0; k0 < Klen; k0 += 64) {
        if (k0) __syncthreads();
        *(u16x8*)AsW       = a0;
        *(u16x8*)BsW       = b00;
        *(u16x8*)(BsW + 8) = b01;
        __syncthreads();
        if (k0 + 64 < Klen) {
            a0  = *(const u16x8*)(Ap + k0 + 64);
            b00 = *(const u16x8*)(Bp + k0 + 64);
            b01 = *(const u16x8*)(Bp + k0 + 72);
        }
        {
            bf16x8 af[2], bfv[4];
#pragma unroll
            for (int mi = 0; mi < 2; ++mi)
                af[mi] = __builtin_bit_cast(bf16x8,
                    *(const u16x8*)(&As[(wm + 16 * mi + fr) * LDST + fk]));
#pragma unroll
            for (int ni = 0; ni < 4; ++ni)
                bfv[ni] = __builtin_bit_cast(bf16x8,
                    *(const u16x8*)(&Bs[(wn + 16 * ni + fr) * LDST + fk]));
#pragma unroll
            for (int mi = 0; mi < 2; ++mi)
#pragma unroll
                for (int ni = 0; ni < 4; ++ni)
                    acc[mi][ni] = __builtin_amdgcn_mfma_f32_16x16x32_bf16(
                        af[mi], bfv[ni], acc[mi][ni], 0, 0, 0);
        }

        __syncthreads();
        *(u16x8*)AsW       = a1;
        *(u16x8*)BsW       = b10;
        *(u16x8*)(BsW + 8) = b11;
        __syncthreads();
        if (k0 + 96 < Klen) {
            a1  = *(const u16x8*)(Ap + k0 + 96);
            b10 = *(const u16x8*)(Bp + k0 + 96);
            b11 = *(const u16x8*)(Bp + k0 + 104);
        }
        {
            bf16x8 af[2], bfv[4];
#pragma unroll
            for (int mi = 0; mi < 2; ++mi)
                af[mi] = __builtin_bit_cast(bf16x8,
                    *(const u16x8*)(&As[(wm + 16 * mi + fr) * LDST + fk]));
#pragma unroll
            for (int ni = 0; ni < 4; ++ni)
                bfv[ni] = __builtin_bit_cast(bf16x8,
                    *(const u16x8*)(&Bs[(wn + 16 * ni + fr) * LDST + fk]));
#pragma unroll
            for (int mi = 0; mi < 2; ++mi)
#pragma unroll
                for (int ni = 0; ni < 4; ++ni)
                    acc[mi][ni] = __builtin_amdgcn_mfma_f32_16x16x32_bf16(
                        af[mi], bfv[ni], acc[mi][ni], 0, 0, 0);
        }
    }

    const int orow0 = row0 + wm + (lane >> 4) * 4;
    const int ocol0 = col0 + wn + fr;
#pragma unroll
    for (int mi = 0; mi < 2; ++mi) {
#pragma unroll
        for (int ni = 0; ni < 4; ++ni) {
            const int col = ocol0 + ni * 16;
            const float bv = bias ? bias[col] : 0.0f;
#pragma unroll
            for (int r = 0; r < 4; ++r) {
                const int row = orow0 + mi * 16 + r;
                float v = acc[mi][ni][r] + bv;
                if (do_gelu) v = 0.5f * v * (1.0f + erff(v * 0.70710678118654752f));
                if (residf) v += residf[(size_t)row * N + col];
                if (residb) v += bf2f(residb[(size_t)row * N + col]);
                if (C)   C[(size_t)row * N + col] = v;
                if (Cbf) Cbf[(size_t)row * ldcbf + cboff + col] = f2bf(v);
            }
        }
    }
}

__global__ __launch_bounds__(256) void gemm64(
    const u16* __restrict__ A, const u16* __restrict__ Bt, int N, int K,
    const float* __restrict__ bias,
    const float* __restrict__ residf, const u16* __restrict__ residb,
    float* __restrict__ C, u16* __restrict__ Cbf, int ldcbf, int do_gelu)
{
    __shared__ u16 As[64 * LDST];
    __shared__ u16 Bs[128 * LDST];
    gemm64_core(A, Bt, N, K, K, bias, residf, residb, C, Cbf, ldcbf, 0, do_gelu,
                blockIdx.y * 64, blockIdx.x * 128, As, Bs);
}

__global__ __launch_bounds__(256) void gemm64_sk(
    const u16* __restrict__ A, const u16* __restrict__ Bt, int N, int Kstride,
    int Klen, float* __restrict__ Cpair)
{
    __shared__ u16 As[64 * LDST];
    __shared__ u16 Bs[128 * LDST];
    const int z = blockIdx.z;
    const int koff = z * Klen;
    gemm64_core(A + koff, Bt + koff, N, Kstride, Klen,
                nullptr, nullptr, nullptr,
                Cpair + (size_t)z * MROWS * N, nullptr, 0, 0, 0,
                blockIdx.y * 64, blockIdx.x * 128, As, Bs);
}

// ---------------------------------------------------------------------------
// Weight transposes (fp32 -> bf16, [K,N] -> [N,K])
// ---------------------------------------------------------------------------
static __device__ __forceinline__ void tcvt_body(
    const float* __restrict__ in, u16* __restrict__ out,
    int K, int N, int bx, int by)
{
    __shared__ float t[32][33];
    const int n0 = bx * 32, k0 = by * 32;
    const int tx = threadIdx.x & 31, ty = threadIdx.x >> 5;
#pragma unroll
    for (int j = 0; j < 4; ++j)
        t[ty + j * 8][tx] = in[(size_t)(k0 + ty + j * 8) * N + n0 + tx];
    __syncthreads();
#pragma unroll
    for (int j = 0; j < 4; ++j)
        out[(size_t)(n0 + ty + j * 8) * K + k0 + tx] = f2bf(t[tx][ty + j * 8]);
}

// Six per-head weights [12,768,64] -> stacked [768,768] each in Wm6.
__global__ __launch_bounds__(256) void tcvt6_kernel(
    const float* __restrict__ w0, const float* __restrict__ w1,
    const float* __restrict__ w2, const float* __restrict__ w3,
    const float* __restrict__ w4, const float* __restrict__ w5,
    u16* __restrict__ Wm6)
{
    __shared__ float t[32][33];
    const int z = blockIdx.z;
    const int wi = z / 12, head = z % 12;
    const float* wsel = (wi == 0) ? w0 : (wi == 1) ? w1 : (wi == 2) ? w2 :
                        (wi == 3) ? w3 : (wi == 4) ? w4 : w5;
    const float* ib = wsel + (size_t)head * DD * DHD;
    u16* ob = Wm6 + (size_t)wi * WPC + (size_t)head * DHD * DD;
    const int n0 = blockIdx.x * 32, k0 = blockIdx.y * 32;
    const int tx = threadIdx.x & 31, ty = threadIdx.x >> 5;
#pragma unroll
    for (int j = 0; j < 4; ++j)
        t[ty + j * 8][tx] = ib[(size_t)(k0 + ty + j * 8) * DHD + n0 + tx];
    __syncthreads();
#pragma unroll
    for (int j = 0; j < 4; ++j)
        ob[(size_t)(n0 + ty + j * 8) * DD + k0 + tx] = f2bf(t[tx][ty + j * 8]);
}

// Wo_m, Wo_c, W1, W2 in ONE flattened launch (5760 blocks).
__global__ __launch_bounds__(256) void tcvt4_kernel(
    const float* __restrict__ wom, const float* __restrict__ woc,
    const float* __restrict__ w1, const float* __restrict__ w2,
    u16* __restrict__ womt, u16* __restrict__ woct,
    u16* __restrict__ w1t, u16* __restrict__ w2t)
{
    const int fid = blockIdx.x;
    if (fid < 576) {
        tcvt_body(wom, womt, DD, DD, fid % 24, fid / 24);
    } else if (fid < 1152) {
        const int l = fid - 576;
        tcvt_body(woc, woct, DD, DD, l % 24, l / 24);
    } else if (fid < 3456) {
        const int l = fid - 1152;
        tcvt_body(w1, w1t, DD, FF, l % 96, l / 96);
    } else {
        const int l = fid - 3456;
        tcvt_body(w2, w2t, FF, DD, l % 24, l / 24);
    }
}

__global__ __launch_bounds__(256) void cvt3_kernel(
    const float* __restrict__ s0, const float* __restrict__ s1,
    const float* __restrict__ s2,
    u16* __restrict__ d0, u16* __restrict__ d1, u16* __restrict__ d2, int n4)
{
    const int z = blockIdx.z;
    const float* s = (z == 0) ? s0 : (z == 1) ? s1 : s2;
    u16* d = (z == 0) ? d0 : (z == 1) ? d1 : d2;
    const int i = blockIdx.x * 256 + threadIdx.x;
    if (i < n4) {
        float4 v = ((const float4*)s)[i];
        ushort4 o;
        o.x = f2bf(v.x); o.y = f2bf(v.y); o.z = f2bf(v.z); o.w = f2bf(v.w);
        ((ushort4*)d)[i] = o;
    }
}

// ---------------------------------------------------------------------------
// MFMA flash attention, max-free exp2 softmax (validated R11/R14 config:
// 256 threads, 64-query tile). Separate ldq / ldkv.
// ---------------------------------------------------------------------------
#define AST 72
#define CSC 0.18033688011112042f   // 0.125 * log2(e)
__global__ __launch_bounds__(256) void attn_mfma_kernel(
    const u16* __restrict__ Q, int ldq,
    const u16* __restrict__ K, const u16* __restrict__ V, int ldkv,
    const int* __restrict__ kmask, u16* __restrict__ O, int causal)
{
    const int qt = causal ? ((int)gridDim.x - 1 - (int)blockIdx.x) : (int)blockIdx.x;
    const int bh = blockIdx.y;
    const int b  = bh / HH;
    const int h  = bh % HH;
    const int tid  = threadIdx.x;
    const int lane = tid & 63;
    const int w    = tid >> 6;
    const int lr = lane & 15;
    const int lg = lane >> 4;

    __shared__ u16 KPs[64 * AST];   // K tile; overwritten by P after QK^T
    __shared__ u16 Vt[64 * AST];

    const int row0 = qt * 64;
    const int q0w  = row0 + w * 16;

    bf16x8 qf[2];
    {
        const u16* qp = Q + (size_t)(b * SS + q0w + lr) * ldq + h * DHD + lg * 8;
        qf[0] = __builtin_bit_cast(bf16x8, *(const u16x8*)(qp));
        qf[1] = __builtin_bit_cast(bf16x8, *(const u16x8*)(qp + 32));
    }

    const int sr = tid >> 2;
    const int sc = (tid & 3) * 16;
    const int vkey = lane;
    const int vj = ((vkey & 15) << 2) | (vkey >> 4);   // permuted k-column
    const int dw = w * 16;

    f32x4 acc[4] = {};
    float lsum[4] = {0.0f, 0.0f, 0.0f, 0.0f};

    const int nkt = causal ? (qt + 1) : 16;

    u16x8 kr0, kr1, vr0, vr1;
    {
        const u16* kp = K + (size_t)(b * SS + sr) * ldkv + h * DHD + sc;
        kr0 = *(const u16x8*)(kp);
        kr1 = *(const u16x8*)(kp + 8);
        const u16* vp = V + (size_t)(b * SS + vkey) * ldkv + h * DHD + dw;
        vr0 = *(const u16x8*)(vp);
        vr1 = *(const u16x8*)(vp + 8);
    }

    for (int kt = 0; kt < nkt; ++kt) {
        const int kcol0 = kt * 64;
        if (kt) __syncthreads();        // all PV reads of KPs/Vt done

        *(u16x8*)(&KPs[sr * AST + sc])     = kr0;
        *(u16x8*)(&KPs[sr * AST + sc + 8]) = kr1;
#pragma unroll
        for (int j = 0; j < 8; ++j) Vt[(dw + j) * AST + vj] = vr0[j];
#pragma unroll
        for (int j = 0; j < 8; ++j) Vt[(dw + 8 + j) * AST + vj] = vr1[j];
        __syncthreads();

        if (kt + 1 < nkt) {
            const int kn = kcol0 + 64;
            const u16* kp = K + (size_t)(b * SS + kn + sr) * ldkv + h * DHD + sc;
            kr0 = *(const u16x8*)(kp);
            kr1 = *(const u16x8*)(kp + 8);
            const u16* vp = V + (size_t)(b * SS + kn + vkey) * ldkv + h * DHD + dw;
            vr0 = *(const u16x8*)(vp);
            vr1 = *(const u16x8*)(vp + 8);
        }

        // QK^T (consumes K tile)
        f32x4 s[4] = {};
#pragma unroll
        for (int fi = 0; fi < 4; ++fi) {
            bf16x8 kf0 = __builtin_bit_cast(bf16x8, *(const u16x8*)(&KPs[(fi * 16 + lr) * AST + lg * 8]));
            bf16x8 kf1 = __builtin_bit_cast(bf16x8, *(const u16x8*)(&KPs[(fi * 16 + lr) * AST + 32 + lg * 8]));
            s[fi] = __builtin_amdgcn_mfma_f32_16x16x32_bf16(qf[0], kf0, s[fi], 0, 0, 0);
            s[fi] = __builtin_amdgcn_mfma_f32_16x16x32_bf16(qf[1], kf1, s[fi], 0, 0, 0);
        }
        __syncthreads();   // K tile fully consumed; safe to overwrite with P

        float biasf[4];
#pragma unroll
        for (int fi = 0; fi < 4; ++fi)
            biasf[fi] = kmask[b * SS + kcol0 + fi * 16 + lr] ? 0.0f : -INFINITY;
        const bool diag = (causal != 0) && (kt == qt);

#pragma unroll
        for (int r = 0; r < 4; ++r) {
            const int qrow = q0w + lg * 4 + r;
            u16x4 pk;
            float rs = 0.0f;
#pragma unroll
            for (int fi = 0; fi < 4; ++fi) {
                float v = fmaf(s[fi][r], CSC, biasf[fi]);
                if (diag) {
                    const int key = kcol0 + fi * 16 + lr;
                    v = (key <= qrow) ? v : -INFINITY;
                }
                const float pv = exp2f(v);   // 0 for masked
                pk[fi] = f2bf(pv);
                rs += pv;
            }
            lsum[r] += rs;
            *(u16x4*)(&KPs[(w * 16 + lg * 4 + r) * AST + lr * 4]) = pk;
        }

        // PV: A = own strip of KPs (P), B = Vt; both k-permuted identically
#pragma unroll
        for (int kk = 0; kk < 2; ++kk) {
            bf16x8 pf = __builtin_bit_cast(bf16x8, *(const u16x8*)(&KPs[(w * 16 + lr) * AST + kk * 32 + lg * 8]));
#pragma unroll
            for (int di = 0; di < 4; ++di) {
                bf16x8 vf = __builtin_bit_cast(bf16x8, *(const u16x8*)(&Vt[(di * 16 + lr) * AST + kk * 32 + lg * 8]));
                acc[di] = __builtin_amdgcn_mfma_f32_16x16x32_bf16(pf, vf, acc[di], 0, 0, 0);
            }
        }
    }

    // one l-reduction for the whole kernel
#pragma unroll
    for (int r = 0; r < 4; ++r) {
        float l = lsum[r];
        l += __shfl_xor(l, 1);
        l += __shfl_xor(l, 2);
        l += __shfl_xor(l, 4);
        l += __shfl_xor(l, 8);
        const float inv = (l > 0.0f) ? (1.0f / l) : 0.0f;
        const size_t orow = (size_t)(b * SS + q0w + lg * 4 + r) * DD + h * DHD;
#pragma unroll
        for (int di = 0; di < 4; ++di)
            O[orow + di * 16 + lr] = f2bf(acc[di][r] * inv);
    }
}

// ---------------------------------------------------------------------------
// LayerNorm over last dim (768); nullable fp32 out / bf16 out.
// ---------------------------------------------------------------------------
__global__ __launch_bounds__(256) void ln_kernel(
    const float* __restrict__ X, const float* __restrict__ gma,
    const float* __restrict__ bta, float* __restrict__ Y, u16* __restrict__ Ybf)
{
    const int row = blockIdx.x;
    const int tid = threadIdx.x;
    const float* x = X + (size_t)row * DD;

    const float v0 = x[tid], v1 = x[tid + 256], v2 = x[tid + 512];

    __shared__ float sd[256];
    sd[tid] = v0 + v1 + v2;
    __syncthreads();
    for (int off = 128; off > 0; off >>= 1) {
        if (tid < off) sd[tid] += sd[tid + off];
        __syncthreads();
    }
    const float mean = sd[0] * (1.0f / 768.0f);
    __syncthreads();

    const float q0 = v0 - mean, q1 = v1 - mean, q2 = v2 - mean;
    sd[tid] = q0 * q0 + q1 * q1 + q2 * q2;
    __syncthreads();
    for (int off = 128; off > 0; off >>= 1) {
        if (tid < off) sd[tid] += sd[tid + off];
        __syncthreads();
    }
    const float var = sd[0] * (1.0f / 768.0f);
    const float inv = rsqrtf(var + 1e-5f);

    const float y0 = q0 * inv * gma[tid]       + bta[tid];
    const float y1 = q1 * inv * gma[tid + 256] + bta[tid + 256];
    const float y2 = q2 * inv * gma[tid + 512] + bta[tid + 512];
    if (Y) {
        float* y = Y + (size_t)row * DD;
        y[tid] = y0; y[tid + 256] = y1; y[tid + 512] = y2;
    }
    if (Ybf) {
        u16* yb = Ybf + (size_t)row * DD;
        yb[tid] = f2bf(y0); yb[tid + 256] = f2bf(y1); yb[tid + 512] = f2bf(y2);
    }
}

// ---------------------------------------------------------------------------
// LayerNorm over (C0 + C1 + bias + resid_bf16): split-K reduce fused in.
// ---------------------------------------------------------------------------
__global__ __launch_bounds__(256) void ln_red_kernel(
    const float* __restrict__ C0, const float* __restrict__ C1,
    const float* __restrict__ bias, const u16* __restrict__ resid,
    const float* __restrict__ gma, const float* __restrict__ bta,
    float* __restrict__ Y)
{
    const int row = blockIdx.x;
    const int tid = threadIdx.x;
    const size_t base = (size_t)row * DD;

    float v[3];
#pragma unroll
    for (int j = 0; j < 3; ++j) {
        const int i = tid + j * 256;
        v[j] = C0[base + i] + C1[base + i] + bias[i] + bf2f(resid[base + i]);
    }

    __shared__ float sd[256];
    sd[tid] = v[0] + v[1] + v[2];
    __syncthreads();
    for (int off = 128; off > 0; off >>= 1) {
        if (tid < off) sd[tid] += sd[tid + off];
        __syncthreads();
    }
    const float mean = sd[0] * (1.0f / 768.0f);
    __syncthreads();

    float q[3];
#pragma unroll
    for (int j = 0; j < 3; ++j) q[j] = v[j] - mean;
    sd[tid] = q[0] * q[0] + q[1] * q[1] + q[2] * q[2];
    __syncthreads();
    for (int off = 128; off > 0; off >>= 1) {
        if (tid < off) sd[tid] += sd[tid + off];
        __syncthreads();
    }
    const float var = sd[0] * (1.0f / 768.0f);
    const float inv = rsqrtf(var + 1e-5f);

    float* y = Y + base;
#pragma unroll
    for (int j = 0; j < 3; ++j) {
        const int i = tid + j * 256;
        y[i] = q[j] * inv * gma[i] + bta[i];
    }
}

// ---------------------------------------------------------------------------
extern "C" void kernel_launch(void* const* d_in, const int* in_sizes, int n_in,
                              void* d_out, int out_size, void* d_ws, size_t ws_size,
                              hipStream_t stream)
{
    (void)in_sizes; (void)n_in; (void)out_size; (void)ws_size;

    const float* key_enc   = (const float*)d_in[0];
    const float* value_enc = (const float*)d_in[1];
    const float* x         = (const float*)d_in[2];
    const int*   src_mask  = (const int*)d_in[3];
    const int*   tgt_mask  = (const int*)d_in[4];
    const float* Wq_m = (const float*)d_in[5];
    const float* Wk_m = (const float*)d_in[6];
    const float* Wv_m = (const float*)d_in[7];
    const float* Wo_m = (const float*)d_in[8];
    const float* Wq_c = (const float*)d_in[9];
    const float* Wk_c = (const float*)d_in[10];
    const float* Wv_c = (const float*)d_in[11];
    const float* Wo_c = (const float*)d_in[12];
    const float* ln1_g = (const float*)d_in[13];
    const float* ln1_b = (const float*)d_in[14];
    const float* ln2_g = (const float*)d_in[15];
    const float* ln2_b = (const float*)d_in[16];
    const float* ln3_g = (const float*)d_in[17];
    const float* ln3_b = (const float*)d_in[18];
    const float* W1 = (const float*)d_in[19];
    const float* b1 = (const float*)d_in[20];
    const float* W2 = (const float*)d_in[21];
    const float* b2 = (const float*)d_in[22];

    float* out = (float*)d_out;

    // workspace layout
    const size_t ACT = (size_t)MROWS * DD;
    char* p = (char*)d_ws;
    u16* QKV  = (u16*)p;   p += 3 * ACT * 2;
    u16* BFx  = (u16*)p;   p += ACT * 2;
    u16* BFK  = (u16*)p;   p += ACT * 2;
    u16* BFV  = (u16*)p;   p += ACT * 2;
    u16* BF1a = (u16*)p;   p += ACT * 2;
    u16* BF1h = (u16*)p;   p += ACT * 2;
    float* T2 = (float*)p; p += ACT * 4;   // pre-LN fp32 / split-K partial 0
    float* T2b = (float*)p; p += ACT * 4;  // split-K partial 1 / cross-KV bf16
    u16* Wm6  = (u16*)p;   p += 6 * (size_t)WPC * 2;
    u16* Wom_t = (u16*)p;  p += (size_t)WPC * 2;
    u16* Woc_t = (u16*)p;  p += (size_t)WPC * 2;
    u16* W1t  = (u16*)p;   p += (size_t)DD * FF * 2;
    u16* W2t  = (u16*)p;   p += (size_t)DD * FF * 2;
    u16* MID  = QKV;       // [4096][3072] bf16 aliases QKV+BFx (dead by MLP)
    u16* KVc  = (u16*)T2b; // [4096][1536] bf16 cross K|V (dead by MLP2)

    const dim3 blk(256);
    const int nc4 = (int)(ACT / 4);

    // Prep (3 dispatches)
    cvt3_kernel<<<dim3(nc4 / 256, 1, 3), blk, 0, stream>>>(
        x, key_enc, value_enc, BFx, BFK, BFV, nc4);
    tcvt6_kernel<<<dim3(2, 24, 72), blk, 0, stream>>>(
        Wq_m, Wk_m, Wv_m, Wq_c, Wk_c, Wv_c, Wm6);
    tcvt4_kernel<<<dim3(5760), blk, 0, stream>>>(
        Wo_m, Wo_c, W1, W2, Wom_t, Woc_t, W1t, W2t);

    const dim3 gProj(960);        // self QKV + cross K/V batched
    const dim3 gQc(6, 32);        // cross Q only
    const dim3 gP(6, 64);         // 64x128 skinny (Wo)
    const dim3 gM1(24, 32);       // MLP1 128x128
    const dim3 gM2(6, 64, 2);     // MLP2 split-K
    const dim3 gAttn(16, BB * HH);

    // All input-independent projections in one launch
    gemm128_proj<<<gProj, blk, 0, stream>>>(BFx, BFK, BFV, Wm6, QKV, KVc);

    // Self-attention
    attn_mfma_kernel<<<gAttn, blk, 0, stream>>>(
        QKV, 3 * DD, QKV + DD, QKV + 2 * DD, 3 * DD, tgt_mask, BF1a, 1);
    gemm64<<<gP, blk, 0, stream>>>(BF1a, Wom_t, DD, DD,
                                   nullptr, x, nullptr,
                                   T2, nullptr, DD, 0);
    ln_kernel<<<MROWS, blk, 0, stream>>>(T2, ln1_g, ln1_b, nullptr, BF1h);

    // Cross-attention (K/V already in KVc)
    gemm128<<<gQc, blk, 0, stream>>>(BF1h, Wm6 + 3 * WPC, DD, nullptr, 0,
                                     QKV, 3 * DD);
    attn_mfma_kernel<<<gAttn, blk, 0, stream>>>(
        QKV, 3 * DD, KVc, KVc + DD, 2 * DD, src_mask, BF1a, 0);
    gemm64<<<gP, blk, 0, stream>>>(BF1a, Woc_t, DD, DD,
                                   nullptr, nullptr, BF1h,
                                   T2, nullptr, DD, 0);
    ln_kernel<<<MROWS, blk, 0, stream>>>(T2, ln2_g, ln2_b, nullptr, BF1h);

    // MLP
    gemm128<<<gM1, blk, 0, stream>>>(BF1h, W1t, DD, b1, 1, MID, FF);
    gemm64_sk<<<gM2, blk, 0, stream>>>(MID, W2t, DD, FF, FF / 2, T2);
    ln_red_kernel<<<MROWS, blk, 0, stream>>>(T2, T2b, b2, BF1h,
                                             ln3_g, ln3_b, out);
}

// Round 18
// 321.240 us; speedup vs baseline: 1.0507x; 1.0214x over previous
//
#include <hip/hip_runtime.h>
#include <math.h>

// Problem constants
#define BB 4
#define SS 1024
#define DD 768
#define HH 12
#define DHD 64
#define MROWS 4096
#define FF 3072
#define WPC (DD * DD)          // 589824, per-weight stride in Wm6

typedef unsigned short u16;
typedef float f32x4 __attribute__((ext_vector_type(4)));
typedef __bf16 bf16x8 __attribute__((ext_vector_type(8)));
typedef unsigned short u16x8 __attribute__((ext_vector_type(8)));
typedef unsigned short u16x4 __attribute__((ext_vector_type(4)));

static __device__ __forceinline__ float bf2f(u16 u) {
    union { unsigned int i; float f; } c; c.i = ((unsigned int)u) << 16; return c.f;
}
static __device__ __forceinline__ u16 f2bf(float f) {
    return __builtin_bit_cast(u16, static_cast<__bf16>(f));
}

#define LDST 40

// ---------------------------------------------------------------------------
// 128x128-tile bf16 MFMA GEMM core. 4 waves (2x2), each 64x64 = 4x4 frags,
// BK=32, depth-2 prefetch via explicit 2-step unroll. K % 64 == 0.
// ---------------------------------------------------------------------------
static __device__ __forceinline__ void gemm128_core(
    const u16* __restrict__ A, const u16* __restrict__ Bt,
    int K,
    const float* __restrict__ bias, int do_gelu,
    u16* __restrict__ Cbf, int ldcbf, int cboff,
    int row0, int col0, u16* As, u16* Bs)
{
    const int tid  = threadIdx.x;
    const int lane = tid & 63;
    const int w    = tid >> 6;
    const int wm = (w >> 1) * 64;
    const int wn = (w & 1) * 64;

    const int srow = tid >> 1;
    const int skc  = (tid & 1) * 16;

    const u16* Ap = A  + (size_t)(row0 + srow) * K + skc;
    const u16* Bp = Bt + (size_t)(col0 + srow) * K + skc;
    u16* AsW = &As[srow * LDST + skc];
    u16* BsW = &Bs[srow * LDST + skc];

    const int fr = lane & 15;
    const int fk = (lane >> 4) * 8;

    f32x4 acc[4][4] = {};

    u16x8 aa0, aa1, ba0, ba1;
    u16x8 ab0, ab1, bb0, bb1;
    aa0 = *(const u16x8*)(Ap);
    aa1 = *(const u16x8*)(Ap + 8);
    ba0 = *(const u16x8*)(Bp);
    ba1 = *(const u16x8*)(Bp + 8);
    ab0 = *(const u16x8*)(Ap + 32);
    ab1 = *(const u16x8*)(Ap + 40);
    bb0 = *(const u16x8*)(Bp + 32);
    bb1 = *(const u16x8*)(Bp + 40);

    for (int k0 = 0; k0 < K; k0 += 64) {
        if (k0) __syncthreads();
        *(u16x8*)(AsW)     = aa0;
        *(u16x8*)(AsW + 8) = aa1;
        *(u16x8*)(BsW)     = ba0;
        *(u16x8*)(BsW + 8) = ba1;
        __syncthreads();
        if (k0 + 64 < K) {
            aa0 = *(const u16x8*)(Ap + k0 + 64);
            aa1 = *(const u16x8*)(Ap + k0 + 72);
            ba0 = *(const u16x8*)(Bp + k0 + 64);
            ba1 = *(const u16x8*)(Bp + k0 + 72);
        }
        {
            bf16x8 af[4], bfv[4];
#pragma unroll
            for (int mi = 0; mi < 4; ++mi)
                af[mi] = __builtin_bit_cast(bf16x8,
                    *(const u16x8*)(&As[(wm + 16 * mi + fr) * LDST + fk]));
#pragma unroll
            for (int ni = 0; ni < 4; ++ni)
                bfv[ni] = __builtin_bit_cast(bf16x8,
                    *(const u16x8*)(&Bs[(wn + 16 * ni + fr) * LDST + fk]));
#pragma unroll
            for (int mi = 0; mi < 4; ++mi)
#pragma unroll
                for (int ni = 0; ni < 4; ++ni)
                    acc[mi][ni] = __builtin_amdgcn_mfma_f32_16x16x32_bf16(
                        af[mi], bfv[ni], acc[mi][ni], 0, 0, 0);
        }

        __syncthreads();
        *(u16x8*)(AsW)     = ab0;
        *(u16x8*)(AsW + 8) = ab1;
        *(u16x8*)(BsW)     = bb0;
        *(u16x8*)(BsW + 8) = bb1;
        __syncthreads();
        if (k0 + 96 < K) {
            ab0 = *(const u16x8*)(Ap + k0 + 96);
            ab1 = *(const u16x8*)(Ap + k0 + 104);
            bb0 = *(const u16x8*)(Bp + k0 + 96);
            bb1 = *(const u16x8*)(Bp + k0 + 104);
        }
        {
            bf16x8 af[4], bfv[4];
#pragma unroll
            for (int mi = 0; mi < 4; ++mi)
                af[mi] = __builtin_bit_cast(bf16x8,
                    *(const u16x8*)(&As[(wm + 16 * mi + fr) * LDST + fk]));
#pragma unroll
            for (int ni = 0; ni < 4; ++ni)
                bfv[ni] = __builtin_bit_cast(bf16x8,
                    *(const u16x8*)(&Bs[(wn + 16 * ni + fr) * LDST + fk]));
#pragma unroll
            for (int mi = 0; mi < 4; ++mi)
#pragma unroll
                for (int ni = 0; ni < 4; ++ni)
                    acc[mi][ni] = __builtin_amdgcn_mfma_f32_16x16x32_bf16(
                        af[mi], bfv[ni], acc[mi][ni], 0, 0, 0);
        }
    }

    const int orow0 = row0 + wm + (lane >> 4) * 4;
    const int ocol0 = col0 + wn + fr;
#pragma unroll
    for (int mi = 0; mi < 4; ++mi) {
#pragma unroll
        for (int ni = 0; ni < 4; ++ni) {
            const int col = ocol0 + ni * 16;
            const float bv = bias ? bias[col] : 0.0f;
#pragma unroll
            for (int r = 0; r < 4; ++r) {
                const int row = orow0 + mi * 16 + r;
                float v = acc[mi][ni][r] + bv;
                if (do_gelu) v = 0.5f * v * (1.0f + erff(v * 0.70710678118654752f));
                Cbf[(size_t)row * ldcbf + cboff + col] = f2bf(v);
            }
        }
    }
}

__global__ __launch_bounds__(256) void gemm128(
    const u16* __restrict__ A, const u16* __restrict__ Bt, int K,
    const float* __restrict__ bias, int do_gelu,
    u16* __restrict__ Cbf, int ldcbf)
{
    __shared__ u16 As[128 * LDST];
    __shared__ u16 Bs[128 * LDST];
    gemm128_core(A, Bt, K, bias, do_gelu, Cbf, ldcbf, 0,
                 blockIdx.y * 128, blockIdx.x * 128, As, Bs);
}

// Batched independent projections (flat 960-block grid)
__global__ __launch_bounds__(256) void gemm128_proj(
    const u16* __restrict__ BFx, const u16* __restrict__ BFK,
    const u16* __restrict__ BFV, const u16* __restrict__ Wm6,
    u16* __restrict__ QKV, u16* __restrict__ KVc)
{
    __shared__ u16 As[128 * LDST];
    __shared__ u16 Bs[128 * LDST];
    const int fid = blockIdx.x;
    const u16* A; const u16* B; u16* C; int ldc, coff, row0, col0;
    if (fid < 576) {
        A = BFx; B = Wm6; C = QKV; ldc = 3 * DD; coff = 0;
        row0 = (fid / 18) * 128; col0 = (fid % 18) * 128;
    } else if (fid < 768) {
        const int l = fid - 576;
        A = BFK; B = Wm6 + 4 * WPC; C = KVc; ldc = 2 * DD; coff = 0;
        row0 = (l / 6) * 128; col0 = (l % 6) * 128;
    } else {
        const int l = fid - 768;
        A = BFV; B = Wm6 + 5 * WPC; C = KVc; ldc = 2 * DD; coff = DD;
        row0 = (l / 6) * 128; col0 = (l % 6) * 128;
    }
    gemm128_core(A, B, DD, nullptr, 0, C, ldc, coff, row0, col0, As, Bs);
}

// ---------------------------------------------------------------------------
// 64x128-tile GEMM (skinny launches: Wo x2, MLP2 split-K). Depth-2 unroll.
// ---------------------------------------------------------------------------
static __device__ __forceinline__ void gemm64_core(
    const u16* __restrict__ A, const u16* __restrict__ Bt,
    int N, int Kstride, int Klen,
    const float* __restrict__ bias,
    const float* __restrict__ residf, const u16* __restrict__ residb,
    float* __restrict__ C, u16* __restrict__ Cbf, int ldcbf, int cboff,
    int do_gelu, int row0, int col0, u16* As, u16* Bs)
{
    const int tid  = threadIdx.x;
    const int lane = tid & 63;
    const int w    = tid >> 6;
    const int wm = (w >> 1) * 32;
    const int wn = (w & 1) * 64;

    const int arow = tid >> 2;
    const int akc  = (tid & 3) * 8;
    const int brow = tid >> 1;
    const int bkc  = (tid & 1) * 16;

    const u16* Ap = A  + (size_t)(row0 + arow) * Kstride + akc;
    const u16* Bp = Bt + (size_t)(col0 + brow) * Kstride + bkc;
    u16* AsW = &As[arow * LDST + akc];
    u16* BsW = &Bs[brow * LDST + bkc];

    const int fr = lane & 15;
    const int fk = (lane >> 4) * 8;

    f32x4 acc[2][4] = {};

    u16x8 a0, b00, b01, a1, b10, b11;
    a0  = *(const u16x8*)(Ap);
    b00 = *(const u16x8*)(Bp);
    b01 = *(const u16x8*)(Bp + 8);
    a1  = *(const u16x8*)(Ap + 32);
    b10 = *(const u16x8*)(Bp + 32);
    b11 = *(const u16x8*)(Bp + 40);

    for (int k0 = 0; k0 < Klen; k0 += 64) {
        if (k0) __syncthreads();
        *(u16x8*)AsW       = a0;
        *(u16x8*)BsW       = b00;
        *(u16x8*)(BsW + 8) = b01;
        __syncthreads();
        if (k0 + 64 < Klen) {
            a0  = *(const u16x8*)(Ap + k0 + 64);
            b00 = *(const u16x8*)(Bp + k0 + 64);
            b01 = *(const u16x8*)(Bp + k0 + 72);
        }
        {
            bf16x8 af[2], bfv[4];
#pragma unroll
            for (int mi = 0; mi < 2; ++mi)
                af[mi] = __builtin_bit_cast(bf16x8,
                    *(const u16x8*)(&As[(wm + 16 * mi + fr) * LDST + fk]));
#pragma unroll
            for (int ni = 0; ni < 4; ++ni)
                bfv[ni] = __builtin_bit_cast(bf16x8,
                    *(const u16x8*)(&Bs[(wn + 16 * ni + fr) * LDST + fk]));
#pragma unroll
            for (int mi = 0; mi < 2; ++mi)
#pragma unroll
                for (int ni = 0; ni < 4; ++ni)
                    acc[mi][ni] = __builtin_amdgcn_mfma_f32_16x16x32_bf16(
                        af[mi], bfv[ni], acc[mi][ni], 0, 0, 0);
        }

        __syncthreads();
        *(u16x8*)AsW       = a1;
        *(u16x8*)BsW       = b10;
        *(u16x8*)(BsW + 8) = b11;
        __syncthreads();
        if (k0 + 96 < Klen) {
            a1  = *(const u16x8*)(Ap + k0 + 96);
            b10 = *(const u16x8*)(Bp + k0 + 96);
            b11 = *(const u16x8*)(Bp + k0 + 104);
        }
        {
            bf16x8 af[2], bfv[4];
#pragma unroll
            for (int mi = 0; mi < 2; ++mi)
                af[mi] = __builtin_bit_cast(bf16x8,
                    *(const u16x8*)(&As[(wm + 16 * mi + fr) * LDST + fk]));
#pragma unroll
            for (int ni = 0; ni < 4; ++ni)
                bfv[ni] = __builtin_bit_cast(bf16x8,
                    *(const u16x8*)(&Bs[(wn + 16 * ni + fr) * LDST + fk]));
#pragma unroll
            for (int mi = 0; mi < 2; ++mi)
#pragma unroll
                for (int ni = 0; ni < 4; ++ni)
                    acc[mi][ni] = __builtin_amdgcn_mfma_f32_16x16x32_bf16(
                        af[mi], bfv[ni], acc[mi][ni], 0, 0, 0);
        }
    }

    const int orow0 = row0 + wm + (lane >> 4) * 4;
    const int ocol0 = col0 + wn + fr;
#pragma unroll
    for (int mi = 0; mi < 2; ++mi) {
#pragma unroll
        for (int ni = 0; ni < 4; ++ni) {
            const int col = ocol0 + ni * 16;
            const float bv = bias ? bias[col] : 0.0f;
#pragma unroll
            for (int r = 0; r < 4; ++r) {
                const int row = orow0 + mi * 16 + r;
                float v = acc[mi][ni][r] + bv;
                if (do_gelu) v = 0.5f * v * (1.0f + erff(v * 0.70710678118654752f));
                if (residf) v += residf[(size_t)row * N + col];
                if (residb) v += bf2f(residb[(size_t)row * N + col]);
                if (C)   C[(size_t)row * N + col] = v;
                if (Cbf) Cbf[(size_t)row * ldcbf + cboff + col] = f2bf(v);
            }
        }
    }
}

__global__ __launch_bounds__(256) void gemm64(
    const u16* __restrict__ A, const u16* __restrict__ Bt, int N, int K,
    const float* __restrict__ bias,
    const float* __restrict__ residf, const u16* __restrict__ residb,
    float* __restrict__ C, u16* __restrict__ Cbf, int ldcbf, int do_gelu)
{
    __shared__ u16 As[64 * LDST];
    __shared__ u16 Bs[128 * LDST];
    gemm64_core(A, Bt, N, K, K, bias, residf, residb, C, Cbf, ldcbf, 0, do_gelu,
                blockIdx.y * 64, blockIdx.x * 128, As, Bs);
}

__global__ __launch_bounds__(256) void gemm64_sk(
    const u16* __restrict__ A, const u16* __restrict__ Bt, int N, int Kstride,
    int Klen, float* __restrict__ Cpair)
{
    __shared__ u16 As[64 * LDST];
    __shared__ u16 Bs[128 * LDST];
    const int z = blockIdx.z;
    const int koff = z * Klen;
    gemm64_core(A + koff, Bt + koff, N, Kstride, Klen,
                nullptr, nullptr, nullptr,
                Cpair + (size_t)z * MROWS * N, nullptr, 0, 0, 0,
                blockIdx.y * 64, blockIdx.x * 128, As, Bs);
}

// ---------------------------------------------------------------------------
// Weight transposes (fp32 -> bf16, [K,N] -> [N,K])
// ---------------------------------------------------------------------------
static __device__ __forceinline__ void tcvt_body(
    const float* __restrict__ in, u16* __restrict__ out,
    int K, int N, int bx, int by)
{
    __shared__ float t[32][33];
    const int n0 = bx * 32, k0 = by * 32;
    const int tx = threadIdx.x & 31, ty = threadIdx.x >> 5;
#pragma unroll
    for (int j = 0; j < 4; ++j)
        t[ty + j * 8][tx] = in[(size_t)(k0 + ty + j * 8) * N + n0 + tx];
    __syncthreads();
#pragma unroll
    for (int j = 0; j < 4; ++j)
        out[(size_t)(n0 + ty + j * 8) * K + k0 + tx] = f2bf(t[tx][ty + j * 8]);
}

__global__ __launch_bounds__(256) void tcvt6_kernel(
    const float* __restrict__ w0, const float* __restrict__ w1,
    const float* __restrict__ w2, const float* __restrict__ w3,
    const float* __restrict__ w4, const float* __restrict__ w5,
    u16* __restrict__ Wm6)
{
    __shared__ float t[32][33];
    const int z = blockIdx.z;
    const int wi = z / 12, head = z % 12;
    const float* wsel = (wi == 0) ? w0 : (wi == 1) ? w1 : (wi == 2) ? w2 :
                        (wi == 3) ? w3 : (wi == 4) ? w4 : w5;
    const float* ib = wsel + (size_t)head * DD * DHD;
    u16* ob = Wm6 + (size_t)wi * WPC + (size_t)head * DHD * DD;
    const int n0 = blockIdx.x * 32, k0 = blockIdx.y * 32;
    const int tx = threadIdx.x & 31, ty = threadIdx.x >> 5;
#pragma unroll
    for (int j = 0; j < 4; ++j)
        t[ty + j * 8][tx] = ib[(size_t)(k0 + ty + j * 8) * DHD + n0 + tx];
    __syncthreads();
#pragma unroll
    for (int j = 0; j < 4; ++j)
        ob[(size_t)(n0 + ty + j * 8) * DD + k0 + tx] = f2bf(t[tx][ty + j * 8]);
}

__global__ __launch_bounds__(256) void tcvt4_kernel(
    const float* __restrict__ wom, const float* __restrict__ woc,
    const float* __restrict__ w1, const float* __restrict__ w2,
    u16* __restrict__ womt, u16* __restrict__ woct,
    u16* __restrict__ w1t, u16* __restrict__ w2t)
{
    const int fid = blockIdx.x;
    if (fid < 576) {
        tcvt_body(wom, womt, DD, DD, fid % 24, fid / 24);
    } else if (fid < 1152) {
        const int l = fid - 576;
        tcvt_body(woc, woct, DD, DD, l % 24, l / 24);
    } else if (fid < 3456) {
        const int l = fid - 1152;
        tcvt_body(w1, w1t, DD, FF, l % 96, l / 96);
    } else {
        const int l = fid - 3456;
        tcvt_body(w2, w2t, FF, DD, l % 24, l / 24);
    }
}

__global__ __launch_bounds__(256) void cvt3_kernel(
    const float* __restrict__ s0, const float* __restrict__ s1,
    const float* __restrict__ s2,
    u16* __restrict__ d0, u16* __restrict__ d1, u16* __restrict__ d2, int n4)
{
    const int z = blockIdx.z;
    const float* s = (z == 0) ? s0 : (z == 1) ? s1 : s2;
    u16* d = (z == 0) ? d0 : (z == 1) ? d1 : d2;
    const int i = blockIdx.x * 256 + threadIdx.x;
    if (i < n4) {
        float4 v = ((const float4*)s)[i];
        ushort4 o;
        o.x = f2bf(v.x); o.y = f2bf(v.y); o.z = f2bf(v.z); o.w = f2bf(v.w);
        ((ushort4*)d)[i] = o;
    }
}

// ---------------------------------------------------------------------------
// MFMA flash attention, max-free exp2 softmax, KVBLK=128.
// 256 threads / 4 waves, 64-query tile. Per 128-key tile:
//   stage K[128][64] (KPs, stride 72) + Vt[64][128] (stride 136, permuted
//   per 64-key half) -> barrier -> QK^T (16 MFMA) -> barrier -> softmax
//   writes P (64 q x 128 k, stride 136, aliases KPs) -> PV (16 MFMA).
// 3 barriers / 128 keys (vs 4 at KVBLK=64). LDS 35840 B.
// ---------------------------------------------------------------------------
#define KAST 72                 // K row stride (u16)
#define PAST 136                // P / Vt row stride (u16)
#define CSC 0.18033688011112042f   // 0.125 * log2(e)
__global__ __launch_bounds__(256) void attn_mfma_kernel(
    const u16* __restrict__ Q, int ldq,
    const u16* __restrict__ K, const u16* __restrict__ V, int ldkv,
    const int* __restrict__ kmask, u16* __restrict__ O, int causal)
{
    const int qt = causal ? ((int)gridDim.x - 1 - (int)blockIdx.x) : (int)blockIdx.x;
    const int bh = blockIdx.y;
    const int b  = bh / HH;
    const int h  = bh % HH;
    const int tid  = threadIdx.x;
    const int lane = tid & 63;
    const int w    = tid >> 6;
    const int lr = lane & 15;
    const int lg = lane >> 4;

    __shared__ u16 KPs[128 * KAST];   // K tile; P (64 x PAST) aliases after QK^T
    __shared__ u16 Vt[64 * PAST];

    const int row0 = qt * 64;
    const int q0w  = row0 + w * 16;

    bf16x8 qf[2];
    {
        const u16* qp = Q + (size_t)(b * SS + q0w + lr) * ldq + h * DHD + lg * 8;
        qf[0] = __builtin_bit_cast(bf16x8, *(const u16x8*)(qp));
        qf[1] = __builtin_bit_cast(bf16x8, *(const u16x8*)(qp + 32));
    }

    // staging geometry: K row sr (0..127), col base scb (0/32); V key vk
    // (0..127), d base vdb (0/32); permuted column within 64-key half.
    const int sr  = tid >> 1;
    const int scb = (tid & 1) * 32;
    const int vk  = tid >> 1;
    const int vdb = (tid & 1) * 32;
    const int k6  = vk & 63;
    const int vcol = ((vk >> 6) << 6) | ((k6 & 15) << 2) | (k6 >> 4);

    f32x4 acc[4] = {};
    float lsum[4] = {0.0f, 0.0f, 0.0f, 0.0f};

    const int nkt = causal ? ((qt + 2) >> 1) : 8;

    u16x8 kr0, kr1, kr2, kr3, vr0, vr1, vr2, vr3;
    {
        const u16* kp = K + (size_t)(b * SS + sr) * ldkv + h * DHD + scb;
        kr0 = *(const u16x8*)(kp);
        kr1 = *(const u16x8*)(kp + 8);
        kr2 = *(const u16x8*)(kp + 16);
        kr3 = *(const u16x8*)(kp + 24);
        const u16* vp = V + (size_t)(b * SS + vk) * ldkv + h * DHD + vdb;
        vr0 = *(const u16x8*)(vp);
        vr1 = *(const u16x8*)(vp + 8);
        vr2 = *(const u16x8*)(vp + 16);
        vr3 = *(const u16x8*)(vp + 24);
    }

    for (int kt = 0; kt < nkt; ++kt) {
        const int kcol0 = kt * 128;
        if (kt) __syncthreads();        // all PV reads of KPs/Vt done

        *(u16x8*)(&KPs[sr * KAST + scb])      = kr0;
        *(u16x8*)(&KPs[sr * KAST + scb + 8])  = kr1;
        *(u16x8*)(&KPs[sr * KAST + scb + 16]) = kr2;
        *(u16x8*)(&KPs[sr * KAST + scb + 24]) = kr3;
#pragma unroll
        for (int j = 0; j < 8; ++j) Vt[(vdb + j) * PAST + vcol]      = vr0[j];
#pragma unroll
        for (int j = 0; j < 8; ++j) Vt[(vdb + 8 + j) * PAST + vcol]  = vr1[j];
#pragma unroll
        for (int j = 0; j < 8; ++j) Vt[(vdb + 16 + j) * PAST + vcol] = vr2[j];
#pragma unroll
        for (int j = 0; j < 8; ++j) Vt[(vdb + 24 + j) * PAST + vcol] = vr3[j];
        __syncthreads();

        if (kt + 1 < nkt) {
            const int kn = kcol0 + 128;
            const u16* kp = K + (size_t)(b * SS + kn + sr) * ldkv + h * DHD + scb;
            kr0 = *(const u16x8*)(kp);
            kr1 = *(const u16x8*)(kp + 8);
            kr2 = *(const u16x8*)(kp + 16);
            kr3 = *(const u16x8*)(kp + 24);
            const u16* vp = V + (size_t)(b * SS + kn + vk) * ldkv + h * DHD + vdb;
            vr0 = *(const u16x8*)(vp);
            vr1 = *(const u16x8*)(vp + 8);
            vr2 = *(const u16x8*)(vp + 16);
            vr3 = *(const u16x8*)(vp + 24);
        }

        // QK^T (consumes K tile): 8 key-groups x 2 k-steps
        f32x4 s[8] = {};
#pragma unroll
        for (int fi = 0; fi < 8; ++fi) {
            bf16x8 kf0 = __builtin_bit_cast(bf16x8, *(const u16x8*)(&KPs[(fi * 16 + lr) * KAST + lg * 8]));
            bf16x8 kf1 = __builtin_bit_cast(bf16x8, *(const u16x8*)(&KPs[(fi * 16 + lr) * KAST + 32 + lg * 8]));
            s[fi] = __builtin_amdgcn_mfma_f32_16x16x32_bf16(qf[0], kf0, s[fi], 0, 0, 0);
            s[fi] = __builtin_amdgcn_mfma_f32_16x16x32_bf16(qf[1], kf1, s[fi], 0, 0, 0);
        }
        __syncthreads();   // K tile fully consumed; safe to overwrite with P

        float biasf[8];
#pragma unroll
        for (int fi = 0; fi < 8; ++fi)
            biasf[fi] = kmask[b * SS + kcol0 + fi * 16 + lr] ? 0.0f : -INFINITY;
        const bool diag = (causal != 0) && (kt == nkt - 1);

#pragma unroll
        for (int r = 0; r < 4; ++r) {
            const int qrow = q0w + lg * 4 + r;
            const int prow = (w * 16 + lg * 4 + r) * PAST;
            u16x4 pk0, pk1;
            float rs = 0.0f;
#pragma unroll
            for (int fi = 0; fi < 8; ++fi) {
                float v = fmaf(s[fi][r], CSC, biasf[fi]);
                if (diag) {
                    const int key = kcol0 + fi * 16 + lr;
                    v = (key <= qrow) ? v : -INFINITY;
                }
                const float pv = exp2f(v);   // 0 for masked
                if (fi < 4) pk0[fi] = f2bf(pv); else pk1[fi - 4] = f2bf(pv);
                rs += pv;
            }
            lsum[r] += rs;
            *(u16x4*)(&KPs[prow + lr * 4])      = pk0;
            *(u16x4*)(&KPs[prow + 64 + lr * 4]) = pk1;
        }

        // PV: A = own wave's P strip, B = Vt; 4 k-steps x 4 d-groups
#pragma unroll
        for (int kk = 0; kk < 4; ++kk) {
            bf16x8 pf = __builtin_bit_cast(bf16x8, *(const u16x8*)(&KPs[(w * 16 + lr) * PAST + kk * 32 + lg * 8]));
#pragma unroll
            for (int di = 0; di < 4; ++di) {
                bf16x8 vf = __builtin_bit_cast(bf16x8, *(const u16x8*)(&Vt[(di * 16 + lr) * PAST + kk * 32 + lg * 8]));
                acc[di] = __builtin_amdgcn_mfma_f32_16x16x32_bf16(pf, vf, acc[di], 0, 0, 0);
            }
        }
    }

    // one l-reduction for the whole kernel
#pragma unroll
    for (int r = 0; r < 4; ++r) {
        float l = lsum[r];
        l += __shfl_xor(l, 1);
        l += __shfl_xor(l, 2);
        l += __shfl_xor(l, 4);
        l += __shfl_xor(l, 8);
        const float inv = (l > 0.0f) ? (1.0f / l) : 0.0f;
        const size_t orow = (size_t)(b * SS + q0w + lg * 4 + r) * DD + h * DHD;
#pragma unroll
        for (int di = 0; di < 4; ++di)
            O[orow + di * 16 + lr] = f2bf(acc[di][r] * inv);
    }
}

// ---------------------------------------------------------------------------
// LayerNorm over last dim (768); nullable fp32 out / bf16 out.
// ---------------------------------------------------------------------------
__global__ __launch_bounds__(256) void ln_kernel(
    const float* __restrict__ X, const float* __restrict__ gma,
    const float* __restrict__ bta, float* __restrict__ Y, u16* __restrict__ Ybf)
{
    const int row = blockIdx.x;
    const int tid = threadIdx.x;
    const float* x = X + (size_t)row * DD;

    const float v0 = x[tid], v1 = x[tid + 256], v2 = x[tid + 512];

    __shared__ float sd[256];
    sd[tid] = v0 + v1 + v2;
    __syncthreads();
    for (int off = 128; off > 0; off >>= 1) {
        if (tid < off) sd[tid] += sd[tid + off];
        __syncthreads();
    }
    const float mean = sd[0] * (1.0f / 768.0f);
    __syncthreads();

    const float q0 = v0 - mean, q1 = v1 - mean, q2 = v2 - mean;
    sd[tid] = q0 * q0 + q1 * q1 + q2 * q2;
    __syncthreads();
    for (int off = 128; off > 0; off >>= 1) {
        if (tid < off) sd[tid] += sd[tid + off];
        __syncthreads();
    }
    const float var = sd[0] * (1.0f / 768.0f);
    const float inv = rsqrtf(var + 1e-5f);

    const float y0 = q0 * inv * gma[tid]       + bta[tid];
    const float y1 = q1 * inv * gma[tid + 256] + bta[tid + 256];
    const float y2 = q2 * inv * gma[tid + 512] + bta[tid + 512];
    if (Y) {
        float* y = Y + (size_t)row * DD;
        y[tid] = y0; y[tid + 256] = y1; y[tid + 512] = y2;
    }
    if (Ybf) {
        u16* yb = Ybf + (size_t)row * DD;
        yb[tid] = f2bf(y0); yb[tid + 256] = f2bf(y1); yb[tid + 512] = f2bf(y2);
    }
}

// ---------------------------------------------------------------------------
// LayerNorm over (C0 + C1 + bias + resid_bf16): split-K reduce fused in.
// ---------------------------------------------------------------------------
__global__ __launch_bounds__(256) void ln_red_kernel(
    const float* __restrict__ C0, const float* __restrict__ C1,
    const float* __restrict__ bias, const u16* __restrict__ resid,
    const float* __restrict__ gma, const float* __restrict__ bta,
    float* __restrict__ Y)
{
    const int row = blockIdx.x;
    const int tid = threadIdx.x;
    const size_t base = (size_t)row * DD;

    float v[3];
#pragma unroll
    for (int j = 0; j < 3; ++j) {
        const int i = tid + j * 256;
        v[j] = C0[base + i] + C1[base + i] + bias[i] + bf2f(resid[base + i]);
    }

    __shared__ float sd[256];
    sd[tid] = v[0] + v[1] + v[2];
    __syncthreads();
    for (int off = 128; off > 0; off >>= 1) {
        if (tid < off) sd[tid] += sd[tid + off];
        __syncthreads();
    }
    const float mean = sd[0] * (1.0f / 768.0f);
    __syncthreads();

    float q[3];
#pragma unroll
    for (int j = 0; j < 3; ++j) q[j] = v[j] - mean;
    sd[tid] = q[0] * q[0] + q[1] * q[1] + q[2] * q[2];
    __syncthreads();
    for (int off = 128; off > 0; off >>= 1) {
        if (tid < off) sd[tid] += sd[tid + off];
        __syncthreads();
    }
    const float var = sd[0] * (1.0f / 768.0f);
    const float inv = rsqrtf(var + 1e-5f);

    float* y = Y + base;
#pragma unroll
    for (int j = 0; j < 3; ++j) {
        const int i = tid + j * 256;
        y[i] = q[j] * inv * gma[i] + bta[i];
    }
}

// ---------------------------------------------------------------------------
extern "C" void kernel_launch(void* const* d_in, const int* in_sizes, int n_in,
                              void* d_out, int out_size, void* d_ws, size_t ws_size,
                              hipStream_t stream)
{
    (void)in_sizes; (void)n_in; (void)out_size; (void)ws_size;

    const float* key_enc   = (const float*)d_in[0];
    const float* value_enc = (const float*)d_in[1];
    const float* x         = (const float*)d_in[2];
    const int*   src_mask  = (const int*)d_in[3];
    const int*   tgt_mask  = (const int*)d_in[4];
    const float* Wq_m = (const float*)d_in[5];
    const float* Wk_m = (const float*)d_in[6];
    const float* Wv_m = (const float*)d_in[7];
    const float* Wo_m = (const float*)d_in[8];
    const float* Wq_c = (const float*)d_in[9];
    const float* Wk_c = (const float*)d_in[10];
    const float* Wv_c = (const float*)d_in[11];
    const float* Wo_c = (const float*)d_in[12];
    const float* ln1_g = (const float*)d_in[13];
    const float* ln1_b = (const float*)d_in[14];
    const float* ln2_g = (const float*)d_in[15];
    const float* ln2_b = (const float*)d_in[16];
    const float* ln3_g = (const float*)d_in[17];
    const float* ln3_b = (const float*)d_in[18];
    const float* W1 = (const float*)d_in[19];
    const float* b1 = (const float*)d_in[20];
    const float* W2 = (const float*)d_in[21];
    const float* b2 = (const float*)d_in[22];

    float* out = (float*)d_out;

    // workspace layout
    const size_t ACT = (size_t)MROWS * DD;
    char* p = (char*)d_ws;
    u16* QKV  = (u16*)p;   p += 3 * ACT * 2;
    u16* BFx  = (u16*)p;   p += ACT * 2;
    u16* BFK  = (u16*)p;   p += ACT * 2;
    u16* BFV  = (u16*)p;   p += ACT * 2;
    u16* BF1a = (u16*)p;   p += ACT * 2;
    u16* BF1h = (u16*)p;   p += ACT * 2;
    float* T2 = (float*)p; p += ACT * 4;   // pre-LN fp32 / split-K partial 0
    float* T2b = (float*)p; p += ACT * 4;  // split-K partial 1 / cross-KV bf16
    u16* Wm6  = (u16*)p;   p += 6 * (size_t)WPC * 2;
    u16* Wom_t = (u16*)p;  p += (size_t)WPC * 2;
    u16* Woc_t = (u16*)p;  p += (size_t)WPC * 2;
    u16* W1t  = (u16*)p;   p += (size_t)DD * FF * 2;
    u16* W2t  = (u16*)p;   p += (size_t)DD * FF * 2;
    u16* MID  = QKV;       // [4096][3072] bf16 aliases QKV+BFx (dead by MLP)
    u16* KVc  = (u16*)T2b; // [4096][1536] bf16 cross K|V (dead by MLP2)

    const dim3 blk(256);
    const int nc4 = (int)(ACT / 4);

    // Prep (3 dispatches)
    cvt3_kernel<<<dim3(nc4 / 256, 1, 3), blk, 0, stream>>>(
        x, key_enc, value_enc, BFx, BFK, BFV, nc4);
    tcvt6_kernel<<<dim3(2, 24, 72), blk, 0, stream>>>(
        Wq_m, Wk_m, Wv_m, Wq_c, Wk_c, Wv_c, Wm6);
    tcvt4_kernel<<<dim3(5760), blk, 0, stream>>>(
        Wo_m, Wo_c, W1, W2, Wom_t, Woc_t, W1t, W2t);

    const dim3 gProj(960);        // self QKV + cross K/V batched
    const dim3 gQc(6, 32);        // cross Q only
    const dim3 gP(6, 64);         // 64x128 skinny (Wo)
    const dim3 gM1(24, 32);       // MLP1 128x128
    const dim3 gM2(6, 64, 2);     // MLP2 split-K
    const dim3 gAttn(16, BB * HH);

    // All input-independent projections in one launch
    gemm128_proj<<<gProj, blk, 0, stream>>>(BFx, BFK, BFV, Wm6, QKV, KVc);

    // Self-attention
    attn_mfma_kernel<<<gAttn, blk, 0, stream>>>(
        QKV, 3 * DD, QKV + DD, QKV + 2 * DD, 3 * DD, tgt_mask, BF1a, 1);
    gemm64<<<gP, blk, 0, stream>>>(BF1a, Wom_t, DD, DD,
                                   nullptr, x, nullptr,
                                   T2, nullptr, DD, 0);
    ln_kernel<<<MROWS, blk, 0, stream>>>(T2, ln1_g, ln1_b, nullptr, BF1h);

    // Cross-attention (K/V already in KVc)
    gemm128<<<gQc, blk, 0, stream>>>(BF1h, Wm6 + 3 * WPC, DD, nullptr, 0,
                                     QKV, 3 * DD);
    attn_mfma_kernel<<<gAttn, blk, 0, stream>>>(
        QKV, 3 * DD, KVc, KVc + DD, 2 * DD, src_mask, BF1a, 0);
    gemm64<<<gP, blk, 0, stream>>>(BF1a, Woc_t, DD, DD,
                                   nullptr, nullptr, BF1h,
                                   T2, nullptr, DD, 0);
    ln_kernel<<<MROWS, blk, 0, stream>>>(T2, ln2_g, ln2_b, nullptr, BF1h);

    // MLP
    gemm128<<<gM1, blk, 0, stream>>>(BF1h, W1t, DD, b1, 1, MID, FF);
    gemm64_sk<<<gM2, blk, 0, stream>>>(MID, W2t, DD, FF, FF / 2, T2);
    ln_red_kernel<<<MROWS, blk, 0, stream>>>(T2, T2b, b2, BF1h,
                                             ln3_g, ln3_b, out);
}

// Round 19
// 315.276 us; speedup vs baseline: 1.0706x; 1.0189x over previous
//
#include <hip/hip_runtime.h>
#include <math.h>

// Problem constants
#define BB 4
#define SS 1024
#define DD 768
#define HH 12
#define DHD 64
#define MROWS 4096
#define FF 3072
#define WPC (DD * DD)

typedef unsigned short u16;
typedef float f32x4 __attribute__((ext_vector_type(4)));
typedef __bf16 bf16x8 __attribute__((ext_vector_type(8)));
typedef unsigned short u16x8 __attribute__((ext_vector_type(8)));
typedef unsigned short u16x4 __attribute__((ext_vector_type(4)));

static __device__ __forceinline__ float bf2f(u16 u) {
    union { unsigned int i; float f; } c; c.i = ((unsigned int)u) << 16; return c.f;
}
static __device__ __forceinline__ u16 f2bf(float f) {
    return __builtin_bit_cast(u16, static_cast<__bf16>(f));
}

#define LDST 40

// ---------------------------------------------------------------------------
// 128x128-tile bf16 MFMA GEMM core (depth-2 explicit unroll). K % 64 == 0.
// ---------------------------------------------------------------------------
static __device__ __forceinline__ void gemm128_core(
    const u16* __restrict__ A, const u16* __restrict__ Bt,
    int K,
    const float* __restrict__ bias, int do_gelu,
    u16* __restrict__ Cbf, int ldcbf, int cboff,
    int row0, int col0, u16* As, u16* Bs)
{
    const int tid  = threadIdx.x;
    const int lane = tid & 63;
    const int w    = tid >> 6;
    const int wm = (w >> 1) * 64;
    const int wn = (w & 1) * 64;

    const int srow = tid >> 1;
    const int skc  = (tid & 1) * 16;

    const u16* Ap = A  + (size_t)(row0 + srow) * K + skc;
    const u16* Bp = Bt + (size_t)(col0 + srow) * K + skc;
    u16* AsW = &As[srow * LDST + skc];
    u16* BsW = &Bs[srow * LDST + skc];

    const int fr = lane & 15;
    const int fk = (lane >> 4) * 8;

    f32x4 acc[4][4] = {};

    u16x8 aa0, aa1, ba0, ba1;
    u16x8 ab0, ab1, bb0, bb1;
    aa0 = *(const u16x8*)(Ap);
    aa1 = *(const u16x8*)(Ap + 8);
    ba0 = *(const u16x8*)(Bp);
    ba1 = *(const u16x8*)(Bp + 8);
    ab0 = *(const u16x8*)(Ap + 32);
    ab1 = *(const u16x8*)(Ap + 40);
    bb0 = *(const u16x8*)(Bp + 32);
    bb1 = *(const u16x8*)(Bp + 40);

    for (int k0 = 0; k0 < K; k0 += 64) {
        if (k0) __syncthreads();
        *(u16x8*)(AsW)     = aa0;
        *(u16x8*)(AsW + 8) = aa1;
        *(u16x8*)(BsW)     = ba0;
        *(u16x8*)(BsW + 8) = ba1;
        __syncthreads();
        if (k0 + 64 < K) {
            aa0 = *(const u16x8*)(Ap + k0 + 64);
            aa1 = *(const u16x8*)(Ap + k0 + 72);
            ba0 = *(const u16x8*)(Bp + k0 + 64);
            ba1 = *(const u16x8*)(Bp + k0 + 72);
        }
        {
            bf16x8 af[4], bfv[4];
#pragma unroll
            for (int mi = 0; mi < 4; ++mi)
                af[mi] = __builtin_bit_cast(bf16x8,
                    *(const u16x8*)(&As[(wm + 16 * mi + fr) * LDST + fk]));
#pragma unroll
            for (int ni = 0; ni < 4; ++ni)
                bfv[ni] = __builtin_bit_cast(bf16x8,
                    *(const u16x8*)(&Bs[(wn + 16 * ni + fr) * LDST + fk]));
#pragma unroll
            for (int mi = 0; mi < 4; ++mi)
#pragma unroll
                for (int ni = 0; ni < 4; ++ni)
                    acc[mi][ni] = __builtin_amdgcn_mfma_f32_16x16x32_bf16(
                        af[mi], bfv[ni], acc[mi][ni], 0, 0, 0);
        }

        __syncthreads();
        *(u16x8*)(AsW)     = ab0;
        *(u16x8*)(AsW + 8) = ab1;
        *(u16x8*)(BsW)     = bb0;
        *(u16x8*)(BsW + 8) = bb1;
        __syncthreads();
        if (k0 + 96 < K) {
            ab0 = *(const u16x8*)(Ap + k0 + 96);
            ab1 = *(const u16x8*)(Ap + k0 + 104);
            bb0 = *(const u16x8*)(Bp + k0 + 96);
            bb1 = *(const u16x8*)(Bp + k0 + 104);
        }
        {
            bf16x8 af[4], bfv[4];
#pragma unroll
            for (int mi = 0; mi < 4; ++mi)
                af[mi] = __builtin_bit_cast(bf16x8,
                    *(const u16x8*)(&As[(wm + 16 * mi + fr) * LDST + fk]));
#pragma unroll
            for (int ni = 0; ni < 4; ++ni)
                bfv[ni] = __builtin_bit_cast(bf16x8,
                    *(const u16x8*)(&Bs[(wn + 16 * ni + fr) * LDST + fk]));
#pragma unroll
            for (int mi = 0; mi < 4; ++mi)
#pragma unroll
                for (int ni = 0; ni < 4; ++ni)
                    acc[mi][ni] = __builtin_amdgcn_mfma_f32_16x16x32_bf16(
                        af[mi], bfv[ni], acc[mi][ni], 0, 0, 0);
        }
    }

    const int orow0 = row0 + wm + (lane >> 4) * 4;
    const int ocol0 = col0 + wn + fr;
#pragma unroll
    for (int mi = 0; mi < 4; ++mi) {
#pragma unroll
        for (int ni = 0; ni < 4; ++ni) {
            const int col = ocol0 + ni * 16;
            const float bv = bias ? bias[col] : 0.0f;
#pragma unroll
            for (int r = 0; r < 4; ++r) {
                const int row = orow0 + mi * 16 + r;
                float v = acc[mi][ni][r] + bv;
                if (do_gelu) v = 0.5f * v * (1.0f + erff(v * 0.70710678118654752f));
                Cbf[(size_t)row * ldcbf + cboff + col] = f2bf(v);
            }
        }
    }
}

__global__ __launch_bounds__(256) void gemm128(
    const u16* __restrict__ A, const u16* __restrict__ Bt, int K,
    const float* __restrict__ bias, int do_gelu,
    u16* __restrict__ Cbf, int ldcbf)
{
    __shared__ u16 As[128 * LDST];
    __shared__ u16 Bs[128 * LDST];
    gemm128_core(A, Bt, K, bias, do_gelu, Cbf, ldcbf, 0,
                 blockIdx.y * 128, blockIdx.x * 128, As, Bs);
}

// Batched independent projections (flat 960-block grid)
__global__ __launch_bounds__(256) void gemm128_proj(
    const u16* __restrict__ BFx, const u16* __restrict__ BFK,
    const u16* __restrict__ BFV, const u16* __restrict__ Wm6,
    u16* __restrict__ QKV, u16* __restrict__ KVc)
{
    __shared__ u16 As[128 * LDST];
    __shared__ u16 Bs[128 * LDST];
    const int fid = blockIdx.x;
    const u16* A; const u16* B; u16* C; int ldc, coff, row0, col0;
    if (fid < 576) {
        A = BFx; B = Wm6; C = QKV; ldc = 3 * DD; coff = 0;
        row0 = (fid / 18) * 128; col0 = (fid % 18) * 128;
    } else if (fid < 768) {
        const int l = fid - 576;
        A = BFK; B = Wm6 + 4 * WPC; C = KVc; ldc = 2 * DD; coff = 0;
        row0 = (l / 6) * 128; col0 = (l % 6) * 128;
    } else {
        const int l = fid - 768;
        A = BFV; B = Wm6 + 5 * WPC; C = KVc; ldc = 2 * DD; coff = DD;
        row0 = (l / 6) * 128; col0 = (l % 6) * 128;
    }
    gemm128_core(A, B, DD, nullptr, 0, C, ldc, coff, row0, col0, As, Bs);
}

// ---------------------------------------------------------------------------
// 64x128-tile GEMM (skinny launches). Depth-2 unroll. All outputs bf16.
// ---------------------------------------------------------------------------
static __device__ __forceinline__ void gemm64_core(
    const u16* __restrict__ A, const u16* __restrict__ Bt,
    int N, int Kstride, int Klen,
    const float* __restrict__ bias,
    const float* __restrict__ residf, const u16* __restrict__ residb,
    u16* __restrict__ Cbf, int ldcbf, int cboff,
    int row0, int col0, u16* As, u16* Bs)
{
    const int tid  = threadIdx.x;
    const int lane = tid & 63;
    const int w    = tid >> 6;
    const int wm = (w >> 1) * 32;
    const int wn = (w & 1) * 64;

    const int arow = tid >> 2;
    const int akc  = (tid & 3) * 8;
    const int brow = tid >> 1;
    const int bkc  = (tid & 1) * 16;

    const u16* Ap = A  + (size_t)(row0 + arow) * Kstride + akc;
    const u16* Bp = Bt + (size_t)(col0 + brow) * Kstride + bkc;
    u16* AsW = &As[arow * LDST + akc];
    u16* BsW = &Bs[brow * LDST + bkc];

    const int fr = lane & 15;
    const int fk = (lane >> 4) * 8;

    f32x4 acc[2][4] = {};

    u16x8 a0, b00, b01, a1, b10, b11;
    a0  = *(const u16x8*)(Ap);
    b00 = *(const u16x8*)(Bp);
    b01 = *(const u16x8*)(Bp + 8);
    a1  = *(const u16x8*)(Ap + 32);
    b10 = *(const u16x8*)(Bp + 32);
    b11 = *(const u16x8*)(Bp + 40);

    for (int k0 = 0; k0 < Klen; k0 += 64) {
        if (k0) __syncthreads();
        *(u16x8*)AsW       = a0;
        *(u16x8*)BsW       = b00;
        *(u16x8*)(BsW + 8) = b01;
        __syncthreads();
        if (k0 + 64 < Klen) {
            a0  = *(const u16x8*)(Ap + k0 + 64);
            b00 = *(const u16x8*)(Bp + k0 + 64);
            b01 = *(const u16x8*)(Bp + k0 + 72);
        }
        {
            bf16x8 af[2], bfv[4];
#pragma unroll
            for (int mi = 0; mi < 2; ++mi)
                af[mi] = __builtin_bit_cast(bf16x8,
                    *(const u16x8*)(&As[(wm + 16 * mi + fr) * LDST + fk]));
#pragma unroll
            for (int ni = 0; ni < 4; ++ni)
                bfv[ni] = __builtin_bit_cast(bf16x8,
                    *(const u16x8*)(&Bs[(wn + 16 * ni + fr) * LDST + fk]));
#pragma unroll
            for (int mi = 0; mi < 2; ++mi)
#pragma unroll
                for (int ni = 0; ni < 4; ++ni)
                    acc[mi][ni] = __builtin_amdgcn_mfma_f32_16x16x32_bf16(
                        af[mi], bfv[ni], acc[mi][ni], 0, 0, 0);
        }

        __syncthreads();
        *(u16x8*)AsW       = a1;
        *(u16x8*)BsW       = b10;
        *(u16x8*)(BsW + 8) = b11;
        __syncthreads();
        if (k0 + 96 < Klen) {
            a1  = *(const u16x8*)(Ap + k0 + 96);
            b10 = *(const u16x8*)(Bp + k0 + 96);
            b11 = *(const u16x8*)(Bp + k0 + 104);
        }
        {
            bf16x8 af[2], bfv[4];
#pragma unroll
            for (int mi = 0; mi < 2; ++mi)
                af[mi] = __builtin_bit_cast(bf16x8,
                    *(const u16x8*)(&As[(wm + 16 * mi + fr) * LDST + fk]));
#pragma unroll
            for (int ni = 0; ni < 4; ++ni)
                bfv[ni] = __builtin_bit_cast(bf16x8,
                    *(const u16x8*)(&Bs[(wn + 16 * ni + fr) * LDST + fk]));
#pragma unroll
            for (int mi = 0; mi < 2; ++mi)
#pragma unroll
                for (int ni = 0; ni < 4; ++ni)
                    acc[mi][ni] = __builtin_amdgcn_mfma_f32_16x16x32_bf16(
                        af[mi], bfv[ni], acc[mi][ni], 0, 0, 0);
        }
    }

    const int orow0 = row0 + wm + (lane >> 4) * 4;
    const int ocol0 = col0 + wn + fr;
#pragma unroll
    for (int mi = 0; mi < 2; ++mi) {
#pragma unroll
        for (int ni = 0; ni < 4; ++ni) {
            const int col = ocol0 + ni * 16;
            const float bv = bias ? bias[col] : 0.0f;
#pragma unroll
            for (int r = 0; r < 4; ++r) {
                const int row = orow0 + mi * 16 + r;
                float v = acc[mi][ni][r] + bv;
                if (residf) v += residf[(size_t)row * N + col];
                if (residb) v += bf2f(residb[(size_t)row * N + col]);
                Cbf[(size_t)row * ldcbf + cboff + col] = f2bf(v);
            }
        }
    }
}

__global__ __launch_bounds__(256) void gemm64(
    const u16* __restrict__ A, const u16* __restrict__ Bt, int N, int K,
    const float* __restrict__ bias,
    const float* __restrict__ residf, const u16* __restrict__ residb,
    u16* __restrict__ Cbf, int ldcbf)
{
    __shared__ u16 As[64 * LDST];
    __shared__ u16 Bs[128 * LDST];
    gemm64_core(A, Bt, N, K, K, bias, residf, residb, Cbf, ldcbf, 0,
                blockIdx.y * 64, blockIdx.x * 128, As, Bs);
}

// Split-K GEMM (gridDim.z = 2): bf16 partial to Pz = Cpair + z*MROWS*N.
__global__ __launch_bounds__(256) void gemm64_sk(
    const u16* __restrict__ A, const u16* __restrict__ Bt, int N, int Kstride,
    int Klen, u16* __restrict__ Cpair)
{
    __shared__ u16 As[64 * LDST];
    __shared__ u16 Bs[128 * LDST];
    const int z = blockIdx.z;
    const int koff = z * Klen;
    gemm64_core(A + koff, Bt + koff, N, Kstride, Klen,
                nullptr, nullptr, nullptr,
                Cpair + (size_t)z * MROWS * N, N, 0,
                blockIdx.y * 64, blockIdx.x * 128, As, Bs);
}

// ---------------------------------------------------------------------------
// Weight transposes (fp32 -> bf16, [K,N] -> [N,K])
// ---------------------------------------------------------------------------
static __device__ __forceinline__ void tcvt_body(
    const float* __restrict__ in, u16* __restrict__ out,
    int K, int N, int bx, int by)
{
    __shared__ float t[32][33];
    const int n0 = bx * 32, k0 = by * 32;
    const int tx = threadIdx.x & 31, ty = threadIdx.x >> 5;
#pragma unroll
    for (int j = 0; j < 4; ++j)
        t[ty + j * 8][tx] = in[(size_t)(k0 + ty + j * 8) * N + n0 + tx];
    __syncthreads();
#pragma unroll
    for (int j = 0; j < 4; ++j)
        out[(size_t)(n0 + ty + j * 8) * K + k0 + tx] = f2bf(t[tx][ty + j * 8]);
}

__global__ __launch_bounds__(256) void tcvt6_kernel(
    const float* __restrict__ w0, const float* __restrict__ w1,
    const float* __restrict__ w2, const float* __restrict__ w3,
    const float* __restrict__ w4, const float* __restrict__ w5,
    u16* __restrict__ Wm6)
{
    __shared__ float t[32][33];
    const int z = blockIdx.z;
    const int wi = z / 12, head = z % 12;
    const float* wsel = (wi == 0) ? w0 : (wi == 1) ? w1 : (wi == 2) ? w2 :
                        (wi == 3) ? w3 : (wi == 4) ? w4 : w5;
    const float* ib = wsel + (size_t)head * DD * DHD;
    u16* ob = Wm6 + (size_t)wi * WPC + (size_t)head * DHD * DD;
    const int n0 = blockIdx.x * 32, k0 = blockIdx.y * 32;
    const int tx = threadIdx.x & 31, ty = threadIdx.x >> 5;
#pragma unroll
    for (int j = 0; j < 4; ++j)
        t[ty + j * 8][tx] = ib[(size_t)(k0 + ty + j * 8) * DHD + n0 + tx];
    __syncthreads();
#pragma unroll
    for (int j = 0; j < 4; ++j)
        ob[(size_t)(n0 + ty + j * 8) * DD + k0 + tx] = f2bf(t[tx][ty + j * 8]);
}

__global__ __launch_bounds__(256) void tcvt4_kernel(
    const float* __restrict__ wom, const float* __restrict__ woc,
    const float* __restrict__ w1, const float* __restrict__ w2,
    u16* __restrict__ womt, u16* __restrict__ woct,
    u16* __restrict__ w1t, u16* __restrict__ w2t)
{
    const int fid = blockIdx.x;
    if (fid < 576) {
        tcvt_body(wom, womt, DD, DD, fid % 24, fid / 24);
    } else if (fid < 1152) {
        const int l = fid - 576;
        tcvt_body(woc, woct, DD, DD, l % 24, l / 24);
    } else if (fid < 3456) {
        const int l = fid - 1152;
        tcvt_body(w1, w1t, DD, FF, l % 96, l / 96);
    } else {
        const int l = fid - 3456;
        tcvt_body(w2, w2t, FF, DD, l % 24, l / 24);
    }
}

__global__ __launch_bounds__(256) void cvt3_kernel(
    const float* __restrict__ s0, const float* __restrict__ s1,
    const float* __restrict__ s2,
    u16* __restrict__ d0, u16* __restrict__ d1, u16* __restrict__ d2, int n4)
{
    const int z = blockIdx.z;
    const float* s = (z == 0) ? s0 : (z == 1) ? s1 : s2;
    u16* d = (z == 0) ? d0 : (z == 1) ? d1 : d2;
    const int i = blockIdx.x * 256 + threadIdx.x;
    if (i < n4) {
        float4 v = ((const float4*)s)[i];
        ushort4 o;
        o.x = f2bf(v.x); o.y = f2bf(v.y); o.z = f2bf(v.z); o.w = f2bf(v.w);
        ((ushort4*)d)[i] = o;
    }
}

// ---------------------------------------------------------------------------
// MFMA flash attention, max-free exp2 softmax, KVBLK=128 (validated R17).
// ---------------------------------------------------------------------------
#define KAST 72
#define PAST 136
#define CSC 0.18033688011112042f   // 0.125 * log2(e)
__global__ __launch_bounds__(256) void attn_mfma_kernel(
    const u16* __restrict__ Q, int ldq,
    const u16* __restrict__ K, const u16* __restrict__ V, int ldkv,
    const int* __restrict__ kmask, u16* __restrict__ O, int causal)
{
    const int qt = causal ? ((int)gridDim.x - 1 - (int)blockIdx.x) : (int)blockIdx.x;
    const int bh = blockIdx.y;
    const int b  = bh / HH;
    const int h  = bh % HH;
    const int tid  = threadIdx.x;
    const int lane = tid & 63;
    const int w    = tid >> 6;
    const int lr = lane & 15;
    const int lg = lane >> 4;

    __shared__ u16 KPs[128 * KAST];
    __shared__ u16 Vt[64 * PAST];

    const int row0 = qt * 64;
    const int q0w  = row0 + w * 16;

    bf16x8 qf[2];
    {
        const u16* qp = Q + (size_t)(b * SS + q0w + lr) * ldq + h * DHD + lg * 8;
        qf[0] = __builtin_bit_cast(bf16x8, *(const u16x8*)(qp));
        qf[1] = __builtin_bit_cast(bf16x8, *(const u16x8*)(qp + 32));
    }

    const int sr  = tid >> 1;
    const int scb = (tid & 1) * 32;
    const int vk  = tid >> 1;
    const int vdb = (tid & 1) * 32;
    const int k6  = vk & 63;
    const int vcol = ((vk >> 6) << 6) | ((k6 & 15) << 2) | (k6 >> 4);

    f32x4 acc[4] = {};
    float lsum[4] = {0.0f, 0.0f, 0.0f, 0.0f};

    const int nkt = causal ? ((qt + 2) >> 1) : 8;

    u16x8 kr0, kr1, kr2, kr3, vr0, vr1, vr2, vr3;
    {
        const u16* kp = K + (size_t)(b * SS + sr) * ldkv + h * DHD + scb;
        kr0 = *(const u16x8*)(kp);
        kr1 = *(const u16x8*)(kp + 8);
        kr2 = *(const u16x8*)(kp + 16);
        kr3 = *(const u16x8*)(kp + 24);
        const u16* vp = V + (size_t)(b * SS + vk) * ldkv + h * DHD + vdb;
        vr0 = *(const u16x8*)(vp);
        vr1 = *(const u16x8*)(vp + 8);
        vr2 = *(const u16x8*)(vp + 16);
        vr3 = *(const u16x8*)(vp + 24);
    }

    for (int kt = 0; kt < nkt; ++kt) {
        const int kcol0 = kt * 128;
        if (kt) __syncthreads();

        *(u16x8*)(&KPs[sr * KAST + scb])      = kr0;
        *(u16x8*)(&KPs[sr * KAST + scb + 8])  = kr1;
        *(u16x8*)(&KPs[sr * KAST + scb + 16]) = kr2;
        *(u16x8*)(&KPs[sr * KAST + scb + 24]) = kr3;
#pragma unroll
        for (int j = 0; j < 8; ++j) Vt[(vdb + j) * PAST + vcol]      = vr0[j];
#pragma unroll
        for (int j = 0; j < 8; ++j) Vt[(vdb + 8 + j) * PAST + vcol]  = vr1[j];
#pragma unroll
        for (int j = 0; j < 8; ++j) Vt[(vdb + 16 + j) * PAST + vcol] = vr2[j];
#pragma unroll
        for (int j = 0; j < 8; ++j) Vt[(vdb + 24 + j) * PAST + vcol] = vr3[j];
        __syncthreads();

        if (kt + 1 < nkt) {
            const int kn = kcol0 + 128;
            const u16* kp = K + (size_t)(b * SS + kn + sr) * ldkv + h * DHD + scb;
            kr0 = *(const u16x8*)(kp);
            kr1 = *(const u16x8*)(kp + 8);
            kr2 = *(const u16x8*)(kp + 16);
            kr3 = *(const u16x8*)(kp + 24);
            const u16* vp = V + (size_t)(b * SS + kn + vk) * ldkv + h * DHD + vdb;
            vr0 = *(const u16x8*)(vp);
            vr1 = *(const u16x8*)(vp + 8);
            vr2 = *(const u16x8*)(vp + 16);
            vr3 = *(const u16x8*)(vp + 24);
        }

        f32x4 s[8] = {};
#pragma unroll
        for (int fi = 0; fi < 8; ++fi) {
            bf16x8 kf0 = __builtin_bit_cast(bf16x8, *(const u16x8*)(&KPs[(fi * 16 + lr) * KAST + lg * 8]));
            bf16x8 kf1 = __builtin_bit_cast(bf16x8, *(const u16x8*)(&KPs[(fi * 16 + lr) * KAST + 32 + lg * 8]));
            s[fi] = __builtin_amdgcn_mfma_f32_16x16x32_bf16(qf[0], kf0, s[fi], 0, 0, 0);
            s[fi] = __builtin_amdgcn_mfma_f32_16x16x32_bf16(qf[1], kf1, s[fi], 0, 0, 0);
        }
        __syncthreads();

        float biasf[8];
#pragma unroll
        for (int fi = 0; fi < 8; ++fi)
            biasf[fi] = kmask[b * SS + kcol0 + fi * 16 + lr] ? 0.0f : -INFINITY;
        const bool diag = (causal != 0) && (kt == nkt - 1);

#pragma unroll
        for (int r = 0; r < 4; ++r) {
            const int qrow = q0w + lg * 4 + r;
            const int prow = (w * 16 + lg * 4 + r) * PAST;
            u16x4 pk0, pk1;
            float rs = 0.0f;
#pragma unroll
            for (int fi = 0; fi < 8; ++fi) {
                float v = fmaf(s[fi][r], CSC, biasf[fi]);
                if (diag) {
                    const int key = kcol0 + fi * 16 + lr;
                    v = (key <= qrow) ? v : -INFINITY;
                }
                const float pv = exp2f(v);
                if (fi < 4) pk0[fi] = f2bf(pv); else pk1[fi - 4] = f2bf(pv);
                rs += pv;
            }
            lsum[r] += rs;
            *(u16x4*)(&KPs[prow + lr * 4])      = pk0;
            *(u16x4*)(&KPs[prow + 64 + lr * 4]) = pk1;
        }

#pragma unroll
        for (int kk = 0; kk < 4; ++kk) {
            bf16x8 pf = __builtin_bit_cast(bf16x8, *(const u16x8*)(&KPs[(w * 16 + lr) * PAST + kk * 32 + lg * 8]));
#pragma unroll
            for (int di = 0; di < 4; ++di) {
                bf16x8 vf = __builtin_bit_cast(bf16x8, *(const u16x8*)(&Vt[(di * 16 + lr) * PAST + kk * 32 + lg * 8]));
                acc[di] = __builtin_amdgcn_mfma_f32_16x16x32_bf16(pf, vf, acc[di], 0, 0, 0);
            }
        }
    }

#pragma unroll
    for (int r = 0; r < 4; ++r) {
        float l = lsum[r];
        l += __shfl_xor(l, 1);
        l += __shfl_xor(l, 2);
        l += __shfl_xor(l, 4);
        l += __shfl_xor(l, 8);
        const float inv = (l > 0.0f) ? (1.0f / l) : 0.0f;
        const size_t orow = (size_t)(b * SS + q0w + lg * 4 + r) * DD + h * DHD;
#pragma unroll
        for (int di = 0; di < 4; ++di)
            O[orow + di * 16 + lr] = f2bf(acc[di][r] * inv);
    }
}

// ---------------------------------------------------------------------------
// LayerNorm over last dim (768), bf16 input -> bf16 output.
// ---------------------------------------------------------------------------
__global__ __launch_bounds__(256) void ln_bf_kernel(
    const u16* __restrict__ X, const float* __restrict__ gma,
    const float* __restrict__ bta, u16* __restrict__ Ybf)
{
    const int row = blockIdx.x;
    const int tid = threadIdx.x;
    const u16* x = X + (size_t)row * DD;

    const float v0 = bf2f(x[tid]);
    const float v1 = bf2f(x[tid + 256]);
    const float v2 = bf2f(x[tid + 512]);

    __shared__ float sd[256];
    sd[tid] = v0 + v1 + v2;
    __syncthreads();
    for (int off = 128; off > 0; off >>= 1) {
        if (tid < off) sd[tid] += sd[tid + off];
        __syncthreads();
    }
    const float mean = sd[0] * (1.0f / 768.0f);
    __syncthreads();

    const float q0 = v0 - mean, q1 = v1 - mean, q2 = v2 - mean;
    sd[tid] = q0 * q0 + q1 * q1 + q2 * q2;
    __syncthreads();
    for (int off = 128; off > 0; off >>= 1) {
        if (tid < off) sd[tid] += sd[tid + off];
        __syncthreads();
    }
    const float var = sd[0] * (1.0f / 768.0f);
    const float inv = rsqrtf(var + 1e-5f);

    u16* yb = Ybf + (size_t)row * DD;
    yb[tid]       = f2bf(q0 * inv * gma[tid]       + bta[tid]);
    yb[tid + 256] = f2bf(q1 * inv * gma[tid + 256] + bta[tid + 256]);
    yb[tid + 512] = f2bf(q2 * inv * gma[tid + 512] + bta[tid + 512]);
}

// ---------------------------------------------------------------------------
// LayerNorm over (P0 + P1 + bias + resid_bf16) -> fp32 out (final).
// ---------------------------------------------------------------------------
__global__ __launch_bounds__(256) void ln_red_kernel(
    const u16* __restrict__ P0, const u16* __restrict__ P1,
    const float* __restrict__ bias, const u16* __restrict__ resid,
    const float* __restrict__ gma, const float* __restrict__ bta,
    float* __restrict__ Y)
{
    const int row = blockIdx.x;
    const int tid = threadIdx.x;
    const size_t base = (size_t)row * DD;

    float v[3];
#pragma unroll
    for (int j = 0; j < 3; ++j) {
        const int i = tid + j * 256;
        v[j] = bf2f(P0[base + i]) + bf2f(P1[base + i]) + bias[i] + bf2f(resid[base + i]);
    }

    __shared__ float sd[256];
    sd[tid] = v[0] + v[1] + v[2];
    __syncthreads();
    for (int off = 128; off > 0; off >>= 1) {
        if (tid < off) sd[tid] += sd[tid + off];
        __syncthreads();
    }
    const float mean = sd[0] * (1.0f / 768.0f);
    __syncthreads();

    float q[3];
#pragma unroll
    for (int j = 0; j < 3; ++j) q[j] = v[j] - mean;
    sd[tid] = q[0] * q[0] + q[1] * q[1] + q[2] * q[2];
    __syncthreads();
    for (int off = 128; off > 0; off >>= 1) {
        if (tid < off) sd[tid] += sd[tid + off];
        __syncthreads();
    }
    const float var = sd[0] * (1.0f / 768.0f);
    const float inv = rsqrtf(var + 1e-5f);

    float* y = Y + base;
#pragma unroll
    for (int j = 0; j < 3; ++j) {
        const int i = tid + j * 256;
        y[i] = q[j] * inv * gma[i] + bta[i];
    }
}

// ---------------------------------------------------------------------------
extern "C" void kernel_launch(void* const* d_in, const int* in_sizes, int n_in,
                              void* d_out, int out_size, void* d_ws, size_t ws_size,
                              hipStream_t stream)
{
    (void)in_sizes; (void)n_in; (void)out_size; (void)ws_size;

    const float* key_enc   = (const float*)d_in[0];
    const float* value_enc = (const float*)d_in[1];
    const float* x         = (const float*)d_in[2];
    const int*   src_mask  = (const int*)d_in[3];
    const int*   tgt_mask  = (const int*)d_in[4];
    const float* Wq_m = (const float*)d_in[5];
    const float* Wk_m = (const float*)d_in[6];
    const float* Wv_m = (const float*)d_in[7];
    const float* Wo_m = (const float*)d_in[8];
    const float* Wq_c = (const float*)d_in[9];
    const float* Wk_c = (const float*)d_in[10];
    const float* Wv_c = (const float*)d_in[11];
    const float* Wo_c = (const float*)d_in[12];
    const float* ln1_g = (const float*)d_in[13];
    const float* ln1_b = (const float*)d_in[14];
    const float* ln2_g = (const float*)d_in[15];
    const float* ln2_b = (const float*)d_in[16];
    const float* ln3_g = (const float*)d_in[17];
    const float* ln3_b = (const float*)d_in[18];
    const float* W1 = (const float*)d_in[19];
    const float* b1 = (const float*)d_in[20];
    const float* W2 = (const float*)d_in[21];
    const float* b2 = (const float*)d_in[22];

    float* out = (float*)d_out;

    // workspace layout
    const size_t ACT = (size_t)MROWS * DD;
    char* p = (char*)d_ws;
    u16* QKV  = (u16*)p;   p += 3 * ACT * 2;
    u16* BFx  = (u16*)p;   p += ACT * 2;
    u16* BFK  = (u16*)p;   p += ACT * 2;
    u16* BFV  = (u16*)p;   p += ACT * 2;
    u16* BF1a = (u16*)p;   p += ACT * 2;
    u16* BF1h = (u16*)p;   p += ACT * 2;
    u16* T2bf = (u16*)p;   p += ACT * 2;           // bf16 pre-LN
    u16* SKKV = (u16*)p;   p += 2 * ACT * 2;       // cross-KV | MLP2 partials
    u16* Wm6  = (u16*)p;   p += 6 * (size_t)WPC * 2;
    u16* Wom_t = (u16*)p;  p += (size_t)WPC * 2;
    u16* Woc_t = (u16*)p;  p += (size_t)WPC * 2;
    u16* W1t  = (u16*)p;   p += (size_t)DD * FF * 2;
    u16* W2t  = (u16*)p;   p += (size_t)DD * FF * 2;
    u16* MID  = QKV;       // [4096][3072] bf16 aliases QKV+BFx (dead by MLP)
    u16* KVc  = SKKV;      // [4096][1536] bf16 cross K|V (dead by MLP2)
    u16* SK0  = SKKV;      // [4096][768] bf16 MLP2 partial 0
    u16* SK1  = SKKV + ACT;

    const dim3 blk(256);
    const int nc4 = (int)(ACT / 4);

    // Prep (3 dispatches)
    cvt3_kernel<<<dim3(nc4 / 256, 1, 3), blk, 0, stream>>>(
        x, key_enc, value_enc, BFx, BFK, BFV, nc4);
    tcvt6_kernel<<<dim3(2, 24, 72), blk, 0, stream>>>(
        Wq_m, Wk_m, Wv_m, Wq_c, Wk_c, Wv_c, Wm6);
    tcvt4_kernel<<<dim3(5760), blk, 0, stream>>>(
        Wo_m, Wo_c, W1, W2, Wom_t, Woc_t, W1t, W2t);

    const dim3 gProj(960);        // self QKV + cross K/V batched
    const dim3 gQc(6, 64);        // cross Q (64x128 tiles)
    const dim3 gP(6, 64);         // Wo (64x128 tiles)
    const dim3 gM1(24, 32);       // MLP1 128x128
    const dim3 gM2(6, 64, 2);     // MLP2 split-K
    const dim3 gAttn(16, BB * HH);

    gemm128_proj<<<gProj, blk, 0, stream>>>(BFx, BFK, BFV, Wm6, QKV, KVc);

    // Self-attention
    attn_mfma_kernel<<<gAttn, blk, 0, stream>>>(
        QKV, 3 * DD, QKV + DD, QKV + 2 * DD, 3 * DD, tgt_mask, BF1a, 1);
    gemm64<<<gP, blk, 0, stream>>>(BF1a, Wom_t, DD, DD,
                                   nullptr, x, nullptr, T2bf, DD);
    ln_bf_kernel<<<MROWS, blk, 0, stream>>>(T2bf, ln1_g, ln1_b, BF1h);

    // Cross-attention (K/V already in KVc)
    gemm64<<<gQc, blk, 0, stream>>>(BF1h, Wm6 + 3 * WPC, DD, DD,
                                    nullptr, nullptr, nullptr, QKV, 3 * DD);
    attn_mfma_kernel<<<gAttn, blk, 0, stream>>>(
        QKV, 3 * DD, KVc, KVc + DD, 2 * DD, src_mask, BF1a, 0);
    gemm64<<<gP, blk, 0, stream>>>(BF1a, Woc_t, DD, DD,
                                   nullptr, nullptr, BF1h, T2bf, DD);
    ln_bf_kernel<<<MROWS, blk, 0, stream>>>(T2bf, ln2_g, ln2_b, BF1h);

    // MLP
    gemm128<<<gM1, blk, 0, stream>>>(BF1h, W1t, DD, b1, 1, MID, FF);
    gemm64_sk<<<gM2, blk, 0, stream>>>(MID, W2t, DD, FF, FF / 2, SKKV);
    ln_red_kernel<<<MROWS, blk, 0, stream>>>(SK0, SK1, b2, BF1h,
                                             ln3_g, ln3_b, out);
}

// Round 20
// 294.982 us; speedup vs baseline: 1.1443x; 1.0688x over previous
//
#include <hip/hip_runtime.h>
#include <math.h>

// Problem constants
#define BB 4
#define SS 1024
#define DD 768
#define HH 12
#define DHD 64
#define MROWS 4096
#define FF 3072
#define WPC (DD * DD)

typedef unsigned short u16;
typedef float f32x4 __attribute__((ext_vector_type(4)));
typedef __bf16 bf16x8 __attribute__((ext_vector_type(8)));
typedef unsigned short u16x8 __attribute__((ext_vector_type(8)));
typedef unsigned short u16x4 __attribute__((ext_vector_type(4)));

static __device__ __forceinline__ float bf2f(u16 u) {
    union { unsigned int i; float f; } c; c.i = ((unsigned int)u) << 16; return c.f;
}
static __device__ __forceinline__ u16 f2bf(float f) {
    return __builtin_bit_cast(u16, static_cast<__bf16>(f));
}
// XCD-chunked swizzle: flat grid, total % 8 == 0. Consecutive LOGICAL ids
// run on the same XCD (8 contiguous chunks), so blocks sharing operand
// panels hit the same L2.
static __device__ __forceinline__ int xcd_swz(int total) {
    const int bid = (int)blockIdx.x;
    return (bid & 7) * (total >> 3) + (bid >> 3);
}

#define LDST 40

// ---------------------------------------------------------------------------
// 128x128-tile bf16 MFMA GEMM core (depth-2 explicit unroll). K % 64 == 0.
// ---------------------------------------------------------------------------
static __device__ __forceinline__ void gemm128_core(
    const u16* __restrict__ A, const u16* __restrict__ Bt,
    int K,
    const float* __restrict__ bias, int do_gelu,
    u16* __restrict__ Cbf, int ldcbf, int cboff,
    int row0, int col0, u16* As, u16* Bs)
{
    const int tid  = threadIdx.x;
    const int lane = tid & 63;
    const int w    = tid >> 6;
    const int wm = (w >> 1) * 64;
    const int wn = (w & 1) * 64;

    const int srow = tid >> 1;
    const int skc  = (tid & 1) * 16;

    const u16* Ap = A  + (size_t)(row0 + srow) * K + skc;
    const u16* Bp = Bt + (size_t)(col0 + srow) * K + skc;
    u16* AsW = &As[srow * LDST + skc];
    u16* BsW = &Bs[srow * LDST + skc];

    const int fr = lane & 15;
    const int fk = (lane >> 4) * 8;

    f32x4 acc[4][4] = {};

    u16x8 aa0, aa1, ba0, ba1;
    u16x8 ab0, ab1, bb0, bb1;
    aa0 = *(const u16x8*)(Ap);
    aa1 = *(const u16x8*)(Ap + 8);
    ba0 = *(const u16x8*)(Bp);
    ba1 = *(const u16x8*)(Bp + 8);
    ab0 = *(const u16x8*)(Ap + 32);
    ab1 = *(const u16x8*)(Ap + 40);
    bb0 = *(const u16x8*)(Bp + 32);
    bb1 = *(const u16x8*)(Bp + 40);

    for (int k0 = 0; k0 < K; k0 += 64) {
        if (k0) __syncthreads();
        *(u16x8*)(AsW)     = aa0;
        *(u16x8*)(AsW + 8) = aa1;
        *(u16x8*)(BsW)     = ba0;
        *(u16x8*)(BsW + 8) = ba1;
        __syncthreads();
        if (k0 + 64 < K) {
            aa0 = *(const u16x8*)(Ap + k0 + 64);
            aa1 = *(const u16x8*)(Ap + k0 + 72);
            ba0 = *(const u16x8*)(Bp + k0 + 64);
            ba1 = *(const u16x8*)(Bp + k0 + 72);
        }
        {
            bf16x8 af[4], bfv[4];
#pragma unroll
            for (int mi = 0; mi < 4; ++mi)
                af[mi] = __builtin_bit_cast(bf16x8,
                    *(const u16x8*)(&As[(wm + 16 * mi + fr) * LDST + fk]));
#pragma unroll
            for (int ni = 0; ni < 4; ++ni)
                bfv[ni] = __builtin_bit_cast(bf16x8,
                    *(const u16x8*)(&Bs[(wn + 16 * ni + fr) * LDST + fk]));
#pragma unroll
            for (int mi = 0; mi < 4; ++mi)
#pragma unroll
                for (int ni = 0; ni < 4; ++ni)
                    acc[mi][ni] = __builtin_amdgcn_mfma_f32_16x16x32_bf16(
                        af[mi], bfv[ni], acc[mi][ni], 0, 0, 0);
        }

        __syncthreads();
        *(u16x8*)(AsW)     = ab0;
        *(u16x8*)(AsW + 8) = ab1;
        *(u16x8*)(BsW)     = bb0;
        *(u16x8*)(BsW + 8) = bb1;
        __syncthreads();
        if (k0 + 96 < K) {
            ab0 = *(const u16x8*)(Ap + k0 + 96);
            ab1 = *(const u16x8*)(Ap + k0 + 104);
            bb0 = *(const u16x8*)(Bp + k0 + 96);
            bb1 = *(const u16x8*)(Bp + k0 + 104);
        }
        {
            bf16x8 af[4], bfv[4];
#pragma unroll
            for (int mi = 0; mi < 4; ++mi)
                af[mi] = __builtin_bit_cast(bf16x8,
                    *(const u16x8*)(&As[(wm + 16 * mi + fr) * LDST + fk]));
#pragma unroll
            for (int ni = 0; ni < 4; ++ni)
                bfv[ni] = __builtin_bit_cast(bf16x8,
                    *(const u16x8*)(&Bs[(wn + 16 * ni + fr) * LDST + fk]));
#pragma unroll
            for (int mi = 0; mi < 4; ++mi)
#pragma unroll
                for (int ni = 0; ni < 4; ++ni)
                    acc[mi][ni] = __builtin_amdgcn_mfma_f32_16x16x32_bf16(
                        af[mi], bfv[ni], acc[mi][ni], 0, 0, 0);
        }
    }

    const int orow0 = row0 + wm + (lane >> 4) * 4;
    const int ocol0 = col0 + wn + fr;
#pragma unroll
    for (int mi = 0; mi < 4; ++mi) {
#pragma unroll
        for (int ni = 0; ni < 4; ++ni) {
            const int col = ocol0 + ni * 16;
            const float bv = bias ? bias[col] : 0.0f;
#pragma unroll
            for (int r = 0; r < 4; ++r) {
                const int row = orow0 + mi * 16 + r;
                float v = acc[mi][ni][r] + bv;
                if (do_gelu) v = 0.5f * v * (1.0f + erff(v * 0.70710678118654752f));
                Cbf[(size_t)row * ldcbf + cboff + col] = f2bf(v);
            }
        }
    }
}

// MLP1: flat 768-block grid (24 x-tiles, 32 y-tiles), XCD-swizzled.
__global__ __launch_bounds__(256) void gemm128_mlp1(
    const u16* __restrict__ A, const u16* __restrict__ Bt,
    const float* __restrict__ bias, u16* __restrict__ Cbf)
{
    __shared__ u16 As[128 * LDST];
    __shared__ u16 Bs[128 * LDST];
    const int lid = xcd_swz(24 * 32);
    gemm128_core(A, Bt, DD, bias, 1, Cbf, FF, 0,
                 (lid / 24) * 128, (lid % 24) * 128, As, Bs);
}

// Batched independent projections, flat 960-block grid, XCD-swizzled.
__global__ __launch_bounds__(256) void gemm128_proj(
    const u16* __restrict__ BFx, const u16* __restrict__ BFK,
    const u16* __restrict__ BFV, const u16* __restrict__ Wm6,
    u16* __restrict__ QKV, u16* __restrict__ KVc)
{
    __shared__ u16 As[128 * LDST];
    __shared__ u16 Bs[128 * LDST];
    const int fid = xcd_swz(960);
    const u16* A; const u16* B; u16* C; int ldc, coff, row0, col0;
    if (fid < 576) {
        A = BFx; B = Wm6; C = QKV; ldc = 3 * DD; coff = 0;
        row0 = (fid / 18) * 128; col0 = (fid % 18) * 128;
    } else if (fid < 768) {
        const int l = fid - 576;
        A = BFK; B = Wm6 + 4 * WPC; C = KVc; ldc = 2 * DD; coff = 0;
        row0 = (l / 6) * 128; col0 = (l % 6) * 128;
    } else {
        const int l = fid - 768;
        A = BFV; B = Wm6 + 5 * WPC; C = KVc; ldc = 2 * DD; coff = DD;
        row0 = (l / 6) * 128; col0 = (l % 6) * 128;
    }
    gemm128_core(A, B, DD, nullptr, 0, C, ldc, coff, row0, col0, As, Bs);
}

// ---------------------------------------------------------------------------
// 64x128-tile GEMM core. Depth-2 unroll. All outputs bf16.
// ---------------------------------------------------------------------------
static __device__ __forceinline__ void gemm64_core(
    const u16* __restrict__ A, const u16* __restrict__ Bt,
    int N, int Kstride, int Klen,
    const float* __restrict__ bias,
    const float* __restrict__ residf, const u16* __restrict__ residb,
    u16* __restrict__ Cbf, int ldcbf, int cboff,
    int row0, int col0, u16* As, u16* Bs)
{
    const int tid  = threadIdx.x;
    const int lane = tid & 63;
    const int w    = tid >> 6;
    const int wm = (w >> 1) * 32;
    const int wn = (w & 1) * 64;

    const int arow = tid >> 2;
    const int akc  = (tid & 3) * 8;
    const int brow = tid >> 1;
    const int bkc  = (tid & 1) * 16;

    const u16* Ap = A  + (size_t)(row0 + arow) * Kstride + akc;
    const u16* Bp = Bt + (size_t)(col0 + brow) * Kstride + bkc;
    u16* AsW = &As[arow * LDST + akc];
    u16* BsW = &Bs[brow * LDST + bkc];

    const int fr = lane & 15;
    const int fk = (lane >> 4) * 8;

    f32x4 acc[2][4] = {};

    u16x8 a0, b00, b01, a1, b10, b11;
    a0  = *(const u16x8*)(Ap);
    b00 = *(const u16x8*)(Bp);
    b01 = *(const u16x8*)(Bp + 8);
    a1  = *(const u16x8*)(Ap + 32);
    b10 = *(const u16x8*)(Bp + 32);
    b11 = *(const u16x8*)(Bp + 40);

    for (int k0 = 0; k0 < Klen; k0 += 64) {
        if (k0) __syncthreads();
        *(u16x8*)AsW       = a0;
        *(u16x8*)BsW       = b00;
        *(u16x8*)(BsW + 8) = b01;
        __syncthreads();
        if (k0 + 64 < Klen) {
            a0  = *(const u16x8*)(Ap + k0 + 64);
            b00 = *(const u16x8*)(Bp + k0 + 64);
            b01 = *(const u16x8*)(Bp + k0 + 72);
        }
        {
            bf16x8 af[2], bfv[4];
#pragma unroll
            for (int mi = 0; mi < 2; ++mi)
                af[mi] = __builtin_bit_cast(bf16x8,
                    *(const u16x8*)(&As[(wm + 16 * mi + fr) * LDST + fk]));
#pragma unroll
            for (int ni = 0; ni < 4; ++ni)
                bfv[ni] = __builtin_bit_cast(bf16x8,
                    *(const u16x8*)(&Bs[(wn + 16 * ni + fr) * LDST + fk]));
#pragma unroll
            for (int mi = 0; mi < 2; ++mi)
#pragma unroll
                for (int ni = 0; ni < 4; ++ni)
                    acc[mi][ni] = __builtin_amdgcn_mfma_f32_16x16x32_bf16(
                        af[mi], bfv[ni], acc[mi][ni], 0, 0, 0);
        }

        __syncthreads();
        *(u16x8*)AsW       = a1;
        *(u16x8*)BsW       = b10;
        *(u16x8*)(BsW + 8) = b11;
        __syncthreads();
        if (k0 + 96 < Klen) {
            a1  = *(const u16x8*)(Ap + k0 + 96);
            b10 = *(const u16x8*)(Bp + k0 + 96);
            b11 = *(const u16x8*)(Bp + k0 + 104);
        }
        {
            bf16x8 af[2], bfv[4];
#pragma unroll
            for (int mi = 0; mi < 2; ++mi)
                af[mi] = __builtin_bit_cast(bf16x8,
                    *(const u16x8*)(&As[(wm + 16 * mi + fr) * LDST + fk]));
#pragma unroll
            for (int ni = 0; ni < 4; ++ni)
                bfv[ni] = __builtin_bit_cast(bf16x8,
                    *(const u16x8*)(&Bs[(wn + 16 * ni + fr) * LDST + fk]));
#pragma unroll
            for (int mi = 0; mi < 2; ++mi)
#pragma unroll
                for (int ni = 0; ni < 4; ++ni)
                    acc[mi][ni] = __builtin_amdgcn_mfma_f32_16x16x32_bf16(
                        af[mi], bfv[ni], acc[mi][ni], 0, 0, 0);
        }
    }

    const int orow0 = row0 + wm + (lane >> 4) * 4;
    const int ocol0 = col0 + wn + fr;
#pragma unroll
    for (int mi = 0; mi < 2; ++mi) {
#pragma unroll
        for (int ni = 0; ni < 4; ++ni) {
            const int col = ocol0 + ni * 16;
            const float bv = bias ? bias[col] : 0.0f;
#pragma unroll
            for (int r = 0; r < 4; ++r) {
                const int row = orow0 + mi * 16 + r;
                float v = acc[mi][ni][r] + bv;
                if (residf) v += residf[(size_t)row * N + col];
                if (residb) v += bf2f(residb[(size_t)row * N + col]);
                Cbf[(size_t)row * ldcbf + cboff + col] = f2bf(v);
            }
        }
    }
}

// N=768 skinny GEMM, flat 384-block grid (6 x-tiles, 64 y-tiles), swizzled.
__global__ __launch_bounds__(256) void gemm64(
    const u16* __restrict__ A, const u16* __restrict__ Bt, int K,
    const float* __restrict__ residf, const u16* __restrict__ residb,
    u16* __restrict__ Cbf, int ldcbf)
{
    __shared__ u16 As[64 * LDST];
    __shared__ u16 Bs[128 * LDST];
    const int lid = xcd_swz(6 * 64);
    gemm64_core(A, Bt, DD, K, K, nullptr, residf, residb, Cbf, ldcbf, 0,
                (lid / 6) * 64, (lid % 6) * 128, As, Bs);
}

// Split-K MLP2: flat 768-block grid (6 x, 64 y, 2 z), swizzled; bf16 partials.
__global__ __launch_bounds__(256) void gemm64_sk(
    const u16* __restrict__ A, const u16* __restrict__ Bt,
    u16* __restrict__ Cpair)
{
    __shared__ u16 As[64 * LDST];
    __shared__ u16 Bs[128 * LDST];
    const int lid = xcd_swz(6 * 64 * 2);
    const int x = lid % 6;
    const int rem = lid / 6;
    const int y = rem % 64;
    const int z = rem / 64;
    const int koff = z * (FF / 2);
    gemm64_core(A + koff, Bt + koff, DD, FF, FF / 2,
                nullptr, nullptr, nullptr,
                Cpair + (size_t)z * MROWS * DD, DD, 0,
                y * 64, x * 128, As, Bs);
}

// ---------------------------------------------------------------------------
// Weight transposes (fp32 -> bf16, [K,N] -> [N,K])
// ---------------------------------------------------------------------------
static __device__ __forceinline__ void tcvt_body(
    const float* __restrict__ in, u16* __restrict__ out,
    int K, int N, int bx, int by)
{
    __shared__ float t[32][33];
    const int n0 = bx * 32, k0 = by * 32;
    const int tx = threadIdx.x & 31, ty = threadIdx.x >> 5;
#pragma unroll
    for (int j = 0; j < 4; ++j)
        t[ty + j * 8][tx] = in[(size_t)(k0 + ty + j * 8) * N + n0 + tx];
    __syncthreads();
#pragma unroll
    for (int j = 0; j < 4; ++j)
        out[(size_t)(n0 + ty + j * 8) * K + k0 + tx] = f2bf(t[tx][ty + j * 8]);
}

__global__ __launch_bounds__(256) void tcvt6_kernel(
    const float* __restrict__ w0, const float* __restrict__ w1,
    const float* __restrict__ w2, const float* __restrict__ w3,
    const float* __restrict__ w4, const float* __restrict__ w5,
    u16* __restrict__ Wm6)
{
    __shared__ float t[32][33];
    const int z = blockIdx.z;
    const int wi = z / 12, head = z % 12;
    const float* wsel = (wi == 0) ? w0 : (wi == 1) ? w1 : (wi == 2) ? w2 :
                        (wi == 3) ? w3 : (wi == 4) ? w4 : w5;
    const float* ib = wsel + (size_t)head * DD * DHD;
    u16* ob = Wm6 + (size_t)wi * WPC + (size_t)head * DHD * DD;
    const int n0 = blockIdx.x * 32, k0 = blockIdx.y * 32;
    const int tx = threadIdx.x & 31, ty = threadIdx.x >> 5;
#pragma unroll
    for (int j = 0; j < 4; ++j)
        t[ty + j * 8][tx] = ib[(size_t)(k0 + ty + j * 8) * DHD + n0 + tx];
    __syncthreads();
#pragma unroll
    for (int j = 0; j < 4; ++j)
        ob[(size_t)(n0 + ty + j * 8) * DD + k0 + tx] = f2bf(t[tx][ty + j * 8]);
}

__global__ __launch_bounds__(256) void tcvt4_kernel(
    const float* __restrict__ wom, const float* __restrict__ woc,
    const float* __restrict__ w1, const float* __restrict__ w2,
    u16* __restrict__ womt, u16* __restrict__ woct,
    u16* __restrict__ w1t, u16* __restrict__ w2t)
{
    const int fid = blockIdx.x;
    if (fid < 576) {
        tcvt_body(wom, womt, DD, DD, fid % 24, fid / 24);
    } else if (fid < 1152) {
        const int l = fid - 576;
        tcvt_body(woc, woct, DD, DD, l % 24, l / 24);
    } else if (fid < 3456) {
        const int l = fid - 1152;
        tcvt_body(w1, w1t, DD, FF, l % 96, l / 96);
    } else {
        const int l = fid - 3456;
        tcvt_body(w2, w2t, FF, DD, l % 24, l / 24);
    }
}

__global__ __launch_bounds__(256) void cvt3_kernel(
    const float* __restrict__ s0, const float* __restrict__ s1,
    const float* __restrict__ s2,
    u16* __restrict__ d0, u16* __restrict__ d1, u16* __restrict__ d2, int n4)
{
    const int z = blockIdx.z;
    const float* s = (z == 0) ? s0 : (z == 1) ? s1 : s2;
    u16* d = (z == 0) ? d0 : (z == 1) ? d1 : d2;
    const int i = blockIdx.x * 256 + threadIdx.x;
    if (i < n4) {
        float4 v = ((const float4*)s)[i];
        ushort4 o;
        o.x = f2bf(v.x); o.y = f2bf(v.y); o.z = f2bf(v.z); o.w = f2bf(v.w);
        ((ushort4*)d)[i] = o;
    }
}

// ---------------------------------------------------------------------------
// MFMA flash attention, max-free exp2 softmax, KVBLK=128 (validated R17).
// Flat 768-block grid, XCD-swizzled (16 qt consecutive per bh -> K/V L2
// locality per XCD).
// ---------------------------------------------------------------------------
#define KAST 72
#define PAST 136
#define CSC 0.18033688011112042f   // 0.125 * log2(e)
__global__ __launch_bounds__(256) void attn_mfma_kernel(
    const u16* __restrict__ Q, int ldq,
    const u16* __restrict__ K, const u16* __restrict__ V, int ldkv,
    const int* __restrict__ kmask, u16* __restrict__ O, int causal)
{
    const int lid = xcd_swz(16 * BB * HH);
    const int qtl = lid % 16;
    const int bh  = lid / 16;
    const int qt = causal ? (15 - qtl) : qtl;
    const int b  = bh / HH;
    const int h  = bh % HH;
    const int tid  = threadIdx.x;
    const int lane = tid & 63;
    const int w    = tid >> 6;
    const int lr = lane & 15;
    const int lg = lane >> 4;

    __shared__ u16 KPs[128 * KAST];
    __shared__ u16 Vt[64 * PAST];

    const int row0 = qt * 64;
    const int q0w  = row0 + w * 16;

    bf16x8 qf[2];
    {
        const u16* qp = Q + (size_t)(b * SS + q0w + lr) * ldq + h * DHD + lg * 8;
        qf[0] = __builtin_bit_cast(bf16x8, *(const u16x8*)(qp));
        qf[1] = __builtin_bit_cast(bf16x8, *(const u16x8*)(qp + 32));
    }

    const int sr  = tid >> 1;
    const int scb = (tid & 1) * 32;
    const int vk  = tid >> 1;
    const int vdb = (tid & 1) * 32;
    const int k6  = vk & 63;
    const int vcol = ((vk >> 6) << 6) | ((k6 & 15) << 2) | (k6 >> 4);

    f32x4 acc[4] = {};
    float lsum[4] = {0.0f, 0.0f, 0.0f, 0.0f};

    const int nkt = causal ? ((qt + 2) >> 1) : 8;

    u16x8 kr0, kr1, kr2, kr3, vr0, vr1, vr2, vr3;
    {
        const u16* kp = K + (size_t)(b * SS + sr) * ldkv + h * DHD + scb;
        kr0 = *(const u16x8*)(kp);
        kr1 = *(const u16x8*)(kp + 8);
        kr2 = *(const u16x8*)(kp + 16);
        kr3 = *(const u16x8*)(kp + 24);
        const u16* vp = V + (size_t)(b * SS + vk) * ldkv + h * DHD + vdb;
        vr0 = *(const u16x8*)(vp);
        vr1 = *(const u16x8*)(vp + 8);
        vr2 = *(const u16x8*)(vp + 16);
        vr3 = *(const u16x8*)(vp + 24);
    }

    for (int kt = 0; kt < nkt; ++kt) {
        const int kcol0 = kt * 128;
        if (kt) __syncthreads();

        *(u16x8*)(&KPs[sr * KAST + scb])      = kr0;
        *(u16x8*)(&KPs[sr * KAST + scb + 8])  = kr1;
        *(u16x8*)(&KPs[sr * KAST + scb + 16]) = kr2;
        *(u16x8*)(&KPs[sr * KAST + scb + 24]) = kr3;
#pragma unroll
        for (int j = 0; j < 8; ++j) Vt[(vdb + j) * PAST + vcol]      = vr0[j];
#pragma unroll
        for (int j = 0; j < 8; ++j) Vt[(vdb + 8 + j) * PAST + vcol]  = vr1[j];
#pragma unroll
        for (int j = 0; j < 8; ++j) Vt[(vdb + 16 + j) * PAST + vcol] = vr2[j];
#pragma unroll
        for (int j = 0; j < 8; ++j) Vt[(vdb + 24 + j) * PAST + vcol] = vr3[j];
        __syncthreads();

        if (kt + 1 < nkt) {
            const int kn = kcol0 + 128;
            const u16* kp = K + (size_t)(b * SS + kn + sr) * ldkv + h * DHD + scb;
            kr0 = *(const u16x8*)(kp);
            kr1 = *(const u16x8*)(kp + 8);
            kr2 = *(const u16x8*)(kp + 16);
            kr3 = *(const u16x8*)(kp + 24);
            const u16* vp = V + (size_t)(b * SS + kn + vk) * ldkv + h * DHD + vdb;
            vr0 = *(const u16x8*)(vp);
            vr1 = *(const u16x8*)(vp + 8);
            vr2 = *(const u16x8*)(vp + 16);
            vr3 = *(const u16x8*)(vp + 24);
        }

        f32x4 s[8] = {};
#pragma unroll
        for (int fi = 0; fi < 8; ++fi) {
            bf16x8 kf0 = __builtin_bit_cast(bf16x8, *(const u16x8*)(&KPs[(fi * 16 + lr) * KAST + lg * 8]));
            bf16x8 kf1 = __builtin_bit_cast(bf16x8, *(const u16x8*)(&KPs[(fi * 16 + lr) * KAST + 32 + lg * 8]));
            s[fi] = __builtin_amdgcn_mfma_f32_16x16x32_bf16(qf[0], kf0, s[fi], 0, 0, 0);
            s[fi] = __builtin_amdgcn_mfma_f32_16x16x32_bf16(qf[1], kf1, s[fi], 0, 0, 0);
        }
        __syncthreads();

        float biasf[8];
#pragma unroll
        for (int fi = 0; fi < 8; ++fi)
            biasf[fi] = kmask[b * SS + kcol0 + fi * 16 + lr] ? 0.0f : -INFINITY;
        const bool diag = (causal != 0) && (kt == nkt - 1);

#pragma unroll
        for (int r = 0; r < 4; ++r) {
            const int qrow = q0w + lg * 4 + r;
            const int prow = (w * 16 + lg * 4 + r) * PAST;
            u16x4 pk0, pk1;
            float rs = 0.0f;
#pragma unroll
            for (int fi = 0; fi < 8; ++fi) {
                float v = fmaf(s[fi][r], CSC, biasf[fi]);
                if (diag) {
                    const int key = kcol0 + fi * 16 + lr;
                    v = (key <= qrow) ? v : -INFINITY;
                }
                const float pv = exp2f(v);
                if (fi < 4) pk0[fi] = f2bf(pv); else pk1[fi - 4] = f2bf(pv);
                rs += pv;
            }
            lsum[r] += rs;
            *(u16x4*)(&KPs[prow + lr * 4])      = pk0;
            *(u16x4*)(&KPs[prow + 64 + lr * 4]) = pk1;
        }

#pragma unroll
        for (int kk = 0; kk < 4; ++kk) {
            bf16x8 pf = __builtin_bit_cast(bf16x8, *(const u16x8*)(&KPs[(w * 16 + lr) * PAST + kk * 32 + lg * 8]));
#pragma unroll
            for (int di = 0; di < 4; ++di) {
                bf16x8 vf = __builtin_bit_cast(bf16x8, *(const u16x8*)(&Vt[(di * 16 + lr) * PAST + kk * 32 + lg * 8]));
                acc[di] = __builtin_amdgcn_mfma_f32_16x16x32_bf16(pf, vf, acc[di], 0, 0, 0);
            }
        }
    }

#pragma unroll
    for (int r = 0; r < 4; ++r) {
        float l = lsum[r];
        l += __shfl_xor(l, 1);
        l += __shfl_xor(l, 2);
        l += __shfl_xor(l, 4);
        l += __shfl_xor(l, 8);
        const float inv = (l > 0.0f) ? (1.0f / l) : 0.0f;
        const size_t orow = (size_t)(b * SS + q0w + lg * 4 + r) * DD + h * DHD;
#pragma unroll
        for (int di = 0; di < 4; ++di)
            O[orow + di * 16 + lr] = f2bf(acc[di][r] * inv);
    }
}

// ---------------------------------------------------------------------------
// LayerNorm, bf16 in -> bf16 out.
// ---------------------------------------------------------------------------
__global__ __launch_bounds__(256) void ln_bf_kernel(
    const u16* __restrict__ X, const float* __restrict__ gma,
    const float* __restrict__ bta, u16* __restrict__ Ybf)
{
    const int row = blockIdx.x;
    const int tid = threadIdx.x;
    const u16* x = X + (size_t)row * DD;

    const float v0 = bf2f(x[tid]);
    const float v1 = bf2f(x[tid + 256]);
    const float v2 = bf2f(x[tid + 512]);

    __shared__ float sd[256];
    sd[tid] = v0 + v1 + v2;
    __syncthreads();
    for (int off = 128; off > 0; off >>= 1) {
        if (tid < off) sd[tid] += sd[tid + off];
        __syncthreads();
    }
    const float mean = sd[0] * (1.0f / 768.0f);
    __syncthreads();

    const float q0 = v0 - mean, q1 = v1 - mean, q2 = v2 - mean;
    sd[tid] = q0 * q0 + q1 * q1 + q2 * q2;
    __syncthreads();
    for (int off = 128; off > 0; off >>= 1) {
        if (tid < off) sd[tid] += sd[tid + off];
        __syncthreads();
    }
    const float var = sd[0] * (1.0f / 768.0f);
    const float inv = rsqrtf(var + 1e-5f);

    u16* yb = Ybf + (size_t)row * DD;
    yb[tid]       = f2bf(q0 * inv * gma[tid]       + bta[tid]);
    yb[tid + 256] = f2bf(q1 * inv * gma[tid + 256] + bta[tid + 256]);
    yb[tid + 512] = f2bf(q2 * inv * gma[tid + 512] + bta[tid + 512]);
}

// ---------------------------------------------------------------------------
// LayerNorm over (P0 + P1 + bias + resid_bf16) -> fp32 out (final).
// ---------------------------------------------------------------------------
__global__ __launch_bounds__(256) void ln_red_kernel(
    const u16* __restrict__ P0, const u16* __restrict__ P1,
    const float* __restrict__ bias, const u16* __restrict__ resid,
    const float* __restrict__ gma, const float* __restrict__ bta,
    float* __restrict__ Y)
{
    const int row = blockIdx.x;
    const int tid = threadIdx.x;
    const size_t base = (size_t)row * DD;

    float v[3];
#pragma unroll
    for (int j = 0; j < 3; ++j) {
        const int i = tid + j * 256;
        v[j] = bf2f(P0[base + i]) + bf2f(P1[base + i]) + bias[i] + bf2f(resid[base + i]);
    }

    __shared__ float sd[256];
    sd[tid] = v[0] + v[1] + v[2];
    __syncthreads();
    for (int off = 128; off > 0; off >>= 1) {
        if (tid < off) sd[tid] += sd[tid + off];
        __syncthreads();
    }
    const float mean = sd[0] * (1.0f / 768.0f);
    __syncthreads();

    float q[3];
#pragma unroll
    for (int j = 0; j < 3; ++j) q[j] = v[j] - mean;
    sd[tid] = q[0] * q[0] + q[1] * q[1] + q[2] * q[2];
    __syncthreads();
    for (int off = 128; off > 0; off >>= 1) {
        if (tid < off) sd[tid] += sd[tid + off];
        __syncthreads();
    }
    const float var = sd[0] * (1.0f / 768.0f);
    const float inv = rsqrtf(var + 1e-5f);

    float* y = Y + base;
#pragma unroll
    for (int j = 0; j < 3; ++j) {
        const int i = tid + j * 256;
        y[i] = q[j] * inv * gma[i] + bta[i];
    }
}

// ---------------------------------------------------------------------------
extern "C" void kernel_launch(void* const* d_in, const int* in_sizes, int n_in,
                              void* d_out, int out_size, void* d_ws, size_t ws_size,
                              hipStream_t stream)
{
    (void)in_sizes; (void)n_in; (void)out_size; (void)ws_size;

    const float* key_enc   = (const float*)d_in[0];
    const float* value_enc = (const float*)d_in[1];
    const float* x         = (const float*)d_in[2];
    const int*   src_mask  = (const int*)d_in[3];
    const int*   tgt_mask  = (const int*)d_in[4];
    const float* Wq_m = (const float*)d_in[5];
    const float* Wk_m = (const float*)d_in[6];
    const float* Wv_m = (const float*)d_in[7];
    const float* Wo_m = (const float*)d_in[8];
    const float* Wq_c = (const float*)d_in[9];
    const float* Wk_c = (const float*)d_in[10];
    const float* Wv_c = (const float*)d_in[11];
    const float* Wo_c = (const float*)d_in[12];
    const float* ln1_g = (const float*)d_in[13];
    const float* ln1_b = (const float*)d_in[14];
    const float* ln2_g = (const float*)d_in[15];
    const float* ln2_b = (const float*)d_in[16];
    const float* ln3_g = (const float*)d_in[17];
    const float* ln3_b = (const float*)d_in[18];
    const float* W1 = (const float*)d_in[19];
    const float* b1 = (const float*)d_in[20];
    const float* W2 = (const float*)d_in[21];
    const float* b2 = (const float*)d_in[22];

    float* out = (float*)d_out;

    // workspace layout
    const size_t ACT = (size_t)MROWS * DD;
    char* p = (char*)d_ws;
    u16* QKV  = (u16*)p;   p += 3 * ACT * 2;
    u16* BFx  = (u16*)p;   p += ACT * 2;
    u16* BFK  = (u16*)p;   p += ACT * 2;
    u16* BFV  = (u16*)p;   p += ACT * 2;
    u16* BF1a = (u16*)p;   p += ACT * 2;
    u16* BF1h = (u16*)p;   p += ACT * 2;
    u16* T2bf = (u16*)p;   p += ACT * 2;           // bf16 pre-LN
    u16* SKKV = (u16*)p;   p += 2 * ACT * 2;       // cross-KV | MLP2 partials
    u16* Wm6  = (u16*)p;   p += 6 * (size_t)WPC * 2;
    u16* Wom_t = (u16*)p;  p += (size_t)WPC * 2;
    u16* Woc_t = (u16*)p;  p += (size_t)WPC * 2;
    u16* W1t  = (u16*)p;   p += (size_t)DD * FF * 2;
    u16* W2t  = (u16*)p;   p += (size_t)DD * FF * 2;
    u16* MID  = QKV;       // [4096][3072] bf16 aliases QKV+BFx (dead by MLP)
    u16* KVc  = SKKV;      // [4096][1536] bf16 cross K|V (dead by MLP2)
    u16* SK0  = SKKV;      // [4096][768] bf16 MLP2 partial 0
    u16* SK1  = SKKV + ACT;

    const dim3 blk(256);
    const int nc4 = (int)(ACT / 4);

    // Prep (3 dispatches)
    cvt3_kernel<<<dim3(nc4 / 256, 1, 3), blk, 0, stream>>>(
        x, key_enc, value_enc, BFx, BFK, BFV, nc4);
    tcvt6_kernel<<<dim3(2, 24, 72), blk, 0, stream>>>(
        Wq_m, Wk_m, Wv_m, Wq_c, Wk_c, Wv_c, Wm6);
    tcvt4_kernel<<<dim3(5760), blk, 0, stream>>>(
        Wo_m, Wo_c, W1, W2, Wom_t, Woc_t, W1t, W2t);

    const dim3 gProj(960);
    const dim3 gSkinny(384);
    const dim3 gM1(768);
    const dim3 gM2(768);
    const dim3 gAttn(768);

    gemm128_proj<<<gProj, blk, 0, stream>>>(BFx, BFK, BFV, Wm6, QKV, KVc);

    // Self-attention
    attn_mfma_kernel<<<gAttn, blk, 0, stream>>>(
        QKV, 3 * DD, QKV + DD, QKV + 2 * DD, 3 * DD, tgt_mask, BF1a, 1);
    gemm64<<<gSkinny, blk, 0, stream>>>(BF1a, Wom_t, DD,
                                        x, nullptr, T2bf, DD);
    ln_bf_kernel<<<MROWS, blk, 0, stream>>>(T2bf, ln1_g, ln1_b, BF1h);

    // Cross-attention (K/V already in KVc)
    gemm64<<<gSkinny, blk, 0, stream>>>(BF1h, Wm6 + 3 * WPC, DD,
                                        nullptr, nullptr, QKV, 3 * DD);
    attn_mfma_kernel<<<gAttn, blk, 0, stream>>>(
        QKV, 3 * DD, KVc, KVc + DD, 2 * DD, src_mask, BF1a, 0);
    gemm64<<<gSkinny, blk, 0, stream>>>(BF1a, Woc_t, DD,
                                        nullptr, BF1h, T2bf, DD);
    ln_bf_kernel<<<MROWS, blk, 0, stream>>>(T2bf, ln2_g, ln2_b, BF1h);

    // MLP
    gemm128_mlp1<<<gM1, blk, 0, stream>>>(BF1h, W1t, b1, MID);
    gemm64_sk<<<gM2, blk, 0, stream>>>(MID, W2t, SKKV);
    ln_red_kernel<<<MROWS, blk, 0, stream>>>(SK0, SK1, b2, BF1h,
                                             ln3_g, ln3_b, out);
}

// Round 21
// 291.008 us; speedup vs baseline: 1.1599x; 1.0137x over previous
//
#include <hip/hip_runtime.h>
#include <math.h>

// Problem constants
#define BB 4
#define SS 1024
#define DD 768
#define HH 12
#define DHD 64
#define MROWS 4096
#define FF 3072
#define WPC (DD * DD)

typedef unsigned short u16;
typedef float f32x4 __attribute__((ext_vector_type(4)));
typedef __bf16 bf16x8 __attribute__((ext_vector_type(8)));
typedef unsigned short u16x8 __attribute__((ext_vector_type(8)));
typedef unsigned short u16x4 __attribute__((ext_vector_type(4)));

static __device__ __forceinline__ float bf2f(u16 u) {
    union { unsigned int i; float f; } c; c.i = ((unsigned int)u) << 16; return c.f;
}
static __device__ __forceinline__ u16 f2bf(float f) {
    return __builtin_bit_cast(u16, static_cast<__bf16>(f));
}
// XCD-chunked swizzle: flat grid, total % 8 == 0. Consecutive LOGICAL ids
// land on the same XCD so shared operand panels hit one L2.
static __device__ __forceinline__ int xcd_swz(int total) {
    const int bid = (int)blockIdx.x;
    return (bid & 7) * (total >> 3) + (bid >> 3);
}

#define LDST 40

// ---------------------------------------------------------------------------
// 128x128-tile bf16 MFMA GEMM core (depth-2 explicit unroll). K % 64 == 0.
// ---------------------------------------------------------------------------
static __device__ __forceinline__ void gemm128_core(
    const u16* __restrict__ A, const u16* __restrict__ Bt,
    int K,
    const float* __restrict__ bias, int do_gelu,
    u16* __restrict__ Cbf, int ldcbf, int cboff,
    int row0, int col0, u16* As, u16* Bs)
{
    const int tid  = threadIdx.x;
    const int lane = tid & 63;
    const int w    = tid >> 6;
    const int wm = (w >> 1) * 64;
    const int wn = (w & 1) * 64;

    const int srow = tid >> 1;
    const int skc  = (tid & 1) * 16;

    const u16* Ap = A  + (size_t)(row0 + srow) * K + skc;
    const u16* Bp = Bt + (size_t)(col0 + srow) * K + skc;
    u16* AsW = &As[srow * LDST + skc];
    u16* BsW = &Bs[srow * LDST + skc];

    const int fr = lane & 15;
    const int fk = (lane >> 4) * 8;

    f32x4 acc[4][4] = {};

    u16x8 aa0, aa1, ba0, ba1;
    u16x8 ab0, ab1, bb0, bb1;
    aa0 = *(const u16x8*)(Ap);
    aa1 = *(const u16x8*)(Ap + 8);
    ba0 = *(const u16x8*)(Bp);
    ba1 = *(const u16x8*)(Bp + 8);
    ab0 = *(const u16x8*)(Ap + 32);
    ab1 = *(const u16x8*)(Ap + 40);
    bb0 = *(const u16x8*)(Bp + 32);
    bb1 = *(const u16x8*)(Bp + 40);

    for (int k0 = 0; k0 < K; k0 += 64) {
        if (k0) __syncthreads();
        *(u16x8*)(AsW)     = aa0;
        *(u16x8*)(AsW + 8) = aa1;
        *(u16x8*)(BsW)     = ba0;
        *(u16x8*)(BsW + 8) = ba1;
        __syncthreads();
        if (k0 + 64 < K) {
            aa0 = *(const u16x8*)(Ap + k0 + 64);
            aa1 = *(const u16x8*)(Ap + k0 + 72);
            ba0 = *(const u16x8*)(Bp + k0 + 64);
            ba1 = *(const u16x8*)(Bp + k0 + 72);
        }
        {
            bf16x8 af[4], bfv[4];
#pragma unroll
            for (int mi = 0; mi < 4; ++mi)
                af[mi] = __builtin_bit_cast(bf16x8,
                    *(const u16x8*)(&As[(wm + 16 * mi + fr) * LDST + fk]));
#pragma unroll
            for (int ni = 0; ni < 4; ++ni)
                bfv[ni] = __builtin_bit_cast(bf16x8,
                    *(const u16x8*)(&Bs[(wn + 16 * ni + fr) * LDST + fk]));
#pragma unroll
            for (int mi = 0; mi < 4; ++mi)
#pragma unroll
                for (int ni = 0; ni < 4; ++ni)
                    acc[mi][ni] = __builtin_amdgcn_mfma_f32_16x16x32_bf16(
                        af[mi], bfv[ni], acc[mi][ni], 0, 0, 0);
        }

        __syncthreads();
        *(u16x8*)(AsW)     = ab0;
        *(u16x8*)(AsW + 8) = ab1;
        *(u16x8*)(BsW)     = bb0;
        *(u16x8*)(BsW + 8) = bb1;
        __syncthreads();
        if (k0 + 96 < K) {
            ab0 = *(const u16x8*)(Ap + k0 + 96);
            ab1 = *(const u16x8*)(Ap + k0 + 104);
            bb0 = *(const u16x8*)(Bp + k0 + 96);
            bb1 = *(const u16x8*)(Bp + k0 + 104);
        }
        {
            bf16x8 af[4], bfv[4];
#pragma unroll
            for (int mi = 0; mi < 4; ++mi)
                af[mi] = __builtin_bit_cast(bf16x8,
                    *(const u16x8*)(&As[(wm + 16 * mi + fr) * LDST + fk]));
#pragma unroll
            for (int ni = 0; ni < 4; ++ni)
                bfv[ni] = __builtin_bit_cast(bf16x8,
                    *(const u16x8*)(&Bs[(wn + 16 * ni + fr) * LDST + fk]));
#pragma unroll
            for (int mi = 0; mi < 4; ++mi)
#pragma unroll
                for (int ni = 0; ni < 4; ++ni)
                    acc[mi][ni] = __builtin_amdgcn_mfma_f32_16x16x32_bf16(
                        af[mi], bfv[ni], acc[mi][ni], 0, 0, 0);
        }
    }

    const int orow0 = row0 + wm + (lane >> 4) * 4;
    const int ocol0 = col0 + wn + fr;
#pragma unroll
    for (int mi = 0; mi < 4; ++mi) {
#pragma unroll
        for (int ni = 0; ni < 4; ++ni) {
            const int col = ocol0 + ni * 16;
            const float bv = bias ? bias[col] : 0.0f;
#pragma unroll
            for (int r = 0; r < 4; ++r) {
                const int row = orow0 + mi * 16 + r;
                float v = acc[mi][ni][r] + bv;
                if (do_gelu) v = 0.5f * v * (1.0f + erff(v * 0.70710678118654752f));
                Cbf[(size_t)row * ldcbf + cboff + col] = f2bf(v);
            }
        }
    }
}

// MLP1: flat 768-block grid, XCD-swizzled.
__global__ __launch_bounds__(256) void gemm128_mlp1(
    const u16* __restrict__ A, const u16* __restrict__ Bt,
    const float* __restrict__ bias, u16* __restrict__ Cbf)
{
    __shared__ u16 As[128 * LDST];
    __shared__ u16 Bs[128 * LDST];
    const int lid = xcd_swz(24 * 32);
    gemm128_core(A, Bt, DD, bias, 1, Cbf, FF, 0,
                 (lid / 24) * 128, (lid % 24) * 128, As, Bs);
}

// Batched independent projections, flat 960-block grid, XCD-swizzled.
__global__ __launch_bounds__(256) void gemm128_proj(
    const u16* __restrict__ BFx, const u16* __restrict__ BFK,
    const u16* __restrict__ BFV, const u16* __restrict__ Wm6,
    u16* __restrict__ QKV, u16* __restrict__ KVc)
{
    __shared__ u16 As[128 * LDST];
    __shared__ u16 Bs[128 * LDST];
    const int fid = xcd_swz(960);
    const u16* A; const u16* B; u16* C; int ldc, coff, row0, col0;
    if (fid < 576) {
        A = BFx; B = Wm6; C = QKV; ldc = 3 * DD; coff = 0;
        row0 = (fid / 18) * 128; col0 = (fid % 18) * 128;
    } else if (fid < 768) {
        const int l = fid - 576;
        A = BFK; B = Wm6 + 4 * WPC; C = KVc; ldc = 2 * DD; coff = 0;
        row0 = (l / 6) * 128; col0 = (l % 6) * 128;
    } else {
        const int l = fid - 768;
        A = BFV; B = Wm6 + 5 * WPC; C = KVc; ldc = 2 * DD; coff = DD;
        row0 = (l / 6) * 128; col0 = (l % 6) * 128;
    }
    gemm128_core(A, B, DD, nullptr, 0, C, ldc, coff, row0, col0, As, Bs);
}

// ---------------------------------------------------------------------------
// 64x128-tile GEMM core. Depth-2 unroll. bf16 outputs.
// ---------------------------------------------------------------------------
static __device__ __forceinline__ void gemm64_core(
    const u16* __restrict__ A, const u16* __restrict__ Bt,
    int N, int Kstride, int Klen,
    const float* __restrict__ bias,
    const float* __restrict__ residf, const u16* __restrict__ residb,
    u16* __restrict__ Cbf, int ldcbf, int cboff,
    int row0, int col0, u16* As, u16* Bs)
{
    const int tid  = threadIdx.x;
    const int lane = tid & 63;
    const int w    = tid >> 6;
    const int wm = (w >> 1) * 32;
    const int wn = (w & 1) * 64;

    const int arow = tid >> 2;
    const int akc  = (tid & 3) * 8;
    const int brow = tid >> 1;
    const int bkc  = (tid & 1) * 16;

    const u16* Ap = A  + (size_t)(row0 + arow) * Kstride + akc;
    const u16* Bp = Bt + (size_t)(col0 + brow) * Kstride + bkc;
    u16* AsW = &As[arow * LDST + akc];
    u16* BsW = &Bs[brow * LDST + bkc];

    const int fr = lane & 15;
    const int fk = (lane >> 4) * 8;

    f32x4 acc[2][4] = {};

    u16x8 a0, b00, b01, a1, b10, b11;
    a0  = *(const u16x8*)(Ap);
    b00 = *(const u16x8*)(Bp);
    b01 = *(const u16x8*)(Bp + 8);
    a1  = *(const u16x8*)(Ap + 32);
    b10 = *(const u16x8*)(Bp + 32);
    b11 = *(const u16x8*)(Bp + 40);

    for (int k0 = 0; k0 < Klen; k0 += 64) {
        if (k0) __syncthreads();
        *(u16x8*)AsW       = a0;
        *(u16x8*)BsW       = b00;
        *(u16x8*)(BsW + 8) = b01;
        __syncthreads();
        if (k0 + 64 < Klen) {
            a0  = *(const u16x8*)(Ap + k0 + 64);
            b00 = *(const u16x8*)(Bp + k0 + 64);
            b01 = *(const u16x8*)(Bp + k0 + 72);
        }
        {
            bf16x8 af[2], bfv[4];
#pragma unroll
            for (int mi = 0; mi < 2; ++mi)
                af[mi] = __builtin_bit_cast(bf16x8,
                    *(const u16x8*)(&As[(wm + 16 * mi + fr) * LDST + fk]));
#pragma unroll
            for (int ni = 0; ni < 4; ++ni)
                bfv[ni] = __builtin_bit_cast(bf16x8,
                    *(const u16x8*)(&Bs[(wn + 16 * ni + fr) * LDST + fk]));
#pragma unroll
            for (int mi = 0; mi < 2; ++mi)
#pragma unroll
                for (int ni = 0; ni < 4; ++ni)
                    acc[mi][ni] = __builtin_amdgcn_mfma_f32_16x16x32_bf16(
                        af[mi], bfv[ni], acc[mi][ni], 0, 0, 0);
        }

        __syncthreads();
        *(u16x8*)AsW       = a1;
        *(u16x8*)BsW       = b10;
        *(u16x8*)(BsW + 8) = b11;
        __syncthreads();
        if (k0 + 96 < Klen) {
            a1  = *(const u16x8*)(Ap + k0 + 96);
            b10 = *(const u16x8*)(Bp + k0 + 96);
            b11 = *(const u16x8*)(Bp + k0 + 104);
        }
        {
            bf16x8 af[2], bfv[4];
#pragma unroll
            for (int mi = 0; mi < 2; ++mi)
                af[mi] = __builtin_bit_cast(bf16x8,
                    *(const u16x8*)(&As[(wm + 16 * mi + fr) * LDST + fk]));
#pragma unroll
            for (int ni = 0; ni < 4; ++ni)
                bfv[ni] = __builtin_bit_cast(bf16x8,
                    *(const u16x8*)(&Bs[(wn + 16 * ni + fr) * LDST + fk]));
#pragma unroll
            for (int mi = 0; mi < 2; ++mi)
#pragma unroll
                for (int ni = 0; ni < 4; ++ni)
                    acc[mi][ni] = __builtin_amdgcn_mfma_f32_16x16x32_bf16(
                        af[mi], bfv[ni], acc[mi][ni], 0, 0, 0);
        }
    }

    const int orow0 = row0 + wm + (lane >> 4) * 4;
    const int ocol0 = col0 + wn + fr;
#pragma unroll
    for (int mi = 0; mi < 2; ++mi) {
#pragma unroll
        for (int ni = 0; ni < 4; ++ni) {
            const int col = ocol0 + ni * 16;
            const float bv = bias ? bias[col] : 0.0f;
#pragma unroll
            for (int r = 0; r < 4; ++r) {
                const int row = orow0 + mi * 16 + r;
                float v = acc[mi][ni][r] + bv;
                if (residf) v += residf[(size_t)row * N + col];
                if (residb) v += bf2f(residb[(size_t)row * N + col]);
                Cbf[(size_t)row * ldcbf + cboff + col] = f2bf(v);
            }
        }
    }
}

// N=768 skinny GEMM, flat 384-block grid, swizzled.
__global__ __launch_bounds__(256) void gemm64(
    const u16* __restrict__ A, const u16* __restrict__ Bt, int K,
    const float* __restrict__ residf, const u16* __restrict__ residb,
    u16* __restrict__ Cbf, int ldcbf)
{
    __shared__ u16 As[64 * LDST];
    __shared__ u16 Bs[128 * LDST];
    const int lid = xcd_swz(6 * 64);
    gemm64_core(A, Bt, DD, K, K, nullptr, residf, residb, Cbf, ldcbf, 0,
                (lid / 6) * 64, (lid % 6) * 128, As, Bs);
}

// Split-K MLP2: flat 768-block grid, swizzled; bf16 partials.
__global__ __launch_bounds__(256) void gemm64_sk(
    const u16* __restrict__ A, const u16* __restrict__ Bt,
    u16* __restrict__ Cpair)
{
    __shared__ u16 As[64 * LDST];
    __shared__ u16 Bs[128 * LDST];
    const int lid = xcd_swz(6 * 64 * 2);
    const int x = lid % 6;
    const int rem = lid / 6;
    const int y = rem % 64;
    const int z = rem / 64;
    const int koff = z * (FF / 2);
    gemm64_core(A + koff, Bt + koff, DD, FF, FF / 2,
                nullptr, nullptr, nullptr,
                Cpair + (size_t)z * MROWS * DD, DD, 0,
                y * 64, x * 128, As, Bs);
}

// ---------------------------------------------------------------------------
// Unified prep kernel: input converts + all weight transposes, ONE launch.
//   fid [0,9216):      cvt3 (3 tensors x 3072 blocks)
//   fid [9216,12672):  tcvt6 (72 z x 48 blocks)
//   fid [12672,18432): tcvt4 (Wo_m, Wo_c, W1, W2)
// ---------------------------------------------------------------------------
static __device__ __forceinline__ void tcvt_body(
    const float* __restrict__ in, u16* __restrict__ out,
    int K, int N, int bx, int by)
{
    __shared__ float t[32][33];
    const int n0 = bx * 32, k0 = by * 32;
    const int tx = threadIdx.x & 31, ty = threadIdx.x >> 5;
#pragma unroll
    for (int j = 0; j < 4; ++j)
        t[ty + j * 8][tx] = in[(size_t)(k0 + ty + j * 8) * N + n0 + tx];
    __syncthreads();
#pragma unroll
    for (int j = 0; j < 4; ++j)
        out[(size_t)(n0 + ty + j * 8) * K + k0 + tx] = f2bf(t[tx][ty + j * 8]);
}

__global__ __launch_bounds__(256) void prep_all(
    const float* __restrict__ x, const float* __restrict__ key_enc,
    const float* __restrict__ value_enc,
    u16* __restrict__ BFx, u16* __restrict__ BFK, u16* __restrict__ BFV,
    const float* __restrict__ wq_m, const float* __restrict__ wk_m,
    const float* __restrict__ wv_m, const float* __restrict__ wq_c,
    const float* __restrict__ wk_c, const float* __restrict__ wv_c,
    u16* __restrict__ Wm6,
    const float* __restrict__ wom, const float* __restrict__ woc,
    const float* __restrict__ w1, const float* __restrict__ w2,
    u16* __restrict__ womt, u16* __restrict__ woct,
    u16* __restrict__ w1t, u16* __restrict__ w2t)
{
    const int fid = (int)blockIdx.x;
    const int tid = threadIdx.x;
    if (fid < 9216) {
        const int z = fid / 3072;
        const float* s = (z == 0) ? x : (z == 1) ? key_enc : value_enc;
        u16* d = (z == 0) ? BFx : (z == 1) ? BFK : BFV;
        const int i = (fid % 3072) * 256 + tid;
        float4 v = ((const float4*)s)[i];
        ushort4 o;
        o.x = f2bf(v.x); o.y = f2bf(v.y); o.z = f2bf(v.z); o.w = f2bf(v.w);
        ((ushort4*)d)[i] = o;
    } else if (fid < 12672) {
        const int l = fid - 9216;
        const int z = l / 48;
        const int r = l % 48;
        const int wi = z / 12, head = z % 12;
        const float* wsel = (wi == 0) ? wq_m : (wi == 1) ? wk_m :
                            (wi == 2) ? wv_m : (wi == 3) ? wq_c :
                            (wi == 4) ? wk_c : wv_c;
        const float* ib = wsel + (size_t)head * DD * DHD;
        u16* ob = Wm6 + (size_t)wi * WPC + (size_t)head * DHD * DD;
        // per-head transpose [768,64] -> [64,768]: K=DD, N=DHD
        __shared__ float t[32][33];
        const int n0 = (r % 2) * 32, k0 = (r / 2) * 32;
        const int tx = tid & 31, ty = tid >> 5;
#pragma unroll
        for (int j = 0; j < 4; ++j)
            t[ty + j * 8][tx] = ib[(size_t)(k0 + ty + j * 8) * DHD + n0 + tx];
        __syncthreads();
#pragma unroll
        for (int j = 0; j < 4; ++j)
            ob[(size_t)(n0 + ty + j * 8) * DD + k0 + tx] = f2bf(t[tx][ty + j * 8]);
    } else {
        const int l = fid - 12672;
        if (l < 576) {
            tcvt_body(wom, womt, DD, DD, l % 24, l / 24);
        } else if (l < 1152) {
            const int m = l - 576;
            tcvt_body(woc, woct, DD, DD, m % 24, m / 24);
        } else if (l < 3456) {
            const int m = l - 1152;
            tcvt_body(w1, w1t, DD, FF, m % 96, m / 96);
        } else {
            const int m = l - 3456;
            tcvt_body(w2, w2t, FF, DD, m % 24, m / 24);
        }
    }
}

// ---------------------------------------------------------------------------
// MFMA flash attention, max-free exp2 softmax, KVBLK=128, 2 barriers/tile.
// P in a SEPARATE wave-private LDS buffer (no K aliasing, no mid barrier).
// LDS 53248 B -> exactly 3 blocks/CU (= grid's 768/256). XCD-swizzled grid.
// ---------------------------------------------------------------------------
#define KAST 72
#define PAST 136
#define CSC 0.18033688011112042f   // 0.125 * log2(e)
__global__ __launch_bounds__(256) void attn_mfma_kernel(
    const u16* __restrict__ Q, int ldq,
    const u16* __restrict__ K, const u16* __restrict__ V, int ldkv,
    const int* __restrict__ kmask, u16* __restrict__ O, int causal)
{
    const int lid = xcd_swz(16 * BB * HH);
    const int qtl = lid % 16;
    const int bh  = lid / 16;
    const int qt = causal ? (15 - qtl) : qtl;
    const int b  = bh / HH;
    const int h  = bh % HH;
    const int tid  = threadIdx.x;
    const int lane = tid & 63;
    const int w    = tid >> 6;
    const int lr = lane & 15;
    const int lg = lane >> 4;

    __shared__ u16 Ks[128 * KAST];
    __shared__ u16 Ps[64 * PAST];
    __shared__ u16 Vt[64 * PAST];

    const int row0 = qt * 64;
    const int q0w  = row0 + w * 16;

    bf16x8 qf[2];
    {
        const u16* qp = Q + (size_t)(b * SS + q0w + lr) * ldq + h * DHD + lg * 8;
        qf[0] = __builtin_bit_cast(bf16x8, *(const u16x8*)(qp));
        qf[1] = __builtin_bit_cast(bf16x8, *(const u16x8*)(qp + 32));
    }

    const int sr  = tid >> 1;
    const int scb = (tid & 1) * 32;
    const int vk  = tid >> 1;
    const int vdb = (tid & 1) * 32;
    const int k6  = vk & 63;
    const int vcol = ((vk >> 6) << 6) | ((k6 & 15) << 2) | (k6 >> 4);

    f32x4 acc[4] = {};
    float lsum[4] = {0.0f, 0.0f, 0.0f, 0.0f};

    const int nkt = causal ? ((qt + 2) >> 1) : 8;

    u16x8 kr0, kr1, kr2, kr3, vr0, vr1, vr2, vr3;
    {
        const u16* kp = K + (size_t)(b * SS + sr) * ldkv + h * DHD + scb;
        kr0 = *(const u16x8*)(kp);
        kr1 = *(const u16x8*)(kp + 8);
        kr2 = *(const u16x8*)(kp + 16);
        kr3 = *(const u16x8*)(kp + 24);
        const u16* vp = V + (size_t)(b * SS + vk) * ldkv + h * DHD + vdb;
        vr0 = *(const u16x8*)(vp);
        vr1 = *(const u16x8*)(vp + 8);
        vr2 = *(const u16x8*)(vp + 16);
        vr3 = *(const u16x8*)(vp + 24);
    }

    for (int kt = 0; kt < nkt; ++kt) {
        const int kcol0 = kt * 128;
        if (kt) __syncthreads();       // all reads of Ks/Vt from prior tile done

        *(u16x8*)(&Ks[sr * KAST + scb])      = kr0;
        *(u16x8*)(&Ks[sr * KAST + scb + 8])  = kr1;
        *(u16x8*)(&Ks[sr * KAST + scb + 16]) = kr2;
        *(u16x8*)(&Ks[sr * KAST + scb + 24]) = kr3;
#pragma unroll
        for (int j = 0; j < 8; ++j) Vt[(vdb + j) * PAST + vcol]      = vr0[j];
#pragma unroll
        for (int j = 0; j < 8; ++j) Vt[(vdb + 8 + j) * PAST + vcol]  = vr1[j];
#pragma unroll
        for (int j = 0; j < 8; ++j) Vt[(vdb + 16 + j) * PAST + vcol] = vr2[j];
#pragma unroll
        for (int j = 0; j < 8; ++j) Vt[(vdb + 24 + j) * PAST + vcol] = vr3[j];
        __syncthreads();

        if (kt + 1 < nkt) {
            const int kn = kcol0 + 128;
            const u16* kp = K + (size_t)(b * SS + kn + sr) * ldkv + h * DHD + scb;
            kr0 = *(const u16x8*)(kp);
            kr1 = *(const u16x8*)(kp + 8);
            kr2 = *(const u16x8*)(kp + 16);
            kr3 = *(const u16x8*)(kp + 24);
            const u16* vp = V + (size_t)(b * SS + kn + vk) * ldkv + h * DHD + vdb;
            vr0 = *(const u16x8*)(vp);
            vr1 = *(const u16x8*)(vp + 8);
            vr2 = *(const u16x8*)(vp + 16);
            vr3 = *(const u16x8*)(vp + 24);
        }

        // QK^T: 8 key-groups x 2 k-steps
        f32x4 s[8] = {};
#pragma unroll
        for (int fi = 0; fi < 8; ++fi) {
            bf16x8 kf0 = __builtin_bit_cast(bf16x8, *(const u16x8*)(&Ks[(fi * 16 + lr) * KAST + lg * 8]));
            bf16x8 kf1 = __builtin_bit_cast(bf16x8, *(const u16x8*)(&Ks[(fi * 16 + lr) * KAST + 32 + lg * 8]));
            s[fi] = __builtin_amdgcn_mfma_f32_16x16x32_bf16(qf[0], kf0, s[fi], 0, 0, 0);
            s[fi] = __builtin_amdgcn_mfma_f32_16x16x32_bf16(qf[1], kf1, s[fi], 0, 0, 0);
        }
        // NO barrier: P goes to its own wave-private buffer.

        float biasf[8];
#pragma unroll
        for (int fi = 0; fi < 8; ++fi)
            biasf[fi] = kmask[b * SS + kcol0 + fi * 16 + lr] ? 0.0f : -INFINITY;
        const bool diag = (causal != 0) && (kt == nkt - 1);

#pragma unroll
        for (int r = 0; r < 4; ++r) {
            const int qrow = q0w + lg * 4 + r;
            const int prow = (w * 16 + lg * 4 + r) * PAST;
            u16x4 pk0, pk1;
            float rs = 0.0f;
#pragma unroll
            for (int fi = 0; fi < 8; ++fi) {
                float v = fmaf(s[fi][r], CSC, biasf[fi]);
                if (diag) {
                    const int key = kcol0 + fi * 16 + lr;
                    v = (key <= qrow) ? v : -INFINITY;
                }
                const float pv = exp2f(v);
                if (fi < 4) pk0[fi] = f2bf(pv); else pk1[fi - 4] = f2bf(pv);
                rs += pv;
            }
            lsum[r] += rs;
            *(u16x4*)(&Ps[prow + lr * 4])      = pk0;
            *(u16x4*)(&Ps[prow + 64 + lr * 4]) = pk1;
        }

        // PV: A = own wave's P strip, B = Vt
#pragma unroll
        for (int kk = 0; kk < 4; ++kk) {
            bf16x8 pf = __builtin_bit_cast(bf16x8, *(const u16x8*)(&Ps[(w * 16 + lr) * PAST + kk * 32 + lg * 8]));
#pragma unroll
            for (int di = 0; di < 4; ++di) {
                bf16x8 vf = __builtin_bit_cast(bf16x8, *(const u16x8*)(&Vt[(di * 16 + lr) * PAST + kk * 32 + lg * 8]));
                acc[di] = __builtin_amdgcn_mfma_f32_16x16x32_bf16(pf, vf, acc[di], 0, 0, 0);
            }
        }
    }

#pragma unroll
    for (int r = 0; r < 4; ++r) {
        float l = lsum[r];
        l += __shfl_xor(l, 1);
        l += __shfl_xor(l, 2);
        l += __shfl_xor(l, 4);
        l += __shfl_xor(l, 8);
        const float inv = (l > 0.0f) ? (1.0f / l) : 0.0f;
        const size_t orow = (size_t)(b * SS + q0w + lg * 4 + r) * DD + h * DHD;
#pragma unroll
        for (int di = 0; di < 4; ++di)
            O[orow + di * 16 + lr] = f2bf(acc[di][r] * inv);
    }
}

// ---------------------------------------------------------------------------
// LayerNorm, bf16 in -> bf16 out.
// ---------------------------------------------------------------------------
__global__ __launch_bounds__(256) void ln_bf_kernel(
    const u16* __restrict__ X, const float* __restrict__ gma,
    const float* __restrict__ bta, u16* __restrict__ Ybf)
{
    const int row = blockIdx.x;
    const int tid = threadIdx.x;
    const u16* x = X + (size_t)row * DD;

    const float v0 = bf2f(x[tid]);
    const float v1 = bf2f(x[tid + 256]);
    const float v2 = bf2f(x[tid + 512]);

    __shared__ float sd[256];
    sd[tid] = v0 + v1 + v2;
    __syncthreads();
    for (int off = 128; off > 0; off >>= 1) {
        if (tid < off) sd[tid] += sd[tid + off];
        __syncthreads();
    }
    const float mean = sd[0] * (1.0f / 768.0f);
    __syncthreads();

    const float q0 = v0 - mean, q1 = v1 - mean, q2 = v2 - mean;
    sd[tid] = q0 * q0 + q1 * q1 + q2 * q2;
    __syncthreads();
    for (int off = 128; off > 0; off >>= 1) {
        if (tid < off) sd[tid] += sd[tid + off];
        __syncthreads();
    }
    const float var = sd[0] * (1.0f / 768.0f);
    const float inv = rsqrtf(var + 1e-5f);

    u16* yb = Ybf + (size_t)row * DD;
    yb[tid]       = f2bf(q0 * inv * gma[tid]       + bta[tid]);
    yb[tid + 256] = f2bf(q1 * inv * gma[tid + 256] + bta[tid + 256]);
    yb[tid + 512] = f2bf(q2 * inv * gma[tid + 512] + bta[tid + 512]);
}

// ---------------------------------------------------------------------------
// LayerNorm over (P0 + P1 + bias + resid_bf16) -> fp32 out (final).
// ---------------------------------------------------------------------------
__global__ __launch_bounds__(256) void ln_red_kernel(
    const u16* __restrict__ P0, const u16* __restrict__ P1,
    const float* __restrict__ bias, const u16* __restrict__ resid,
    const float* __restrict__ gma, const float* __restrict__ bta,
    float* __restrict__ Y)
{
    const int row = blockIdx.x;
    const int tid = threadIdx.x;
    const size_t base = (size_t)row * DD;

    float v[3];
#pragma unroll
    for (int j = 0; j < 3; ++j) {
        const int i = tid + j * 256;
        v[j] = bf2f(P0[base + i]) + bf2f(P1[base + i]) + bias[i] + bf2f(resid[base + i]);
    }

    __shared__ float sd[256];
    sd[tid] = v[0] + v[1] + v[2];
    __syncthreads();
    for (int off = 128; off > 0; off >>= 1) {
        if (tid < off) sd[tid] += sd[tid + off];
        __syncthreads();
    }
    const float mean = sd[0] * (1.0f / 768.0f);
    __syncthreads();

    float q[3];
#pragma unroll
    for (int j = 0; j < 3; ++j) q[j] = v[j] - mean;
    sd[tid] = q[0] * q[0] + q[1] * q[1] + q[2] * q[2];
    __syncthreads();
    for (int off = 128; off > 0; off >>= 1) {
        if (tid < off) sd[tid] += sd[tid + off];
        __syncthreads();
    }
    const float var = sd[0] * (1.0f / 768.0f);
    const float inv = rsqrtf(var + 1e-5f);

    float* y = Y + base;
#pragma unroll
    for (int j = 0; j < 3; ++j) {
        const int i = tid + j * 256;
        y[i] = q[j] * inv * gma[i] + bta[i];
    }
}

// ---------------------------------------------------------------------------
extern "C" void kernel_launch(void* const* d_in, const int* in_sizes, int n_in,
                              void* d_out, int out_size, void* d_ws, size_t ws_size,
                              hipStream_t stream)
{
    (void)in_sizes; (void)n_in; (void)out_size; (void)ws_size;

    const float* key_enc   = (const float*)d_in[0];
    const float* value_enc = (const float*)d_in[1];
    const float* x         = (const float*)d_in[2];
    const int*   src_mask  = (const int*)d_in[3];
    const int*   tgt_mask  = (const int*)d_in[4];
    const float* Wq_m = (const float*)d_in[5];
    const float* Wk_m = (const float*)d_in[6];
    const float* Wv_m = (const float*)d_in[7];
    const float* Wo_m = (const float*)d_in[8];
    const float* Wq_c = (const float*)d_in[9];
    const float* Wk_c = (const float*)d_in[10];
    const float* Wv_c = (const float*)d_in[11];
    const float* Wo_c = (const float*)d_in[12];
    const float* ln1_g = (const float*)d_in[13];
    const float* ln1_b = (const float*)d_in[14];
    const float* ln2_g = (const float*)d_in[15];
    const float* ln2_b = (const float*)d_in[16];
    const float* ln3_g = (const float*)d_in[17];
    const float* ln3_b = (const float*)d_in[18];
    const float* W1 = (const float*)d_in[19];
    const float* b1 = (const float*)d_in[20];
    const float* W2 = (const float*)d_in[21];
    const float* b2 = (const float*)d_in[22];

    float* out = (float*)d_out;

    // workspace layout
    const size_t ACT = (size_t)MROWS * DD;
    char* p = (char*)d_ws;
    u16* QKV  = (u16*)p;   p += 3 * ACT * 2;
    u16* BFx  = (u16*)p;   p += ACT * 2;
    u16* BFK  = (u16*)p;   p += ACT * 2;
    u16* BFV  = (u16*)p;   p += ACT * 2;
    u16* BF1a = (u16*)p;   p += ACT * 2;
    u16* BF1h = (u16*)p;   p += ACT * 2;
    u16* T2bf = (u16*)p;   p += ACT * 2;           // bf16 pre-LN
    u16* SKKV = (u16*)p;   p += 2 * ACT * 2;       // cross-KV | MLP2 partials
    u16* Wm6  = (u16*)p;   p += 6 * (size_t)WPC * 2;
    u16* Wom_t = (u16*)p;  p += (size_t)WPC * 2;
    u16* Woc_t = (u16*)p;  p += (size_t)WPC * 2;
    u16* W1t  = (u16*)p;   p += (size_t)DD * FF * 2;
    u16* W2t  = (u16*)p;   p += (size_t)DD * FF * 2;
    u16* MID  = QKV;       // [4096][3072] bf16 aliases QKV+BFx (dead by MLP)
    u16* KVc  = SKKV;      // [4096][1536] bf16 cross K|V (dead by MLP2)
    u16* SK0  = SKKV;      // [4096][768] bf16 MLP2 partial 0
    u16* SK1  = SKKV + ACT;

    const dim3 blk(256);

    // Unified prep (1 dispatch)
    prep_all<<<dim3(18432), blk, 0, stream>>>(
        x, key_enc, value_enc, BFx, BFK, BFV,
        Wq_m, Wk_m, Wv_m, Wq_c, Wk_c, Wv_c, Wm6,
        Wo_m, Wo_c, W1, W2, Wom_t, Woc_t, W1t, W2t);

    const dim3 gProj(960);
    const dim3 gSkinny(384);
    const dim3 gM1(768);
    const dim3 gM2(768);
    const dim3 gAttn(768);

    gemm128_proj<<<gProj, blk, 0, stream>>>(BFx, BFK, BFV, Wm6, QKV, KVc);

    // Self-attention
    attn_mfma_kernel<<<gAttn, blk, 0, stream>>>(
        QKV, 3 * DD, QKV + DD, QKV + 2 * DD, 3 * DD, tgt_mask, BF1a, 1);
    gemm64<<<gSkinny, blk, 0, stream>>>(BF1a, Wom_t, DD,
                                        x, nullptr, T2bf, DD);
    ln_bf_kernel<<<MROWS, blk, 0, stream>>>(T2bf, ln1_g, ln1_b, BF1h);

    // Cross-attention (K/V already in KVc)
    gemm64<<<gSkinny, blk, 0, stream>>>(BF1h, Wm6 + 3 * WPC, DD,
                                        nullptr, nullptr, QKV, 3 * DD);
    attn_mfma_kernel<<<gAttn, blk, 0, stream>>>(
        QKV, 3 * DD, KVc, KVc + DD, 2 * DD, src_mask, BF1a, 0);
    gemm64<<<gSkinny, blk, 0, stream>>>(BF1a, Woc_t, DD,
                                        nullptr, BF1h, T2bf, DD);
    ln_bf_kernel<<<MROWS, blk, 0, stream>>>(T2bf, ln2_g, ln2_b, BF1h);

    // MLP
    gemm128_mlp1<<<gM1, blk, 0, stream>>>(BF1h, W1t, b1, MID);
    gemm64_sk<<<gM2, blk, 0, stream>>>(MID, W2t, SKKV);
    ln_red_kernel<<<MROWS, blk, 0, stream>>>(SK0, SK1, b2, BF1h,
                                             ln3_g, ln3_b, out);
}